// Round 1
// 3289.405 us; speedup vs baseline: 1.0332x; 1.0332x over previous
//
#include <hip/hip_runtime.h>

#define PI2 6.28318530717958647692f

typedef __attribute__((ext_vector_type(8))) short bf16x8;
typedef __attribute__((ext_vector_type(4))) float f32x4;

__device__ __forceinline__ void cfma(float2& acc, float2 a, float2 t) {
  acc.x += a.x * t.x - a.y * t.y;
  acc.y += a.x * t.y + a.y * t.x;
}
// multiply by conj(t) (inverse twiddle), t = e^{-i\theta}
__device__ __forceinline__ void cfmac(float2& acc, float2 a, float2 t) {
  acc.x += a.x * t.x + a.y * t.y;
  acc.y += a.y * t.x - a.x * t.y;
}

__device__ __forceinline__ short f2bf(float f) {
  unsigned u = __float_as_uint(f);
  unsigned r = (u + 0x7fff + ((u >> 16) & 1)) >> 16;
  return (short)r;
}

// twiddle tables: T[0..31]=e^{-2pi i m/32}, T[32..47]=N16, T[48..67]=N20, T[68..71]=N4
__global__ void k_twid(float2* __restrict__ T) {
  int i = threadIdx.x;
  float s, c;
  if (i < 32) { __sincosf(-PI2 * (float)i / 32.f, &s, &c); T[i] = make_float2(c, s); }
  if (i < 16) { __sincosf(-PI2 * (float)i / 16.f, &s, &c); T[32 + i] = make_float2(c, s); }
  if (i < 20) { __sincosf(-PI2 * (float)i / 20.f, &s, &c); T[48 + i] = make_float2(c, s); }
  if (i < 4)  { __sincosf(-PI2 * (float)i / 4.f,  &s, &c); T[68 + i] = make_float2(c, s); }
}

// ---------------- spectral forward ----------------
__global__ void k_fwd_z(const float* __restrict__ x, const float2* __restrict__ T,
                        float2* __restrict__ out, int nrows) {
  __shared__ float2 tw[16];
  if (threadIdx.x < 16) tw[threadIdx.x] = T[32 + threadIdx.x];
  __syncthreads();
  int r = blockIdx.x * 256 + threadIdx.x;
  if (r >= nrows) return;
  const float* p = x + (size_t)r * 16;
  float v[16];
#pragma unroll
  for (int z = 0; z < 16; z++) v[z] = p[z];
#pragma unroll
  for (int zk = 0; zk < 4; zk++) {
    float re = 0.f, im = 0.f;
#pragma unroll
    for (int z = 0; z < 16; z++) {
      float2 t = tw[(z * zk) & 15];
      re += v[z] * t.x;
      im += v[z] * t.y;
    }
    out[(size_t)r * 4 + zk] = make_float2(re, im);
  }
}

__global__ void k_fwd_y(const float2* __restrict__ in, const float2* __restrict__ T,
                        float2* __restrict__ out, int n) {
  __shared__ float2 tw[32];
  if (threadIdx.x < 32) tw[threadIdx.x] = T[threadIdx.x];
  __syncthreads();
  int i = blockIdx.x * 256 + threadIdx.x;
  if (i >= n) return;
  int zk = i & 3, yk = (i >> 2) & 7, slab = i >> 5;
  const float2* p = in + (size_t)slab * 128 + zk;
  float2 acc = make_float2(0.f, 0.f);
  for (int y = 0; y < 32; y++) cfma(acc, p[y * 4], tw[(y * yk) & 31]);
  out[i] = acc;
}

__global__ void k_fwd_x(const float2* __restrict__ in, const float2* __restrict__ T,
                        float2* __restrict__ out, int n) {
  __shared__ float2 tw[32];
  if (threadIdx.x < 32) tw[threadIdx.x] = T[threadIdx.x];
  __syncthreads();
  int i = blockIdx.x * 256 + threadIdx.x;
  if (i >= n) return;
  int zk = i & 3, yk = (i >> 2) & 7, xi = (i >> 5) & 15, slab = i >> 9;
  int xk = (xi < 8) ? xi : xi + 16;
  const float2* p = in + (size_t)slab * 1024 + yk * 4 + zk;
  float2 acc = make_float2(0.f, 0.f);
  for (int xx = 0; xx < 32; xx++) cfma(acc, p[xx * 32], tw[(xx * xk) & 31]);
  out[i] = acc;
}

__global__ void k_fwd_t(const float2* __restrict__ in, const float2* __restrict__ T,
                        float2* __restrict__ out, int n) {
  __shared__ float2 tw[16];
  if (threadIdx.x < 16) tw[threadIdx.x] = T[32 + threadIdx.x];
  __syncthreads();
  int i = blockIdx.x * 256 + threadIdx.x;
  if (i >= n) return;
  int zk = i & 3, yk = (i >> 2) & 7, xi = (i >> 5) & 15, ti = (i >> 9) & 7, bc = i >> 12;
  int tk = (ti < 4) ? ti : ti + 8;
  const float2* p = in + (size_t)bc * 8192 + xi * 32 + yk * 4 + zk;
  float2 acc = make_float2(0.f, 0.f);
  for (int t = 0; t < 16; t++) cfma(acc, p[t * 512], tw[(t * tk) & 15]);
  out[i] = acc;
}

__global__ void k_fwd_c(const float2* __restrict__ in, const float2* __restrict__ T,
                        float2* __restrict__ out, int n) {
  __shared__ float2 tw[20];
  if (threadIdx.x < 20) tw[threadIdx.x] = T[48 + threadIdx.x];
  __syncthreads();
  int i = blockIdx.x * 256 + threadIdx.x;
  if (i >= n) return;
  int mode = i & 4095, r = i >> 12, ck = r % 20, b = r / 20;
  const float2* p = in + (size_t)b * 81920 + mode;
  float2 acc = make_float2(0.f, 0.f);
  int idx = 0;
  for (int c = 0; c < 20; c++) {
    cfma(acc, p[(size_t)c * 4096], tw[idx]);
    idx += ck; if (idx >= 20) idx -= 20;
  }
  out[i] = acc;
}

__global__ void k_fwd_b(const float2* __restrict__ in, const float2* __restrict__ T,
                        float2* __restrict__ out, int n) {
  __shared__ float2 tw[4];
  if (threadIdx.x < 4) tw[threadIdx.x] = T[68 + threadIdx.x];
  __syncthreads();
  int i = blockIdx.x * 256 + threadIdx.x;
  if (i >= n) return;
  int mode = i & 4095, r = i >> 12, ck = r % 20, bk = r / 20;
  const float2* p = in + (size_t)ck * 4096 + mode;
  float2 acc = make_float2(0.f, 0.f);
#pragma unroll
  for (int b = 0; b < 4; b++) cfma(acc, p[(size_t)b * 81920], tw[(b * bk) & 3]);
  out[i] = acc;
}

__global__ void k_smul(const float2* __restrict__ in,
                       const float* __restrict__ sw1, const float* __restrict__ sw2,
                       const float* __restrict__ sw3, const float* __restrict__ sw4,
                       float2* __restrict__ out, int n) {
  int i = blockIdx.x * 256 + threadIdx.x;
  if (i >= n) return;
  int mode = i & 4095, r = i >> 12, o = r % 20, bk = r / 20;
  int ti = mode >> 9, xi = (mode >> 5) & 15, yk = (mode >> 2) & 7, zk = mode & 3;
  const float* w = (ti < 4) ? ((xi < 8) ? sw1 : sw3) : ((xi < 8) ? sw2 : sw4);
  int tl = ti & 3, xl = xi & 7;
  const float2* wp = (const float2*)w;
  const float2* ip = in + (size_t)bk * 81920 + mode;
  size_t wsub = (size_t)o * 1024 + (size_t)tl * 256 + (size_t)xl * 32 + yk * 4 + zk;
  float2 acc = make_float2(0.f, 0.f);
  for (int ci = 0; ci < 20; ci++) cfma(acc, ip[(size_t)ci * 4096], wp[(size_t)ci * 20480 + wsub]);
  out[i] = acc;
}

// ---------------- spectral inverse ----------------
__global__ void k_inv_t(const float2* __restrict__ in, const float2* __restrict__ T,
                        float2* __restrict__ out, int n) {
  __shared__ float2 tw[16];
  if (threadIdx.x < 16) tw[threadIdx.x] = T[32 + threadIdx.x];
  __syncthreads();
  int i = blockIdx.x * 256 + threadIdx.x;
  if (i >= n) return;
  int zk = i & 3, yk = (i >> 2) & 7, xi = (i >> 5) & 15, tp = (i >> 9) & 15, bc = i >> 13;
  const float2* p = in + (size_t)bc * 4096 + xi * 32 + yk * 4 + zk;
  float2 acc = make_float2(0.f, 0.f);
#pragma unroll
  for (int ti = 0; ti < 8; ti++) {
    int tk = (ti < 4) ? ti : ti + 8;
    cfmac(acc, p[ti * 512], tw[(tk * tp) & 15]);
  }
  out[i] = acc;
}

__global__ void k_inv_x(const float2* __restrict__ in, const float2* __restrict__ T,
                        float2* __restrict__ out, int n) {
  __shared__ float2 tw[32];
  if (threadIdx.x < 32) tw[threadIdx.x] = T[threadIdx.x];
  __syncthreads();
  int i = blockIdx.x * 256 + threadIdx.x;
  if (i >= n) return;
  int zk = i & 3, yk = (i >> 2) & 7, xp = (i >> 5) & 31, tp = (i >> 10) & 15, bc = i >> 14;
  const float2* p = in + (size_t)bc * 8192 + tp * 512 + yk * 4 + zk;
  float2 acc = make_float2(0.f, 0.f);
#pragma unroll
  for (int xi = 0; xi < 16; xi++) {
    int xk = (xi < 8) ? xi : xi + 16;
    cfmac(acc, p[xi * 32], tw[(xk * xp) & 31]);
  }
  out[i] = acc;
}

// fused inverse-y + c2r-z: thread per (bc,tp,xp,yp), emits full 16-z real row.
__global__ void k_inv_yz(const float2* __restrict__ in, const float2* __restrict__ T,
                         float* __restrict__ out, int n) {
  __shared__ float2 tw[48];  // 0..31: N32, 32..47: N16
  if (threadIdx.x < 48) tw[threadIdx.x] = T[threadIdx.x];
  __syncthreads();
  int i = blockIdx.x * 256 + threadIdx.x;
  if (i >= n) return;
  int yp = i & 31;
  const float2* p = in + (size_t)(i >> 5) * 32;  // [bc][tp][xp] slab: [yk8][zk4]
  float2 Ay[4];
#pragma unroll
  for (int zk = 0; zk < 4; zk++) Ay[zk] = make_float2(0.f, 0.f);
#pragma unroll
  for (int yk = 0; yk < 8; yk++) {
    float2 w = tw[(yk * yp) & 31];
#pragma unroll
    for (int zk = 0; zk < 4; zk++) cfmac(Ay[zk], p[yk * 4 + zk], w);
  }
  float res[16];
#pragma unroll
  for (int zp = 0; zp < 16; zp++) {
    float v = Ay[0].x;
#pragma unroll
    for (int zk = 1; zk < 4; zk++) {
      float2 t = tw[32 + ((zk * zp) & 15)];
      v += 2.f * (Ay[zk].x * t.x + Ay[zk].y * t.y);
    }
    res[zp] = v * (1.f / 262144.f);
  }
  float4* o4 = (float4*)(out + (size_t)i * 16);
#pragma unroll
  for (int q = 0; q < 4; q++)
    o4[q] = make_float4(res[q * 4], res[q * 4 + 1], res[q * 4 + 2], res[q * 4 + 3]);
}

// ---------------- U-Net: convs ----------------
__global__ void k_conv4d_pos(const float* __restrict__ in1, int Ci1,
                             const float* __restrict__ in2, int Ci2,
                             const float* __restrict__ W, float* __restrict__ out,
                             int Ti, int Xi, int Yi, int Zi,
                             int To, int Xo, int Yo, int Zo, int stride, int n) {
  int idx = blockIdx.x * 256 + threadIdx.x;
  if (idx >= n) return;
  int zo = idx % Zo; int r = idx / Zo;
  int yo = r % Yo; r /= Yo;
  int xo = r % Xo; r /= Xo;
  int to = r % To; int b = r / To;
  float acc[20];
#pragma unroll
  for (int o = 0; o < 20; o++) acc[o] = 0.f;
  int Ci = Ci1 + Ci2;
  size_t in_sp = (size_t)Ti * Xi * Yi * Zi;
  for (int ci = 0; ci < Ci; ci++) {
    const float* base = (ci < Ci1) ? in1 + ((size_t)b * Ci1 + ci) * in_sp
                                   : in2 + ((size_t)b * Ci2 + (ci - Ci1)) * in_sp;
    const float* wc = W + (size_t)ci * 81;
    for (int kt = 0; kt < 3; kt++) {
      int t = to * stride + kt - 1; if (t < 0 || t >= Ti) continue;
      for (int kx = 0; kx < 3; kx++) {
        int xx = xo * stride + kx - 1; if (xx < 0 || xx >= Xi) continue;
        for (int ky = 0; ky < 3; ky++) {
          int y = yo * stride + ky - 1; if (y < 0 || y >= Yi) continue;
          for (int kz = 0; kz < 3; kz++) {
            int z = zo * stride + kz - 1; if (z < 0 || z >= Zi) continue;
            float v = base[(((size_t)t * Xi + xx) * Yi + y) * Zi + z];
            int tap = ((kt * 3 + kx) * 3 + ky) * 3 + kz;
#pragma unroll
            for (int o = 0; o < 20; o++) acc[o] += v * wc[(size_t)o * Ci * 81 + tap];
          }
        }
      }
    }
  }
  size_t osp = (size_t)To * Xo * Yo * Zo;
  size_t obase = (size_t)b * 20 * osp + (((size_t)to * Xo + xo) * Yo + yo) * Zo + zo;
#pragma unroll
  for (int o = 0; o < 20; o++) out[obase + (size_t)o * osp] = acc[o];
}

__global__ void k_conv4d_elem(const float* __restrict__ in, const float* __restrict__ W,
                              float* __restrict__ out, int Ci,
                              int Ti, int Xi, int Yi, int Zi,
                              int To, int Xo, int Yo, int Zo, int stride, int n) {
  int idx = blockIdx.x * 256 + threadIdx.x;
  if (idx >= n) return;
  int zo = idx % Zo; int r = idx / Zo;
  int yo = r % Yo; r /= Yo;
  int xo = r % Xo; r /= Xo;
  int to = r % To; r /= To;
  int o = r % 20; int b = r / 20;
  float acc = 0.f;
  size_t in_sp = (size_t)Ti * Xi * Yi * Zi;
  for (int ci = 0; ci < Ci; ci++) {
    const float* base = in + ((size_t)b * Ci + ci) * in_sp;
    const float* wc = W + ((size_t)o * Ci + ci) * 81;
    for (int kt = 0; kt < 3; kt++) {
      int t = to * stride + kt - 1; if (t < 0 || t >= Ti) continue;
      for (int kx = 0; kx < 3; kx++) {
        int xx = xo * stride + kx - 1; if (xx < 0 || xx >= Xi) continue;
        for (int ky = 0; ky < 3; ky++) {
          int y = yo * stride + ky - 1; if (y < 0 || y >= Yi) continue;
          for (int kz = 0; kz < 3; kz++) {
            int z = zo * stride + kz - 1; if (z < 0 || z >= Zi) continue;
            acc += base[(((size_t)t * Xi + xx) * Yi + y) * Zi + z] * wc[((kt * 3 + kx) * 3 + ky) * 3 + kz];
          }
        }
      }
    }
  }
  out[idx] = acc;
}

// ---------------- BN ----------------
__global__ void k_bn_stats(const float* __restrict__ d, int S, float* __restrict__ stats) {
  int c = blockIdx.x;
  int tid = threadIdx.x;
  float s = 0.f, s2 = 0.f;
  for (int b = 0; b < 4; b++) {
    const float* p = d + ((size_t)b * 20 + c) * S;
    for (int i = tid; i < S; i += 256) { float v = p[i]; s += v; s2 += v * v; }
  }
  __shared__ float ls[256], lq[256];
  ls[tid] = s; lq[tid] = s2;
  __syncthreads();
  for (int off = 128; off > 0; off >>= 1) {
    if (tid < off) { ls[tid] += ls[tid + off]; lq[tid] += lq[tid + off]; }
    __syncthreads();
  }
  if (tid == 0) {
    float cnt = 4.f * (float)S;
    float mean = ls[0] / cnt;
    float var = lq[0] / cnt - mean * mean;
    stats[2 * c] = mean;
    stats[2 * c + 1] = rsqrtf(var + 1e-5f);
  }
}

__global__ void k_bn_apply(float* __restrict__ d, int S, const float* __restrict__ stats,
                           const float* __restrict__ g, const float* __restrict__ bb, int n) {
  int idx = blockIdx.x * 256 + threadIdx.x;
  if (idx >= n) return;
  int c = (idx / S) % 20;
  float v = d[idx];
  v = (v - stats[2 * c]) * stats[2 * c + 1] * g[c] + bb[c];
  d[idx] = (v >= 0.f) ? v : 0.1f * v;
}

// BN apply for oc1 + bf16 channels-last copy into CLd0 ci 0..19
__global__ void k_bn_apply_cl(float* __restrict__ d, const float* __restrict__ stats,
                              const float* __restrict__ g, const float* __restrict__ bb,
                              short* __restrict__ CL, int n) {
  int idx = blockIdx.x * 256 + threadIdx.x;
  if (idx >= n) return;
  int s = idx & 16383;
  int r = idx >> 14;
  int c = r % 20, b = r / 20;
  float v = d[idx];
  v = (v - stats[2 * c]) * stats[2 * c + 1] * g[c] + bb[c];
  v = (v >= 0.f) ? v : 0.1f * v;
  d[idx] = v;
  CL[((size_t)(b * 16384 + s)) * 40 + c] = f2bf(v);
}

// ---------------- deconv (ConvTranspose4d k=4 s=2 p=1), bias+lrelu fused ----------------
__device__ __forceinline__ int dcands(int p, int n_in, int* q, int* k) {
  int cnt = 0;
  int q0 = (p + 1) >> 1, k0 = p + 1 - 2 * q0;
  if (q0 >= 0 && q0 < n_in) { q[cnt] = q0; k[cnt] = k0; cnt++; }
  int q1 = q0 - 1, k1 = k0 + 2;
  if (q1 >= 0 && q1 < n_in) { q[cnt] = q1; k[cnt] = k1; cnt++; }
  return cnt;
}

__global__ void k_deconv4d(const float* __restrict__ in1, int Ci1,
                           const float* __restrict__ in2, int Ci2,
                           const float* __restrict__ W, const float* __restrict__ bias,
                           float* __restrict__ out,
                           int Ti, int Xi, int Yi, int Zi, int n) {
  int idx = blockIdx.x * 256 + threadIdx.x;
  if (idx >= n) return;
  int To = 2 * Ti, Xo = 2 * Xi, Yo = 2 * Yi, Zo = 2 * Zi;
  int zo = idx % Zo; int r = idx / Zo;
  int yo = r % Yo; r /= Yo;
  int xo = r % Xo; r /= Xo;
  int to = r % To; int b = r / To;
  int qt[2], kt[2], qx[2], kx[2], qy[2], ky[2], qz[2], kz[2];
  int nt = dcands(to, Ti, qt, kt), nx = dcands(xo, Xi, qx, kx);
  int ny = dcands(yo, Yi, qy, ky), nz = dcands(zo, Zi, qz, kz);
  float acc[20];
#pragma unroll
  for (int o = 0; o < 20; o++) acc[o] = 0.f;
  int Ci = Ci1 + Ci2;
  size_t in_sp = (size_t)Ti * Xi * Yi * Zi;
  for (int ci = 0; ci < Ci; ci++) {
    const float* base = (ci < Ci1) ? in1 + ((size_t)b * Ci1 + ci) * in_sp
                                   : in2 + ((size_t)b * Ci2 + (ci - Ci1)) * in_sp;
    const float* wc = W + (size_t)ci * 5120;  // [ci][o(20)][256]
    for (int it = 0; it < nt; it++)
      for (int ix = 0; ix < nx; ix++)
        for (int iy = 0; iy < ny; iy++)
          for (int iz = 0; iz < nz; iz++) {
            float v = base[(((size_t)qt[it] * Xi + qx[ix]) * Yi + qy[iy]) * Zi + qz[iz]];
            int tap = ((kt[it] * 4 + kx[ix]) * 4 + ky[iy]) * 4 + kz[iz];
#pragma unroll
            for (int o = 0; o < 20; o++) acc[o] += v * wc[o * 256 + tap];
          }
  }
  size_t osp = (size_t)To * Xo * Yo * Zo;
  size_t obase = (size_t)b * 20 * osp + (((size_t)to * Xo + xo) * Yo + yo) * Zo + zo;
#pragma unroll
  for (int o = 0; o < 20; o++) {
    float v2 = acc[o] + bias[o];
    out[obase + (size_t)o * osp] = (v2 >= 0.f) ? v2 : 0.1f * v2;
  }
}

// d1 deconv: in 4x8x8x4 (oc2|od2, Ci=40) -> out 8x16x16x8 written bf16 CL ci 20..39
__global__ void k_deconv_d1_cl(const float* __restrict__ in1, const float* __restrict__ in2,
                               const float* __restrict__ W, const float* __restrict__ bias,
                               short* __restrict__ CL, int n) {
  int idx = blockIdx.x * 256 + threadIdx.x;
  if (idx >= n) return;
  int zo = idx & 7; int r = idx >> 3;
  int yo = r & 15; r >>= 4;
  int xo = r & 15; r >>= 4;
  int to = r & 7; int b = r >> 3;
  int qt[2], kt[2], qx[2], kx[2], qy[2], ky[2], qz[2], kz[2];
  int nt = dcands(to, 4, qt, kt), nx = dcands(xo, 8, qx, kx);
  int ny = dcands(yo, 8, qy, ky), nz = dcands(zo, 4, qz, kz);
  float acc[20];
#pragma unroll
  for (int o = 0; o < 20; o++) acc[o] = 0.f;
  const size_t in_sp = 4 * 8 * 8 * 4;
  for (int ci = 0; ci < 40; ci++) {
    const float* base = (ci < 20) ? in1 + ((size_t)b * 20 + ci) * in_sp
                                  : in2 + ((size_t)b * 20 + (ci - 20)) * in_sp;
    const float* wc = W + (size_t)ci * 5120;
    for (int it = 0; it < nt; it++)
      for (int ix = 0; ix < nx; ix++)
        for (int iy = 0; iy < ny; iy++)
          for (int iz = 0; iz < nz; iz++) {
            float v = base[(((size_t)qt[it] * 8 + qx[ix]) * 8 + qy[iy]) * 4 + qz[iz]];
            int tap = ((kt[it] * 4 + kx[ix]) * 4 + ky[iy]) * 4 + kz[iz];
#pragma unroll
            for (int o = 0; o < 20; o++) acc[o] += v * wc[o * 256 + tap];
          }
  }
  size_t pos = (((size_t)b * 8 + to) * 16 + xo) * 16 * 8 + (size_t)yo * 8 + zo;
  short* dst = CL + pos * 40 + 20;
#pragma unroll
  for (int o = 0; o < 20; o++) {
    float v2 = acc[o] + bias[o];
    v2 = (v2 >= 0.f) ? v2 : 0.1f * v2;
    dst[o] = f2bf(v2);
  }
}

// fill Xcl ci 0..19 from x
__global__ void k_xcl_x(const float* __restrict__ x, short* __restrict__ Xcl, int n) {
  int i = blockIdx.x * 256 + threadIdx.x;
  if (i >= n) return;
  int s = i & 262143, b = i >> 18;
  short* dst = Xcl + (size_t)i * 40;
  const float* src = x + (size_t)b * 20 * 262144 + s;
#pragma unroll
  for (int c = 0; c < 20; c++) dst[c] = f2bf(src[(size_t)c * 262144]);
}

// pack out_w [20][40][81] + w_pw [20][20] -> Wp[tap(82)][mt(2)][m(16)][k(64)] bf16 + zero-page
// tap 81 = pointwise (x2) weights.
__global__ void k_pack_w(const float* __restrict__ out_w, const float* __restrict__ w_pw,
                         short* __restrict__ Wp, short* __restrict__ zp, int n) {
  int i = blockIdx.x * 256 + threadIdx.x;
  if (i >= n) return;
  int k = i & 63, m = (i >> 6) & 15, mt = (i >> 10) & 1, tap = i >> 11;
  int o = mt * 16 + m;
  float v = 0.f;
  if (o < 20 && k < 40) {
    if (tap < 81) v = out_w[((size_t)o * 40 + k) * 81 + tap];
    else if (k < 20) v = w_pw[o * 20 + k];
  }
  Wp[i] = f2bf(v);
  if (i < 64) zp[i] = 0;
}

// pack d0_w [40][20][256] -> Wd[tap(256)][mt(2)][m(16)][k(64)] bf16
__global__ void k_pack_wd(const float* __restrict__ d0_w, short* __restrict__ Wd, int n) {
  int i = blockIdx.x * 256 + threadIdx.x;
  if (i >= n) return;
  int k = i & 63, m = (i >> 6) & 15, mt = (i >> 10) & 1, tap = i >> 11;
  int o = mt * 16 + m;
  float v = (o < 20 && k < 40) ? d0_w[((size_t)k * 20 + o) * 256 + tap] : 0.f;
  Wd[i] = f2bf(v);
}

// ---------------- d0 deconv via MFMA (parity-class decomposition) ----------------
__global__ __launch_bounds__(256) void k_d0_mfma(
    const short* __restrict__ CL, const short* __restrict__ Wd,
    const short* __restrict__ zp, const float* __restrict__ bias,
    short* __restrict__ Xcl) {
  int gw = blockIdx.x * 4 + (threadIdx.x >> 6);
  int uz = gw & 7, ux = (gw >> 3) & 15, ut = (gw >> 7) & 7, b = gw >> 10;
  int lane = threadIdx.x & 63;
  int ln15 = lane & 15, kg = lane >> 4;  // ln15 = uy

  const char* xb = (const char*)CL;
  const char* wb = (const char*)Wd;
  const char* zb = (const char*)zp;

#pragma unroll 1
  for (int cls = 0; cls < 16; cls++) {
    int et = (cls >> 3) & 1, ex = (cls >> 2) & 1, ey = (cls >> 1) & 1, ez = cls & 1;
    f32x4 acc0, acc1;
#pragma unroll
    for (int j = 0; j < 4; j++) { acc0[j] = 0.f; acc1[j] = 0.f; }
#pragma unroll
    for (int it = 0; it < 2; it++) {
      int kt = et ? (2 * it) : (1 + 2 * it);
      int qt = ut + (et ? (1 - it) : (-it));
      if (qt < 0 || qt > 7) continue;
#pragma unroll
      for (int ix = 0; ix < 2; ix++) {
        int kx = ex ? (2 * ix) : (1 + 2 * ix);
        int qx = ux + (ex ? (1 - ix) : (-ix));
        if (qx < 0 || qx > 15) continue;
#pragma unroll
        for (int iz = 0; iz < 2; iz++) {
          int kz = ez ? (2 * iz) : (1 + 2 * iz);
          int qz = uz + (ez ? (1 - iz) : (-iz));
          if (qz < 0 || qz > 7) continue;
#pragma unroll
          for (int iy = 0; iy < 2; iy++) {
            int ky = ey ? (2 * iy) : (1 + 2 * iy);
            int qy = ln15 + (ey ? (1 - iy) : (-iy));
            bool yok = (qy >= 0) && (qy < 16);
            int tap = ((kt * 4 + kx) * 4 + ky) * 4 + kz;
            long pos = ((((long)b * 8 + qt) * 16 + qx) * 16 + qy) * 8 + qz;
            const char* wt = wb + (size_t)tap * 4096;
#pragma unroll
            for (int ch = 0; ch < 2; ch++) {
              bf16x8 a0 = *(const bf16x8*)(wt + ln15 * 128 + ch * 64 + kg * 16);
              bf16x8 a1 = *(const bf16x8*)(wt + 2048 + ln15 * 128 + ch * 64 + kg * 16);
              const char* src = yok ? (xb + pos * 80 + ch * 64 + kg * 16)
                                    : (zb + ch * 64 + kg * 16);
              bf16x8 bv = *(const bf16x8*)src;
              acc0 = __builtin_amdgcn_mfma_f32_16x16x32_bf16(a0, bv, acc0, 0, 0, 0);
              acc1 = __builtin_amdgcn_mfma_f32_16x16x32_bf16(a1, bv, acc1, 0, 0, 0);
            }
          }
        }
      }
    }
    int to = 2 * ut + et, xo = 2 * ux + ex, zo = 2 * uz + ez, yo = 2 * ln15 + ey;
    long opos = ((((long)b * 16 + to) * 32 + xo) * 32 + yo) * 16 + zo;
    short* dst = Xcl + opos * 40 + 20;
    {
      unsigned h[4];
#pragma unroll
      for (int r = 0; r < 4; r++) {
        float v = acc0[r] + bias[kg * 4 + r];
        v = (v >= 0.f) ? v : 0.1f * v;
        h[r] = (unsigned)(unsigned short)f2bf(v);
      }
      uint2 u;
      u.x = h[0] | (h[1] << 16);
      u.y = h[2] | (h[3] << 16);
      *(uint2*)(dst + kg * 4) = u;
    }
    if (kg == 0) {
      unsigned h[4];
#pragma unroll
      for (int r = 0; r < 4; r++) {
        float v = acc1[r] + bias[16 + r];
        v = (v >= 0.f) ? v : 0.1f * v;
        h[r] = (unsigned)(unsigned short)f2bf(v);
      }
      uint2 u;
      u.x = h[0] | (h[1] << 16);
      u.y = h[2] | (h[3] << 16);
      *(uint2*)(dst + 16) = u;
    }
  }
}

// ---------------- final conv: LDS-staged bf16 MFMA implicit GEMM ----------------
// Block = (b, t0, x0), 512 threads = 8 waves covering y 0..31, z 0..15, och 0..19.
// Each valid (ti,xi) input slab is one contiguous 40KB run of Xcl; it is staged
// into LDS once via global_load_lds (dbuf: stage i+1 overlaps compute i), instead
// of re-streaming it from L2/L3 per tap. Boundary y/z handled by clamp+zero-select.
// ch=1 B-chunk is a single broadcast 16B read (k rows 40..63 have zero weights).
__global__ __launch_bounds__(512, 4) void k_fconv_mfma(
    const short* __restrict__ Xcl, const short* __restrict__ Wp,
    const float* __restrict__ bias, const float* __restrict__ bpw,
    float* __restrict__ io) {
  __shared__ __align__(16) char lds[2][40960];  // 81920 B: exactly 2 blocks/CU
  int bid = blockIdx.x;
  int xcd = bid & 7, idx = bid >> 3;
  int b = xcd >> 1, xh = xcd & 1;
  // t0-major within each XCD: working set 3 xi-slabs x 16 ti x 40KB ~ 1.9MB < 4MB L2
  int t0 = idx & 15, x0 = xh * 16 + ((idx >> 4) & 15);
  int tid = threadIdx.x;
  int lane = tid & 63;
  int ln15 = lane & 15, kg = lane >> 4;
  int ybase = (tid >> 6) * 4;

  // valid (kt,kx) slab list, 4 bits per entry (code = kt*4+kx; center = 5)
  unsigned long long codes = 0ull;
  int ns = 0;
  for (int kt = 0; kt < 3; kt++) {
    int ti = t0 + kt - 1;
    if (ti < 0 || ti > 15) continue;
    for (int kx = 0; kx < 3; kx++) {
      int xi = x0 + kx - 1;
      if (xi < 0 || xi > 31) continue;
      codes |= (unsigned long long)(kt * 4 + kx) << (4 * ns);
      ns++;
    }
  }

  const char* xb = (const char*)Xcl;
  const char* wb = (const char*)Wp;

  auto stage = [&](char* dst, int code) {
    int ti = t0 + (code >> 2) - 1, xi = x0 + (code & 3) - 1;
    const char* src = xb + (size_t)((b * 16 + ti) * 32 + xi) * 512 * 80;
#pragma unroll
    for (int s = 0; s < 5; s++) {
      int off = s * 8192 + tid * 16;
      __builtin_amdgcn_global_load_lds(
          (const __attribute__((address_space(1))) void*)(src + off),
          (__attribute__((address_space(3))) void*)(dst + off), 16, 0, 0);
    }
  };

  f32x4 acc[2][4];
#pragma unroll
  for (int mt = 0; mt < 2; mt++)
#pragma unroll
    for (int nt = 0; nt < 4; nt++)
#pragma unroll
      for (int j = 0; j < 4; j++) acc[mt][nt][j] = 0.f;

  stage(lds[0], (int)(codes & 15));
  asm volatile("s_waitcnt vmcnt(0)" ::: "memory");
  __syncthreads();

  int cur = 0;
#pragma unroll 1
  for (int i = 0; i < ns; i++) {
    const char* bufc = lds[cur];
    if (i + 1 < ns) stage(lds[cur ^ 1], (int)((codes >> (4 * (i + 1))) & 15));
    int code = (int)((codes >> (4 * i)) & 15);
    int kt = code >> 2, kx = code & 3;
    bf16x8 zv = {0, 0, 0, 0, 0, 0, 0, 0};
#pragma unroll
    for (int kz = 0; kz < 3; kz++) {
      int zi = ln15 + kz - 1;
      bool zok = (zi >= 0) && (zi < 16);
      int zc = zok ? zi : 0;
#pragma unroll
      for (int ch = 0; ch < 2; ch++) {
        int co = ch ? 64 : kg * 16;  // ch=1: broadcast ci 32..39 chunk to all kg
        bf16x8 bv[6];
#pragma unroll
        for (int j = 0; j < 6; j++) {
          int yi = ybase + j - 1;
          int yc = (yi < 0) ? 0 : ((yi > 31) ? 31 : yi);
          bf16x8 v = *(const bf16x8*)(bufc + (size_t)(yc * 16 + zc) * 80 + co);
          bool ok = zok && (yi >= 0) && (yi < 32);
          bv[j] = ok ? v : zv;
        }
        bf16x8 av[3][2];
#pragma unroll
        for (int ky = 0; ky < 3; ky++) {
          int tap = ((kt * 3 + kx) * 3 + ky) * 3 + kz;
          const char* wt = wb + (size_t)tap * 4096 + ln15 * 128 + ch * 64 + kg * 16;
          av[ky][0] = *(const bf16x8*)wt;
          av[ky][1] = *(const bf16x8*)(wt + 2048);
        }
#pragma unroll
        for (int ky = 0; ky < 3; ky++)
#pragma unroll
          for (int nt = 0; nt < 4; nt++) {
            acc[0][nt] = __builtin_amdgcn_mfma_f32_16x16x32_bf16(av[ky][0], bv[nt + ky], acc[0][nt], 0, 0, 0);
            acc[1][nt] = __builtin_amdgcn_mfma_f32_16x16x32_bf16(av[ky][1], bv[nt + ky], acc[1][nt], 0, 0, 0);
          }
      }
    }
    if (code == 5) {
      // center slab: fused pointwise (x2) tap, ci 0..19 (weights zero for k>=20)
      const char* wt = wb + (size_t)81 * 4096 + ln15 * 128 + kg * 16;
      bf16x8 a0 = *(const bf16x8*)wt;
      bf16x8 a1 = *(const bf16x8*)(wt + 2048);
#pragma unroll
      for (int nt = 0; nt < 4; nt++) {
        bf16x8 bv = *(const bf16x8*)(bufc + (size_t)((ybase + nt) * 16 + ln15) * 80 + kg * 16);
        acc[0][nt] = __builtin_amdgcn_mfma_f32_16x16x32_bf16(a0, bv, acc[0][nt], 0, 0, 0);
        acc[1][nt] = __builtin_amdgcn_mfma_f32_16x16x32_bf16(a1, bv, acc[1][nt], 0, 0, 0);
      }
    }
    asm volatile("s_waitcnt vmcnt(0)" ::: "memory");
    __syncthreads();
    cur ^= 1;
  }

#pragma unroll
  for (int mt = 0; mt < 2; mt++)
#pragma unroll
    for (int r = 0; r < 4; r++) {
      int o = mt * 16 + kg * 4 + r;
      if (o >= 20) continue;
      float bo = bias[o] + bpw[o];
#pragma unroll
      for (int nt = 0; nt < 4; nt++) {
        int y = ybase + nt;
        size_t oidx = ((size_t)(b * 20 + o)) * 262144 +
                      ((((size_t)t0 * 32 + x0) * 32 + y) * 16 + ln15);
        float v = acc[mt][nt][r] + bo + io[oidx];
        io[oidx] = fmaxf(v, 0.f);
      }
    }
}

extern "C" void kernel_launch(void* const* d_in, const int* in_sizes, int n_in,
                              void* d_out, int out_size, void* d_ws, size_t ws_size,
                              hipStream_t stream) {
  const float* x     = (const float*)d_in[0];
  const float* sw1   = (const float*)d_in[1];
  const float* sw2   = (const float*)d_in[2];
  const float* sw3   = (const float*)d_in[3];
  const float* sw4   = (const float*)d_in[4];
  const float* w_pw  = (const float*)d_in[5];
  const float* b_pw  = (const float*)d_in[6];
  const float* c1_w  = (const float*)d_in[7];
  const float* c2_w  = (const float*)d_in[8];
  const float* c21_w = (const float*)d_in[9];
  const float* c3_w  = (const float*)d_in[10];
  const float* c31_w = (const float*)d_in[11];
  const float* bn1_g = (const float*)d_in[12];
  const float* bn1_b = (const float*)d_in[13];
  const float* bn2_g = (const float*)d_in[14];
  const float* bn2_b = (const float*)d_in[15];
  const float* bn21_g = (const float*)d_in[16];
  const float* bn21_b = (const float*)d_in[17];
  const float* bn3_g = (const float*)d_in[18];
  const float* bn3_b = (const float*)d_in[19];
  const float* bn31_g = (const float*)d_in[20];
  const float* bn31_b = (const float*)d_in[21];
  const float* d2_w  = (const float*)d_in[22];
  const float* d2_b  = (const float*)d_in[23];
  const float* d1_w  = (const float*)d_in[24];
  const float* d1_b  = (const float*)d_in[25];
  const float* d0_w  = (const float*)d_in[26];
  const float* d0_b  = (const float*)d_in[27];
  const float* out_w = (const float*)d_in[28];
  const float* out_b = (const float*)d_in[29];
  float* out = (float*)d_out;
  float* ws = (float*)d_ws;

  // spectral arena (phase 1 only)
  float2* A  = (float2*)(ws);
  float2* Bb = (float2*)(ws + 10485760);
  float2* Cb = (float2*)(ws + 13107200);
  float2* Dd = (float2*)(ws + 14417920);
  float2* Ee = (float2*)(ws + 15073280);
  float2* Ff = (float2*)(ws + 15728640);
  float2* Gg = (float2*)(ws + 16384000);
  // twiddle tables: live only during spectral phase; region inside Xcl span,
  // beyond the spectral arena end (17,039,360 fl), overwritten later by k_xcl_x.
  float2* Twid = (float2*)(ws + 23000000);

  // U-Net arena
  float* oc1   = ws;
  short* CLd0  = (short*)(ws + 1310720);
  float* oc2a  = ws + 2621440;
  float* oc2   = ws + 2703360;
  float* oc3a  = ws + 2785280;
  float* oc3   = ws + 2790400;
  float* od2   = ws + 2795520;
  short* Xcl   = (short*)(ws + 2877440);
  float* stats = ws + 23848960;
  short* Wd = (short*)(ws);
  short* Wp = (short*)(ws + 262144);
  short* zp = (short*)(ws + 349184);

  auto nb = [](int n) { return (n + 255) / 256; };
  dim3 blk(256);

  // ---- twiddle tables ----
  k_twid<<<1, 64, 0, stream>>>(Twid);

  // ---- spectral path: x1 -> d_out ----
  k_fwd_z<<<nb(1310720), blk, 0, stream>>>(x, Twid, A, 1310720);
  k_fwd_y<<<nb(1310720), blk, 0, stream>>>(A, Twid, Bb, 1310720);
  k_fwd_x<<<nb(655360), blk, 0, stream>>>(Bb, Twid, Cb, 655360);
  k_fwd_t<<<nb(327680), blk, 0, stream>>>(Cb, Twid, Dd, 327680);
  k_fwd_c<<<nb(327680), blk, 0, stream>>>(Dd, Twid, Ee, 327680);
  k_fwd_b<<<nb(327680), blk, 0, stream>>>(Ee, Twid, Ff, 327680);
  k_smul<<<nb(327680), blk, 0, stream>>>(Ff, sw1, sw2, sw3, sw4, Gg, 327680);
  k_inv_t<<<nb(655360), blk, 0, stream>>>(Gg, Twid, Cb, 655360);
  k_inv_x<<<nb(1310720), blk, 0, stream>>>(Cb, Twid, Bb, 1310720);
  k_inv_yz<<<nb(1310720), blk, 0, stream>>>(Bb, Twid, out, 1310720);

  // ---- Xcl ci 0..19 from x ----
  k_xcl_x<<<nb(1048576), blk, 0, stream>>>(x, Xcl, 1048576);

  // ---- U-Net encoder ----
  k_conv4d_pos<<<nb(65536), blk, 0, stream>>>(x, 20, nullptr, 0, c1_w, oc1,
                                              16, 32, 32, 16, 8, 16, 16, 8, 2, 65536);
  k_bn_stats<<<20, blk, 0, stream>>>(oc1, 16384, stats);
  k_bn_apply_cl<<<nb(1310720), blk, 0, stream>>>(oc1, stats, bn1_g, bn1_b, CLd0, 1310720);

  k_conv4d_elem<<<nb(81920), blk, 0, stream>>>(oc1, c2_w, oc2a, 20,
                                               8, 16, 16, 8, 4, 8, 8, 4, 2, 81920);
  k_bn_stats<<<20, blk, 0, stream>>>(oc2a, 1024, stats);
  k_bn_apply<<<nb(81920), blk, 0, stream>>>(oc2a, 1024, stats, bn2_g, bn2_b, 81920);

  k_conv4d_elem<<<nb(81920), blk, 0, stream>>>(oc2a, c21_w, oc2, 20,
                                               4, 8, 8, 4, 4, 8, 8, 4, 1, 81920);
  k_bn_stats<<<20, blk, 0, stream>>>(oc2, 1024, stats);
  k_bn_apply<<<nb(81920), blk, 0, stream>>>(oc2, 1024, stats, bn21_g, bn21_b, 81920);

  k_conv4d_elem<<<nb(5120), blk, 0, stream>>>(oc2, c3_w, oc3a, 20,
                                              4, 8, 8, 4, 2, 4, 4, 2, 2, 5120);
  k_bn_stats<<<20, blk, 0, stream>>>(oc3a, 64, stats);
  k_bn_apply<<<nb(5120), blk, 0, stream>>>(oc3a, 64, stats, bn3_g, bn3_b, 5120);

  k_conv4d_elem<<<nb(5120), blk, 0, stream>>>(oc3a, c31_w, oc3, 20,
                                              2, 4, 4, 2, 2, 4, 4, 2, 1, 5120);
  k_bn_stats<<<20, blk, 0, stream>>>(oc3, 64, stats);
  k_bn_apply<<<nb(5120), blk, 0, stream>>>(oc3, 64, stats, bn31_g, bn31_b, 5120);

  // ---- decoder ----
  k_deconv4d<<<nb(4096), blk, 0, stream>>>(oc3, 20, nullptr, 0, d2_w, d2_b, od2,
                                           2, 4, 4, 2, 4096);
  k_deconv_d1_cl<<<nb(65536), blk, 0, stream>>>(oc2, od2, d1_w, d1_b, CLd0, 65536);

  // weight packs
  k_pack_w<<<nb(167936), blk, 0, stream>>>(out_w, w_pw, Wp, zp, 167936);
  k_pack_wd<<<nb(524288), blk, 0, stream>>>(d0_w, Wd, 524288);

  // d0 deconv via MFMA -> Xcl ci 20..39
  k_d0_mfma<<<1024, blk, 0, stream>>>(CLd0, Wd, zp, d0_b, Xcl);

  // final conv via MFMA (LDS-staged), fused +bias +x1 +x2(pointwise) +relu into d_out
  k_fconv_mfma<<<2048, dim3(512), 0, stream>>>(Xcl, Wp, out_b, b_pw, out);
}

// Round 2
// 2771.628 us; speedup vs baseline: 1.2263x; 1.1868x over previous
//
#include <hip/hip_runtime.h>

#define PI2 6.28318530717958647692f

typedef __attribute__((ext_vector_type(8))) short bf16x8;
typedef __attribute__((ext_vector_type(4))) float f32x4;

__device__ __forceinline__ void cfma(float2& acc, float2 a, float2 t) {
  acc.x += a.x * t.x - a.y * t.y;
  acc.y += a.x * t.y + a.y * t.x;
}
// multiply by conj(t) (inverse twiddle), t = e^{-i\theta}
__device__ __forceinline__ void cfmac(float2& acc, float2 a, float2 t) {
  acc.x += a.x * t.x + a.y * t.y;
  acc.y += a.y * t.x - a.x * t.y;
}

__device__ __forceinline__ short f2bf(float f) {
  unsigned u = __float_as_uint(f);
  unsigned r = (u + 0x7fff + ((u >> 16) & 1)) >> 16;
  return (short)r;
}

// twiddle tables: T[0..31]=e^{-2pi i m/32}, T[32..47]=N16, T[48..67]=N20, T[68..71]=N4
__global__ void k_twid(float2* __restrict__ T) {
  int i = threadIdx.x;
  float s, c;
  if (i < 32) { __sincosf(-PI2 * (float)i / 32.f, &s, &c); T[i] = make_float2(c, s); }
  if (i < 16) { __sincosf(-PI2 * (float)i / 16.f, &s, &c); T[32 + i] = make_float2(c, s); }
  if (i < 20) { __sincosf(-PI2 * (float)i / 20.f, &s, &c); T[48 + i] = make_float2(c, s); }
  if (i < 4)  { __sincosf(-PI2 * (float)i / 4.f,  &s, &c); T[68 + i] = make_float2(c, s); }
}

// ---------------- spectral forward ----------------
__global__ void k_fwd_z(const float* __restrict__ x, const float2* __restrict__ T,
                        float2* __restrict__ out, int nrows) {
  __shared__ float2 tw[16];
  if (threadIdx.x < 16) tw[threadIdx.x] = T[32 + threadIdx.x];
  __syncthreads();
  int r = blockIdx.x * 256 + threadIdx.x;
  if (r >= nrows) return;
  const float* p = x + (size_t)r * 16;
  float v[16];
#pragma unroll
  for (int z = 0; z < 16; z++) v[z] = p[z];
#pragma unroll
  for (int zk = 0; zk < 4; zk++) {
    float re = 0.f, im = 0.f;
#pragma unroll
    for (int z = 0; z < 16; z++) {
      float2 t = tw[(z * zk) & 15];
      re += v[z] * t.x;
      im += v[z] * t.y;
    }
    out[(size_t)r * 4 + zk] = make_float2(re, im);
  }
}

__global__ void k_fwd_y(const float2* __restrict__ in, const float2* __restrict__ T,
                        float2* __restrict__ out, int n) {
  __shared__ float2 tw[32];
  if (threadIdx.x < 32) tw[threadIdx.x] = T[threadIdx.x];
  __syncthreads();
  int i = blockIdx.x * 256 + threadIdx.x;
  if (i >= n) return;
  int zk = i & 3, yk = (i >> 2) & 7, slab = i >> 5;
  const float2* p = in + (size_t)slab * 128 + zk;
  float2 acc = make_float2(0.f, 0.f);
  for (int y = 0; y < 32; y++) cfma(acc, p[y * 4], tw[(y * yk) & 31]);
  out[i] = acc;
}

__global__ void k_fwd_x(const float2* __restrict__ in, const float2* __restrict__ T,
                        float2* __restrict__ out, int n) {
  __shared__ float2 tw[32];
  if (threadIdx.x < 32) tw[threadIdx.x] = T[threadIdx.x];
  __syncthreads();
  int i = blockIdx.x * 256 + threadIdx.x;
  if (i >= n) return;
  int zk = i & 3, yk = (i >> 2) & 7, xi = (i >> 5) & 15, slab = i >> 9;
  int xk = (xi < 8) ? xi : xi + 16;
  const float2* p = in + (size_t)slab * 1024 + yk * 4 + zk;
  float2 acc = make_float2(0.f, 0.f);
  for (int xx = 0; xx < 32; xx++) cfma(acc, p[xx * 32], tw[(xx * xk) & 31]);
  out[i] = acc;
}

__global__ void k_fwd_t(const float2* __restrict__ in, const float2* __restrict__ T,
                        float2* __restrict__ out, int n) {
  __shared__ float2 tw[16];
  if (threadIdx.x < 16) tw[threadIdx.x] = T[32 + threadIdx.x];
  __syncthreads();
  int i = blockIdx.x * 256 + threadIdx.x;
  if (i >= n) return;
  int zk = i & 3, yk = (i >> 2) & 7, xi = (i >> 5) & 15, ti = (i >> 9) & 7, bc = i >> 12;
  int tk = (ti < 4) ? ti : ti + 8;
  const float2* p = in + (size_t)bc * 8192 + xi * 32 + yk * 4 + zk;
  float2 acc = make_float2(0.f, 0.f);
  for (int t = 0; t < 16; t++) cfma(acc, p[t * 512], tw[(t * tk) & 15]);
  out[i] = acc;
}

__global__ void k_fwd_c(const float2* __restrict__ in, const float2* __restrict__ T,
                        float2* __restrict__ out, int n) {
  __shared__ float2 tw[20];
  if (threadIdx.x < 20) tw[threadIdx.x] = T[48 + threadIdx.x];
  __syncthreads();
  int i = blockIdx.x * 256 + threadIdx.x;
  if (i >= n) return;
  int mode = i & 4095, r = i >> 12, ck = r % 20, b = r / 20;
  const float2* p = in + (size_t)b * 81920 + mode;
  float2 acc = make_float2(0.f, 0.f);
  int idx = 0;
  for (int c = 0; c < 20; c++) {
    cfma(acc, p[(size_t)c * 4096], tw[idx]);
    idx += ck; if (idx >= 20) idx -= 20;
  }
  out[i] = acc;
}

__global__ void k_fwd_b(const float2* __restrict__ in, const float2* __restrict__ T,
                        float2* __restrict__ out, int n) {
  __shared__ float2 tw[4];
  if (threadIdx.x < 4) tw[threadIdx.x] = T[68 + threadIdx.x];
  __syncthreads();
  int i = blockIdx.x * 256 + threadIdx.x;
  if (i >= n) return;
  int mode = i & 4095, r = i >> 12, ck = r % 20, bk = r / 20;
  const float2* p = in + (size_t)ck * 4096 + mode;
  float2 acc = make_float2(0.f, 0.f);
#pragma unroll
  for (int b = 0; b < 4; b++) cfma(acc, p[(size_t)b * 81920], tw[(b * bk) & 3]);
  out[i] = acc;
}

__global__ void k_smul(const float2* __restrict__ in,
                       const float* __restrict__ sw1, const float* __restrict__ sw2,
                       const float* __restrict__ sw3, const float* __restrict__ sw4,
                       float2* __restrict__ out, int n) {
  int i = blockIdx.x * 256 + threadIdx.x;
  if (i >= n) return;
  int mode = i & 4095, r = i >> 12, o = r % 20, bk = r / 20;
  int ti = mode >> 9, xi = (mode >> 5) & 15, yk = (mode >> 2) & 7, zk = mode & 3;
  const float* w = (ti < 4) ? ((xi < 8) ? sw1 : sw3) : ((xi < 8) ? sw2 : sw4);
  int tl = ti & 3, xl = xi & 7;
  const float2* wp = (const float2*)w;
  const float2* ip = in + (size_t)bk * 81920 + mode;
  size_t wsub = (size_t)o * 1024 + (size_t)tl * 256 + (size_t)xl * 32 + yk * 4 + zk;
  float2 acc = make_float2(0.f, 0.f);
  for (int ci = 0; ci < 20; ci++) cfma(acc, ip[(size_t)ci * 4096], wp[(size_t)ci * 20480 + wsub]);
  out[i] = acc;
}

// ---------------- spectral inverse ----------------
__global__ void k_inv_t(const float2* __restrict__ in, const float2* __restrict__ T,
                        float2* __restrict__ out, int n) {
  __shared__ float2 tw[16];
  if (threadIdx.x < 16) tw[threadIdx.x] = T[32 + threadIdx.x];
  __syncthreads();
  int i = blockIdx.x * 256 + threadIdx.x;
  if (i >= n) return;
  int zk = i & 3, yk = (i >> 2) & 7, xi = (i >> 5) & 15, tp = (i >> 9) & 15, bc = i >> 13;
  const float2* p = in + (size_t)bc * 4096 + xi * 32 + yk * 4 + zk;
  float2 acc = make_float2(0.f, 0.f);
#pragma unroll
  for (int ti = 0; ti < 8; ti++) {
    int tk = (ti < 4) ? ti : ti + 8;
    cfmac(acc, p[ti * 512], tw[(tk * tp) & 15]);
  }
  out[i] = acc;
}

__global__ void k_inv_x(const float2* __restrict__ in, const float2* __restrict__ T,
                        float2* __restrict__ out, int n) {
  __shared__ float2 tw[32];
  if (threadIdx.x < 32) tw[threadIdx.x] = T[threadIdx.x];
  __syncthreads();
  int i = blockIdx.x * 256 + threadIdx.x;
  if (i >= n) return;
  int zk = i & 3, yk = (i >> 2) & 7, xp = (i >> 5) & 31, tp = (i >> 10) & 15, bc = i >> 14;
  const float2* p = in + (size_t)bc * 8192 + tp * 512 + yk * 4 + zk;
  float2 acc = make_float2(0.f, 0.f);
#pragma unroll
  for (int xi = 0; xi < 16; xi++) {
    int xk = (xi < 8) ? xi : xi + 16;
    cfmac(acc, p[xi * 32], tw[(xk * xp) & 31]);
  }
  out[i] = acc;
}

// fused inverse-y + c2r-z: thread per (bc,tp,xp,yp), emits full 16-z real row.
__global__ void k_inv_yz(const float2* __restrict__ in, const float2* __restrict__ T,
                         float* __restrict__ out, int n) {
  __shared__ float2 tw[48];  // 0..31: N32, 32..47: N16
  if (threadIdx.x < 48) tw[threadIdx.x] = T[threadIdx.x];
  __syncthreads();
  int i = blockIdx.x * 256 + threadIdx.x;
  if (i >= n) return;
  int yp = i & 31;
  const float2* p = in + (size_t)(i >> 5) * 32;  // [bc][tp][xp] slab: [yk8][zk4]
  float2 Ay[4];
#pragma unroll
  for (int zk = 0; zk < 4; zk++) Ay[zk] = make_float2(0.f, 0.f);
#pragma unroll
  for (int yk = 0; yk < 8; yk++) {
    float2 w = tw[(yk * yp) & 31];
#pragma unroll
    for (int zk = 0; zk < 4; zk++) cfmac(Ay[zk], p[yk * 4 + zk], w);
  }
  float res[16];
#pragma unroll
  for (int zp = 0; zp < 16; zp++) {
    float v = Ay[0].x;
#pragma unroll
    for (int zk = 1; zk < 4; zk++) {
      float2 t = tw[32 + ((zk * zp) & 15)];
      v += 2.f * (Ay[zk].x * t.x + Ay[zk].y * t.y);
    }
    res[zp] = v * (1.f / 262144.f);
  }
  float4* o4 = (float4*)(out + (size_t)i * 16);
#pragma unroll
  for (int q = 0; q < 4; q++)
    o4[q] = make_float4(res[q * 4], res[q * 4 + 1], res[q * 4 + 2], res[q * 4 + 3]);
}

// ---------------- U-Net: convs ----------------
__global__ void k_conv4d_pos(const float* __restrict__ in1, int Ci1,
                             const float* __restrict__ in2, int Ci2,
                             const float* __restrict__ W, float* __restrict__ out,
                             int Ti, int Xi, int Yi, int Zi,
                             int To, int Xo, int Yo, int Zo, int stride, int n) {
  int idx = blockIdx.x * 256 + threadIdx.x;
  if (idx >= n) return;
  int zo = idx % Zo; int r = idx / Zo;
  int yo = r % Yo; r /= Yo;
  int xo = r % Xo; r /= Xo;
  int to = r % To; int b = r / To;
  float acc[20];
#pragma unroll
  for (int o = 0; o < 20; o++) acc[o] = 0.f;
  int Ci = Ci1 + Ci2;
  size_t in_sp = (size_t)Ti * Xi * Yi * Zi;
  for (int ci = 0; ci < Ci; ci++) {
    const float* base = (ci < Ci1) ? in1 + ((size_t)b * Ci1 + ci) * in_sp
                                   : in2 + ((size_t)b * Ci2 + (ci - Ci1)) * in_sp;
    const float* wc = W + (size_t)ci * 81;
    for (int kt = 0; kt < 3; kt++) {
      int t = to * stride + kt - 1; if (t < 0 || t >= Ti) continue;
      for (int kx = 0; kx < 3; kx++) {
        int xx = xo * stride + kx - 1; if (xx < 0 || xx >= Xi) continue;
        for (int ky = 0; ky < 3; ky++) {
          int y = yo * stride + ky - 1; if (y < 0 || y >= Yi) continue;
          for (int kz = 0; kz < 3; kz++) {
            int z = zo * stride + kz - 1; if (z < 0 || z >= Zi) continue;
            float v = base[(((size_t)t * Xi + xx) * Yi + y) * Zi + z];
            int tap = ((kt * 3 + kx) * 3 + ky) * 3 + kz;
#pragma unroll
            for (int o = 0; o < 20; o++) acc[o] += v * wc[(size_t)o * Ci * 81 + tap];
          }
        }
      }
    }
  }
  size_t osp = (size_t)To * Xo * Yo * Zo;
  size_t obase = (size_t)b * 20 * osp + (((size_t)to * Xo + xo) * Yo + yo) * Zo + zo;
#pragma unroll
  for (int o = 0; o < 20; o++) out[obase + (size_t)o * osp] = acc[o];
}

__global__ void k_conv4d_elem(const float* __restrict__ in, const float* __restrict__ W,
                              float* __restrict__ out, int Ci,
                              int Ti, int Xi, int Yi, int Zi,
                              int To, int Xo, int Yo, int Zo, int stride, int n) {
  int idx = blockIdx.x * 256 + threadIdx.x;
  if (idx >= n) return;
  int zo = idx % Zo; int r = idx / Zo;
  int yo = r % Yo; r /= Yo;
  int xo = r % Xo; r /= Xo;
  int to = r % To; r /= To;
  int o = r % 20; int b = r / 20;
  float acc = 0.f;
  size_t in_sp = (size_t)Ti * Xi * Yi * Zi;
  for (int ci = 0; ci < Ci; ci++) {
    const float* base = in + ((size_t)b * Ci + ci) * in_sp;
    const float* wc = W + ((size_t)o * Ci + ci) * 81;
    for (int kt = 0; kt < 3; kt++) {
      int t = to * stride + kt - 1; if (t < 0 || t >= Ti) continue;
      for (int kx = 0; kx < 3; kx++) {
        int xx = xo * stride + kx - 1; if (xx < 0 || xx >= Xi) continue;
        for (int ky = 0; ky < 3; ky++) {
          int y = yo * stride + ky - 1; if (y < 0 || y >= Yi) continue;
          for (int kz = 0; kz < 3; kz++) {
            int z = zo * stride + kz - 1; if (z < 0 || z >= Zi) continue;
            acc += base[(((size_t)t * Xi + xx) * Yi + y) * Zi + z] * wc[((kt * 3 + kx) * 3 + ky) * 3 + kz];
          }
        }
      }
    }
  }
  out[idx] = acc;
}

// ---------------- BN ----------------
__global__ void k_bn_stats(const float* __restrict__ d, int S, float* __restrict__ stats) {
  int c = blockIdx.x;
  int tid = threadIdx.x;
  float s = 0.f, s2 = 0.f;
  for (int b = 0; b < 4; b++) {
    const float* p = d + ((size_t)b * 20 + c) * S;
    for (int i = tid; i < S; i += 256) { float v = p[i]; s += v; s2 += v * v; }
  }
  __shared__ float ls[256], lq[256];
  ls[tid] = s; lq[tid] = s2;
  __syncthreads();
  for (int off = 128; off > 0; off >>= 1) {
    if (tid < off) { ls[tid] += ls[tid + off]; lq[tid] += lq[tid + off]; }
    __syncthreads();
  }
  if (tid == 0) {
    float cnt = 4.f * (float)S;
    float mean = ls[0] / cnt;
    float var = lq[0] / cnt - mean * mean;
    stats[2 * c] = mean;
    stats[2 * c + 1] = rsqrtf(var + 1e-5f);
  }
}

__global__ void k_bn_apply(float* __restrict__ d, int S, const float* __restrict__ stats,
                           const float* __restrict__ g, const float* __restrict__ bb, int n) {
  int idx = blockIdx.x * 256 + threadIdx.x;
  if (idx >= n) return;
  int c = (idx / S) % 20;
  float v = d[idx];
  v = (v - stats[2 * c]) * stats[2 * c + 1] * g[c] + bb[c];
  d[idx] = (v >= 0.f) ? v : 0.1f * v;
}

// BN apply for oc1 + bf16 channels-last copy into CLd0 ci 0..19
__global__ void k_bn_apply_cl(float* __restrict__ d, const float* __restrict__ stats,
                              const float* __restrict__ g, const float* __restrict__ bb,
                              short* __restrict__ CL, int n) {
  int idx = blockIdx.x * 256 + threadIdx.x;
  if (idx >= n) return;
  int s = idx & 16383;
  int r = idx >> 14;
  int c = r % 20, b = r / 20;
  float v = d[idx];
  v = (v - stats[2 * c]) * stats[2 * c + 1] * g[c] + bb[c];
  v = (v >= 0.f) ? v : 0.1f * v;
  d[idx] = v;
  CL[((size_t)(b * 16384 + s)) * 40 + c] = f2bf(v);
}

// ---------------- deconv (ConvTranspose4d k=4 s=2 p=1), bias+lrelu fused ----------------
__device__ __forceinline__ int dcands(int p, int n_in, int* q, int* k) {
  int cnt = 0;
  int q0 = (p + 1) >> 1, k0 = p + 1 - 2 * q0;
  if (q0 >= 0 && q0 < n_in) { q[cnt] = q0; k[cnt] = k0; cnt++; }
  int q1 = q0 - 1, k1 = k0 + 2;
  if (q1 >= 0 && q1 < n_in) { q[cnt] = q1; k[cnt] = k1; cnt++; }
  return cnt;
}

__global__ void k_deconv4d(const float* __restrict__ in1, int Ci1,
                           const float* __restrict__ in2, int Ci2,
                           const float* __restrict__ W, const float* __restrict__ bias,
                           float* __restrict__ out,
                           int Ti, int Xi, int Yi, int Zi, int n) {
  int idx = blockIdx.x * 256 + threadIdx.x;
  if (idx >= n) return;
  int To = 2 * Ti, Xo = 2 * Xi, Yo = 2 * Yi, Zo = 2 * Zi;
  int zo = idx % Zo; int r = idx / Zo;
  int yo = r % Yo; r /= Yo;
  int xo = r % Xo; r /= Xo;
  int to = r % To; int b = r / To;
  int qt[2], kt[2], qx[2], kx[2], qy[2], ky[2], qz[2], kz[2];
  int nt = dcands(to, Ti, qt, kt), nx = dcands(xo, Xi, qx, kx);
  int ny = dcands(yo, Yi, qy, ky), nz = dcands(zo, Zi, qz, kz);
  float acc[20];
#pragma unroll
  for (int o = 0; o < 20; o++) acc[o] = 0.f;
  int Ci = Ci1 + Ci2;
  size_t in_sp = (size_t)Ti * Xi * Yi * Zi;
  for (int ci = 0; ci < Ci; ci++) {
    const float* base = (ci < Ci1) ? in1 + ((size_t)b * Ci1 + ci) * in_sp
                                   : in2 + ((size_t)b * Ci2 + (ci - Ci1)) * in_sp;
    const float* wc = W + (size_t)ci * 5120;  // [ci][o(20)][256]
    for (int it = 0; it < nt; it++)
      for (int ix = 0; ix < nx; ix++)
        for (int iy = 0; iy < ny; iy++)
          for (int iz = 0; iz < nz; iz++) {
            float v = base[(((size_t)qt[it] * Xi + qx[ix]) * Yi + qy[iy]) * Zi + qz[iz]];
            int tap = ((kt[it] * 4 + kx[ix]) * 4 + ky[iy]) * 4 + kz[iz];
#pragma unroll
            for (int o = 0; o < 20; o++) acc[o] += v * wc[o * 256 + tap];
          }
  }
  size_t osp = (size_t)To * Xo * Yo * Zo;
  size_t obase = (size_t)b * 20 * osp + (((size_t)to * Xo + xo) * Yo + yo) * Zo + zo;
#pragma unroll
  for (int o = 0; o < 20; o++) {
    float v2 = acc[o] + bias[o];
    out[obase + (size_t)o * osp] = (v2 >= 0.f) ? v2 : 0.1f * v2;
  }
}

// d1 deconv: in 4x8x8x4 (oc2|od2, Ci=40) -> out 8x16x16x8 written bf16 CL ci 20..39
__global__ void k_deconv_d1_cl(const float* __restrict__ in1, const float* __restrict__ in2,
                               const float* __restrict__ W, const float* __restrict__ bias,
                               short* __restrict__ CL, int n) {
  int idx = blockIdx.x * 256 + threadIdx.x;
  if (idx >= n) return;
  int zo = idx & 7; int r = idx >> 3;
  int yo = r & 15; r >>= 4;
  int xo = r & 15; r >>= 4;
  int to = r & 7; int b = r >> 3;
  int qt[2], kt[2], qx[2], kx[2], qy[2], ky[2], qz[2], kz[2];
  int nt = dcands(to, 4, qt, kt), nx = dcands(xo, 8, qx, kx);
  int ny = dcands(yo, 8, qy, ky), nz = dcands(zo, 4, qz, kz);
  float acc[20];
#pragma unroll
  for (int o = 0; o < 20; o++) acc[o] = 0.f;
  const size_t in_sp = 4 * 8 * 8 * 4;
  for (int ci = 0; ci < 40; ci++) {
    const float* base = (ci < 20) ? in1 + ((size_t)b * 20 + ci) * in_sp
                                  : in2 + ((size_t)b * 20 + (ci - 20)) * in_sp;
    const float* wc = W + (size_t)ci * 5120;
    for (int it = 0; it < nt; it++)
      for (int ix = 0; ix < nx; ix++)
        for (int iy = 0; iy < ny; iy++)
          for (int iz = 0; iz < nz; iz++) {
            float v = base[(((size_t)qt[it] * 8 + qx[ix]) * 8 + qy[iy]) * 4 + qz[iz]];
            int tap = ((kt[it] * 4 + kx[ix]) * 4 + ky[iy]) * 4 + kz[iz];
#pragma unroll
            for (int o = 0; o < 20; o++) acc[o] += v * wc[o * 256 + tap];
          }
  }
  size_t pos = (((size_t)b * 8 + to) * 16 + xo) * 16 * 8 + (size_t)yo * 8 + zo;
  short* dst = CL + pos * 40 + 20;
#pragma unroll
  for (int o = 0; o < 20; o++) {
    float v2 = acc[o] + bias[o];
    v2 = (v2 >= 0.f) ? v2 : 0.1f * v2;
    dst[o] = f2bf(v2);
  }
}

// fill Xcl ci 0..19 from x
__global__ void k_xcl_x(const float* __restrict__ x, short* __restrict__ Xcl, int n) {
  int i = blockIdx.x * 256 + threadIdx.x;
  if (i >= n) return;
  int s = i & 262143, b = i >> 18;
  short* dst = Xcl + (size_t)i * 40;
  const float* src = x + (size_t)b * 20 * 262144 + s;
#pragma unroll
  for (int c = 0; c < 20; c++) dst[c] = f2bf(src[(size_t)c * 262144]);
}

// pack out_w [20][40][81] + w_pw [20][20] -> Wp[tap(82)][mt(2)][m(16)][k(64)] bf16 + zero-page
// tap 81 = pointwise (x2) weights.
__global__ void k_pack_w(const float* __restrict__ out_w, const float* __restrict__ w_pw,
                         short* __restrict__ Wp, short* __restrict__ zp, int n) {
  int i = blockIdx.x * 256 + threadIdx.x;
  if (i >= n) return;
  int k = i & 63, m = (i >> 6) & 15, mt = (i >> 10) & 1, tap = i >> 11;
  int o = mt * 16 + m;
  float v = 0.f;
  if (o < 20 && k < 40) {
    if (tap < 81) v = out_w[((size_t)o * 40 + k) * 81 + tap];
    else if (k < 20) v = w_pw[o * 20 + k];
  }
  Wp[i] = f2bf(v);
  if (i < 64) zp[i] = 0;
}

// pack d0_w [40][20][256] -> Wd parity-class-major:
// [h(32)=cls*2+it][sub(8)=ix*4+iz*2+iy][mt(2)][m(16)][k(64)] bf16,
// bank-swizzled: element index i -> i ^ ((m&7)<<3)  (byte ^ ((row&7)<<4)).
__global__ void k_pack_wd(const float* __restrict__ d0_w, short* __restrict__ Wd, int n) {
  int i = blockIdx.x * 256 + threadIdx.x;
  if (i >= n) return;
  int k = i & 63, m = (i >> 6) & 15, mt = (i >> 10) & 1, sub = (i >> 11) & 7, h = i >> 14;
  int it = h & 1, cls = h >> 1;
  int ez = cls & 1, ey = (cls >> 1) & 1, ex = (cls >> 2) & 1, et = (cls >> 3) & 1;
  int iy = sub & 1, iz = (sub >> 1) & 1, ix = (sub >> 2) & 1;
  int kt = et ? (2 * it) : (1 + 2 * it);
  int kx = ex ? (2 * ix) : (1 + 2 * ix);
  int ky = ey ? (2 * iy) : (1 + 2 * iy);
  int kz = ez ? (2 * iz) : (1 + 2 * iz);
  int tap = ((kt * 4 + kx) * 4 + ky) * 4 + kz;
  int o = mt * 16 + m;
  float v = (o < 20 && k < 40) ? d0_w[((size_t)k * 20 + o) * 256 + tap] : 0.f;
  Wd[i ^ ((m & 7) << 3)] = f2bf(v);
}

// ---------------- d0 deconv via MFMA (parity-class, LDS-staged) ----------------
// Block = (b, ut, ux): 512 threads = 8 waves, wave = uz. B working set = 9 (qt,qx)
// y-z planes x 10240B staged once into LDS (bank-swizzled via pre-swizzled global src).
// A (weights) staged per half-class phase (32KB contiguous, pre-swizzled pack),
// double-buffered: stage h+1 overlaps compute h. All operand reads are ds_read_b128.
__global__ __launch_bounds__(512) void k_d0_mfma(
    const short* __restrict__ CLd0, const short* __restrict__ Wd,
    const float* __restrict__ bias, short* __restrict__ Xcl) {
  __shared__ __align__(16) char lds[157696];  // 9*10240 B-planes + 2*32768 A dbuf
  char* lds_a = lds + 92160;
  int bid = blockIdx.x;
  int ux = bid & 15, ut = (bid >> 4) & 7, b = bid >> 7;
  int tid = threadIdx.x;
  int uz = tid >> 6;
  int lane = tid & 63, ln15 = lane & 15, kg = lane >> 4;  // ln15 = uy

  const char* xb = (const char*)CLd0;
  const char* wb = (const char*)Wd;

  auto gld = [](const char* src, char* dst) {
    __builtin_amdgcn_global_load_lds(
        (const __attribute__((address_space(1))) void*)src,
        (__attribute__((address_space(3))) void*)dst, 16, 0, 0);
  };

  // ---- prologue: stage B planes (swizzle baked into per-lane global src) ----
#pragma unroll
  for (int pt = 0; pt < 3; pt++) {
    int qt = ut - 1 + pt;
    if (qt < 0 || qt > 7) continue;
#pragma unroll
    for (int px = 0; px < 3; px++) {
      int qx = ux - 1 + px;
      if (qx < 0 || qx > 15) continue;
      const char* src = xb + (size_t)((b * 8 + qt) * 16 + qx) * 10240;
      char* dst = lds + (pt * 3 + px) * 10240;
      for (int g = tid; g < 640; g += 512) {
        int key = ((g / 40) & 7) << 4;
        gld(src + ((g * 16) ^ key), dst + g * 16);
      }
    }
  }
  // stage A half-block h=0 (pack is pre-swizzled -> linear copy)
  for (int g = tid; g < 2048; g += 512) gld(wb + g * 16, lds_a + g * 16);
  asm volatile("s_waitcnt vmcnt(0)" ::: "memory");
  __syncthreads();

  bf16x8 zv = {0, 0, 0, 0, 0, 0, 0, 0};
  int aswz = ((ln15 * 128 + kg * 16) ^ ((ln15 & 7) << 4));

#pragma unroll 1
  for (int cls = 0; cls < 16; cls++) {
    int ez = cls & 1, ey = (cls >> 1) & 1, ex = (cls >> 2) & 1, et = (cls >> 3) & 1;
    f32x4 acc0, acc1;
#pragma unroll
    for (int j = 0; j < 4; j++) { acc0[j] = 0.f; acc1[j] = 0.f; }
#pragma unroll
    for (int it = 0; it < 2; it++) {
      int h = cls * 2 + it;
      // stage next A half-block into the other buffer
      if (h + 1 < 32) {
        const char* asrc = wb + (size_t)(h + 1) * 32768;
        char* adst = lds_a + (it ^ 1) * 32768;
        for (int g = tid; g < 2048; g += 512) gld(asrc + g * 16, adst + g * 16);
      }
      const char* ab = lds_a + it * 32768;
      int kt_q = ut + (et ? (1 - it) : (-it));
      if (kt_q >= 0 && kt_q <= 7) {
        int pt = kt_q - ut + 1;
#pragma unroll
        for (int ix = 0; ix < 2; ix++) {
          int qx = ux + (ex ? (1 - ix) : (-ix));
          if (qx < 0 || qx > 15) continue;
          int px = qx - ux + 1;
          const char* pbase = lds + (pt * 3 + px) * 10240;
#pragma unroll
          for (int iz = 0; iz < 2; iz++) {
            int qz = uz + (ez ? (1 - iz) : (-iz));
            if (qz < 0 || qz > 7) continue;
#pragma unroll
            for (int iy = 0; iy < 2; iy++) {
              int qy = ln15 + (ey ? (1 - iy) : (-iy));
              bool yok = (qy >= 0) && (qy < 16);
              int qyc = yok ? qy : 0;
              int bkey = (qyc & 7) << 4;
              const char* abase = ab + (ix * 4 + iz * 2 + iy) * 4096;
#pragma unroll
              for (int ch = 0; ch < 2; ch++) {
                int co = ch ? 64 : kg * 16;  // ch=1: broadcast ci 32..39 (k>=40 wts are 0)
                int boff = (qyc * 640 + qz * 80 + co) ^ bkey;
                bf16x8 bvv = *(const bf16x8*)(pbase + boff);
                bf16x8 bv = yok ? bvv : zv;
                int aoff = (ch ? (aswz ^ 64) : aswz);
                bf16x8 a0 = *(const bf16x8*)(abase + aoff);
                bf16x8 a1 = *(const bf16x8*)(abase + 2048 + aoff);
                acc0 = __builtin_amdgcn_mfma_f32_16x16x32_bf16(a0, bv, acc0, 0, 0, 0);
                acc1 = __builtin_amdgcn_mfma_f32_16x16x32_bf16(a1, bv, acc1, 0, 0, 0);
              }
            }
          }
        }
      }
      asm volatile("s_waitcnt vmcnt(0)" ::: "memory");
      __syncthreads();
    }
    int to = 2 * ut + et, xo = 2 * ux + ex, zo = 2 * uz + ez, yo = 2 * ln15 + ey;
    long opos = ((((long)b * 16 + to) * 32 + xo) * 32 + yo) * 16 + zo;
    short* dst = Xcl + opos * 40 + 20;
    {
      unsigned hh[4];
#pragma unroll
      for (int r = 0; r < 4; r++) {
        float v = acc0[r] + bias[kg * 4 + r];
        v = (v >= 0.f) ? v : 0.1f * v;
        hh[r] = (unsigned)(unsigned short)f2bf(v);
      }
      uint2 u;
      u.x = hh[0] | (hh[1] << 16);
      u.y = hh[2] | (hh[3] << 16);
      *(uint2*)(dst + kg * 4) = u;
    }
    if (kg == 0) {
      unsigned hh[4];
#pragma unroll
      for (int r = 0; r < 4; r++) {
        float v = acc1[r] + bias[16 + r];
        v = (v >= 0.f) ? v : 0.1f * v;
        hh[r] = (unsigned)(unsigned short)f2bf(v);
      }
      uint2 u;
      u.x = hh[0] | (hh[1] << 16);
      u.y = hh[2] | (hh[3] << 16);
      *(uint2*)(dst + 16) = u;
    }
  }
}

// ---------------- final conv: LDS-staged bf16 MFMA implicit GEMM ----------------
__global__ __launch_bounds__(512, 4) void k_fconv_mfma(
    const short* __restrict__ Xcl, const short* __restrict__ Wp,
    const float* __restrict__ bias, const float* __restrict__ bpw,
    float* __restrict__ io) {
  __shared__ __align__(16) char lds[2][40960];  // 81920 B: exactly 2 blocks/CU
  int bid = blockIdx.x;
  int xcd = bid & 7, idx = bid >> 3;
  int b = xcd >> 1, xh = xcd & 1;
  // t0-major within each XCD: working set 3 xi-slabs x 16 ti x 40KB ~ 1.9MB < 4MB L2
  int t0 = idx & 15, x0 = xh * 16 + ((idx >> 4) & 15);
  int tid = threadIdx.x;
  int lane = tid & 63;
  int ln15 = lane & 15, kg = lane >> 4;
  int ybase = (tid >> 6) * 4;

  // valid (kt,kx) slab list, 4 bits per entry (code = kt*4+kx; center = 5)
  unsigned long long codes = 0ull;
  int ns = 0;
  for (int kt = 0; kt < 3; kt++) {
    int ti = t0 + kt - 1;
    if (ti < 0 || ti > 15) continue;
    for (int kx = 0; kx < 3; kx++) {
      int xi = x0 + kx - 1;
      if (xi < 0 || xi > 31) continue;
      codes |= (unsigned long long)(kt * 4 + kx) << (4 * ns);
      ns++;
    }
  }

  const char* xb = (const char*)Xcl;
  const char* wb = (const char*)Wp;

  auto stage = [&](char* dst, int code) {
    int ti = t0 + (code >> 2) - 1, xi = x0 + (code & 3) - 1;
    const char* src = xb + (size_t)((b * 16 + ti) * 32 + xi) * 512 * 80;
#pragma unroll
    for (int s = 0; s < 5; s++) {
      int off = s * 8192 + tid * 16;
      __builtin_amdgcn_global_load_lds(
          (const __attribute__((address_space(1))) void*)(src + off),
          (__attribute__((address_space(3))) void*)(dst + off), 16, 0, 0);
    }
  };

  f32x4 acc[2][4];
#pragma unroll
  for (int mt = 0; mt < 2; mt++)
#pragma unroll
    for (int nt = 0; nt < 4; nt++)
#pragma unroll
      for (int j = 0; j < 4; j++) acc[mt][nt][j] = 0.f;

  stage(lds[0], (int)(codes & 15));
  asm volatile("s_waitcnt vmcnt(0)" ::: "memory");
  __syncthreads();

  int cur = 0;
#pragma unroll 1
  for (int i = 0; i < ns; i++) {
    const char* bufc = lds[cur];
    if (i + 1 < ns) stage(lds[cur ^ 1], (int)((codes >> (4 * (i + 1))) & 15));
    int code = (int)((codes >> (4 * i)) & 15);
    int kt = code >> 2, kx = code & 3;
    bf16x8 zv = {0, 0, 0, 0, 0, 0, 0, 0};
#pragma unroll
    for (int kz = 0; kz < 3; kz++) {
      int zi = ln15 + kz - 1;
      bool zok = (zi >= 0) && (zi < 16);
      int zc = zok ? zi : 0;
#pragma unroll
      for (int ch = 0; ch < 2; ch++) {
        int co = ch ? 64 : kg * 16;  // ch=1: broadcast ci 32..39 chunk to all kg
        bf16x8 bv[6];
#pragma unroll
        for (int j = 0; j < 6; j++) {
          int yi = ybase + j - 1;
          int yc = (yi < 0) ? 0 : ((yi > 31) ? 31 : yi);
          bf16x8 v = *(const bf16x8*)(bufc + (size_t)(yc * 16 + zc) * 80 + co);
          bool ok = zok && (yi >= 0) && (yi < 32);
          bv[j] = ok ? v : zv;
        }
        bf16x8 av[3][2];
#pragma unroll
        for (int ky = 0; ky < 3; ky++) {
          int tap = ((kt * 3 + kx) * 3 + ky) * 3 + kz;
          const char* wt = wb + (size_t)tap * 4096 + ln15 * 128 + ch * 64 + kg * 16;
          av[ky][0] = *(const bf16x8*)wt;
          av[ky][1] = *(const bf16x8*)(wt + 2048);
        }
#pragma unroll
        for (int ky = 0; ky < 3; ky++)
#pragma unroll
          for (int nt = 0; nt < 4; nt++) {
            acc[0][nt] = __builtin_amdgcn_mfma_f32_16x16x32_bf16(av[ky][0], bv[nt + ky], acc[0][nt], 0, 0, 0);
            acc[1][nt] = __builtin_amdgcn_mfma_f32_16x16x32_bf16(av[ky][1], bv[nt + ky], acc[1][nt], 0, 0, 0);
          }
      }
    }
    if (code == 5) {
      // center slab: fused pointwise (x2) tap, ci 0..19 (weights zero for k>=20)
      const char* wt = wb + (size_t)81 * 4096 + ln15 * 128 + kg * 16;
      bf16x8 a0 = *(const bf16x8*)wt;
      bf16x8 a1 = *(const bf16x8*)(wt + 2048);
#pragma unroll
      for (int nt = 0; nt < 4; nt++) {
        bf16x8 bv = *(const bf16x8*)(bufc + (size_t)((ybase + nt) * 16 + ln15) * 80 + kg * 16);
        acc[0][nt] = __builtin_amdgcn_mfma_f32_16x16x32_bf16(a0, bv, acc[0][nt], 0, 0, 0);
        acc[1][nt] = __builtin_amdgcn_mfma_f32_16x16x32_bf16(a1, bv, acc[1][nt], 0, 0, 0);
      }
    }
    asm volatile("s_waitcnt vmcnt(0)" ::: "memory");
    __syncthreads();
    cur ^= 1;
  }

#pragma unroll
  for (int mt = 0; mt < 2; mt++)
#pragma unroll
    for (int r = 0; r < 4; r++) {
      int o = mt * 16 + kg * 4 + r;
      if (o >= 20) continue;
      float bo = bias[o] + bpw[o];
#pragma unroll
      for (int nt = 0; nt < 4; nt++) {
        int y = ybase + nt;
        size_t oidx = ((size_t)(b * 20 + o)) * 262144 +
                      ((((size_t)t0 * 32 + x0) * 32 + y) * 16 + ln15);
        float v = acc[mt][nt][r] + bo + io[oidx];
        io[oidx] = fmaxf(v, 0.f);
      }
    }
}

extern "C" void kernel_launch(void* const* d_in, const int* in_sizes, int n_in,
                              void* d_out, int out_size, void* d_ws, size_t ws_size,
                              hipStream_t stream) {
  const float* x     = (const float*)d_in[0];
  const float* sw1   = (const float*)d_in[1];
  const float* sw2   = (const float*)d_in[2];
  const float* sw3   = (const float*)d_in[3];
  const float* sw4   = (const float*)d_in[4];
  const float* w_pw  = (const float*)d_in[5];
  const float* b_pw  = (const float*)d_in[6];
  const float* c1_w  = (const float*)d_in[7];
  const float* c2_w  = (const float*)d_in[8];
  const float* c21_w = (const float*)d_in[9];
  const float* c3_w  = (const float*)d_in[10];
  const float* c31_w = (const float*)d_in[11];
  const float* bn1_g = (const float*)d_in[12];
  const float* bn1_b = (const float*)d_in[13];
  const float* bn2_g = (const float*)d_in[14];
  const float* bn2_b = (const float*)d_in[15];
  const float* bn21_g = (const float*)d_in[16];
  const float* bn21_b = (const float*)d_in[17];
  const float* bn3_g = (const float*)d_in[18];
  const float* bn3_b = (const float*)d_in[19];
  const float* bn31_g = (const float*)d_in[20];
  const float* bn31_b = (const float*)d_in[21];
  const float* d2_w  = (const float*)d_in[22];
  const float* d2_b  = (const float*)d_in[23];
  const float* d1_w  = (const float*)d_in[24];
  const float* d1_b  = (const float*)d_in[25];
  const float* d0_w  = (const float*)d_in[26];
  const float* d0_b  = (const float*)d_in[27];
  const float* out_w = (const float*)d_in[28];
  const float* out_b = (const float*)d_in[29];
  float* out = (float*)d_out;
  float* ws = (float*)d_ws;

  // spectral arena (phase 1 only)
  float2* A  = (float2*)(ws);
  float2* Bb = (float2*)(ws + 10485760);
  float2* Cb = (float2*)(ws + 13107200);
  float2* Dd = (float2*)(ws + 14417920);
  float2* Ee = (float2*)(ws + 15073280);
  float2* Ff = (float2*)(ws + 15728640);
  float2* Gg = (float2*)(ws + 16384000);
  // twiddle tables: live only during spectral phase; region inside Xcl span,
  // beyond the spectral arena end (17,039,360 fl), overwritten later by k_xcl_x.
  float2* Twid = (float2*)(ws + 23000000);

  // U-Net arena
  float* oc1   = ws;
  short* CLd0  = (short*)(ws + 1310720);
  float* oc2a  = ws + 2621440;
  float* oc2   = ws + 2703360;
  float* oc3a  = ws + 2785280;
  float* oc3   = ws + 2790400;
  float* od2   = ws + 2795520;
  short* Xcl   = (short*)(ws + 2877440);
  float* stats = ws + 23848960;
  short* Wd = (short*)(ws);
  short* Wp = (short*)(ws + 262144);
  short* zp = (short*)(ws + 349184);

  auto nb = [](int n) { return (n + 255) / 256; };
  dim3 blk(256);

  // ---- twiddle tables ----
  k_twid<<<1, 64, 0, stream>>>(Twid);

  // ---- spectral path: x1 -> d_out ----
  k_fwd_z<<<nb(1310720), blk, 0, stream>>>(x, Twid, A, 1310720);
  k_fwd_y<<<nb(1310720), blk, 0, stream>>>(A, Twid, Bb, 1310720);
  k_fwd_x<<<nb(655360), blk, 0, stream>>>(Bb, Twid, Cb, 655360);
  k_fwd_t<<<nb(327680), blk, 0, stream>>>(Cb, Twid, Dd, 327680);
  k_fwd_c<<<nb(327680), blk, 0, stream>>>(Dd, Twid, Ee, 327680);
  k_fwd_b<<<nb(327680), blk, 0, stream>>>(Ee, Twid, Ff, 327680);
  k_smul<<<nb(327680), blk, 0, stream>>>(Ff, sw1, sw2, sw3, sw4, Gg, 327680);
  k_inv_t<<<nb(655360), blk, 0, stream>>>(Gg, Twid, Cb, 655360);
  k_inv_x<<<nb(1310720), blk, 0, stream>>>(Cb, Twid, Bb, 1310720);
  k_inv_yz<<<nb(1310720), blk, 0, stream>>>(Bb, Twid, out, 1310720);

  // ---- Xcl ci 0..19 from x ----
  k_xcl_x<<<nb(1048576), blk, 0, stream>>>(x, Xcl, 1048576);

  // ---- U-Net encoder ----
  k_conv4d_pos<<<nb(65536), blk, 0, stream>>>(x, 20, nullptr, 0, c1_w, oc1,
                                              16, 32, 32, 16, 8, 16, 16, 8, 2, 65536);
  k_bn_stats<<<20, blk, 0, stream>>>(oc1, 16384, stats);
  k_bn_apply_cl<<<nb(1310720), blk, 0, stream>>>(oc1, stats, bn1_g, bn1_b, CLd0, 1310720);

  k_conv4d_elem<<<nb(81920), blk, 0, stream>>>(oc1, c2_w, oc2a, 20,
                                               8, 16, 16, 8, 4, 8, 8, 4, 2, 81920);
  k_bn_stats<<<20, blk, 0, stream>>>(oc2a, 1024, stats);
  k_bn_apply<<<nb(81920), blk, 0, stream>>>(oc2a, 1024, stats, bn2_g, bn2_b, 81920);

  k_conv4d_elem<<<nb(81920), blk, 0, stream>>>(oc2a, c21_w, oc2, 20,
                                               4, 8, 8, 4, 4, 8, 8, 4, 1, 81920);
  k_bn_stats<<<20, blk, 0, stream>>>(oc2, 1024, stats);
  k_bn_apply<<<nb(81920), blk, 0, stream>>>(oc2, 1024, stats, bn21_g, bn21_b, 81920);

  k_conv4d_elem<<<nb(5120), blk, 0, stream>>>(oc2, c3_w, oc3a, 20,
                                              4, 8, 8, 4, 2, 4, 4, 2, 2, 5120);
  k_bn_stats<<<20, blk, 0, stream>>>(oc3a, 64, stats);
  k_bn_apply<<<nb(5120), blk, 0, stream>>>(oc3a, 64, stats, bn3_g, bn3_b, 5120);

  k_conv4d_elem<<<nb(5120), blk, 0, stream>>>(oc3a, c31_w, oc3, 20,
                                              2, 4, 4, 2, 2, 4, 4, 2, 1, 5120);
  k_bn_stats<<<20, blk, 0, stream>>>(oc3, 64, stats);
  k_bn_apply<<<nb(5120), blk, 0, stream>>>(oc3, 64, stats, bn31_g, bn31_b, 5120);

  // ---- decoder ----
  k_deconv4d<<<nb(4096), blk, 0, stream>>>(oc3, 20, nullptr, 0, d2_w, d2_b, od2,
                                           2, 4, 4, 2, 4096);
  k_deconv_d1_cl<<<nb(65536), blk, 0, stream>>>(oc2, od2, d1_w, d1_b, CLd0, 65536);

  // weight packs
  k_pack_w<<<nb(167936), blk, 0, stream>>>(out_w, w_pw, Wp, zp, 167936);
  k_pack_wd<<<nb(524288), blk, 0, stream>>>(d0_w, Wd, 524288);

  // d0 deconv via MFMA (LDS-staged) -> Xcl ci 20..39
  k_d0_mfma<<<512, dim3(512), 0, stream>>>(CLd0, Wd, d0_b, Xcl);

  // final conv via MFMA (LDS-staged), fused +bias +x1 +x2(pointwise) +relu into d_out
  k_fconv_mfma<<<2048, dim3(512), 0, stream>>>(Xcl, Wp, out_b, b_pw, out);
}

// Round 3
// 2495.301 us; speedup vs baseline: 1.3620x; 1.1107x over previous
//
#include <hip/hip_runtime.h>

#define PI2 6.28318530717958647692f

typedef __attribute__((ext_vector_type(8))) short bf16x8;
typedef __attribute__((ext_vector_type(4))) float f32x4;

__device__ __forceinline__ void cfma(float2& acc, float2 a, float2 t) {
  acc.x += a.x * t.x - a.y * t.y;
  acc.y += a.x * t.y + a.y * t.x;
}
// multiply by conj(t) (inverse twiddle), t = e^{-i\theta}
__device__ __forceinline__ void cfmac(float2& acc, float2 a, float2 t) {
  acc.x += a.x * t.x + a.y * t.y;
  acc.y += a.y * t.x - a.x * t.y;
}

__device__ __forceinline__ short f2bf(float f) {
  unsigned u = __float_as_uint(f);
  unsigned r = (u + 0x7fff + ((u >> 16) & 1)) >> 16;
  return (short)r;
}

// twiddle tables: T[0..31]=e^{-2pi i m/32}, T[32..47]=N16, T[48..67]=N20, T[68..71]=N4
__global__ void k_twid(float2* __restrict__ T) {
  int i = threadIdx.x;
  float s, c;
  if (i < 32) { __sincosf(-PI2 * (float)i / 32.f, &s, &c); T[i] = make_float2(c, s); }
  if (i < 16) { __sincosf(-PI2 * (float)i / 16.f, &s, &c); T[32 + i] = make_float2(c, s); }
  if (i < 20) { __sincosf(-PI2 * (float)i / 20.f, &s, &c); T[48 + i] = make_float2(c, s); }
  if (i < 4)  { __sincosf(-PI2 * (float)i / 4.f,  &s, &c); T[68 + i] = make_float2(c, s); }
}

// ---------------- spectral forward ----------------
__global__ void k_fwd_z(const float* __restrict__ x, const float2* __restrict__ T,
                        float2* __restrict__ out, int nrows) {
  __shared__ float2 tw[16];
  if (threadIdx.x < 16) tw[threadIdx.x] = T[32 + threadIdx.x];
  __syncthreads();
  int r = blockIdx.x * 256 + threadIdx.x;
  if (r >= nrows) return;
  const float* p = x + (size_t)r * 16;
  float v[16];
#pragma unroll
  for (int z = 0; z < 16; z++) v[z] = p[z];
#pragma unroll
  for (int zk = 0; zk < 4; zk++) {
    float re = 0.f, im = 0.f;
#pragma unroll
    for (int z = 0; z < 16; z++) {
      float2 t = tw[(z * zk) & 15];
      re += v[z] * t.x;
      im += v[z] * t.y;
    }
    out[(size_t)r * 4 + zk] = make_float2(re, im);
  }
}

__global__ void k_fwd_y(const float2* __restrict__ in, const float2* __restrict__ T,
                        float2* __restrict__ out, int n) {
  __shared__ float2 tw[32];
  if (threadIdx.x < 32) tw[threadIdx.x] = T[threadIdx.x];
  __syncthreads();
  int i = blockIdx.x * 256 + threadIdx.x;
  if (i >= n) return;
  int zk = i & 3, yk = (i >> 2) & 7, slab = i >> 5;
  const float2* p = in + (size_t)slab * 128 + zk;
  float2 acc = make_float2(0.f, 0.f);
  for (int y = 0; y < 32; y++) cfma(acc, p[y * 4], tw[(y * yk) & 31]);
  out[i] = acc;
}

__global__ void k_fwd_x(const float2* __restrict__ in, const float2* __restrict__ T,
                        float2* __restrict__ out, int n) {
  __shared__ float2 tw[32];
  if (threadIdx.x < 32) tw[threadIdx.x] = T[threadIdx.x];
  __syncthreads();
  int i = blockIdx.x * 256 + threadIdx.x;
  if (i >= n) return;
  int zk = i & 3, yk = (i >> 2) & 7, xi = (i >> 5) & 15, slab = i >> 9;
  int xk = (xi < 8) ? xi : xi + 16;
  const float2* p = in + (size_t)slab * 1024 + yk * 4 + zk;
  float2 acc = make_float2(0.f, 0.f);
  for (int xx = 0; xx < 32; xx++) cfma(acc, p[xx * 32], tw[(xx * xk) & 31]);
  out[i] = acc;
}

__global__ void k_fwd_t(const float2* __restrict__ in, const float2* __restrict__ T,
                        float2* __restrict__ out, int n) {
  __shared__ float2 tw[16];
  if (threadIdx.x < 16) tw[threadIdx.x] = T[32 + threadIdx.x];
  __syncthreads();
  int i = blockIdx.x * 256 + threadIdx.x;
  if (i >= n) return;
  int zk = i & 3, yk = (i >> 2) & 7, xi = (i >> 5) & 15, ti = (i >> 9) & 7, bc = i >> 12;
  int tk = (ti < 4) ? ti : ti + 8;
  const float2* p = in + (size_t)bc * 8192 + xi * 32 + yk * 4 + zk;
  float2 acc = make_float2(0.f, 0.f);
  for (int t = 0; t < 16; t++) cfma(acc, p[t * 512], tw[(t * tk) & 15]);
  out[i] = acc;
}

__global__ void k_fwd_c(const float2* __restrict__ in, const float2* __restrict__ T,
                        float2* __restrict__ out, int n) {
  __shared__ float2 tw[20];
  if (threadIdx.x < 20) tw[threadIdx.x] = T[48 + threadIdx.x];
  __syncthreads();
  int i = blockIdx.x * 256 + threadIdx.x;
  if (i >= n) return;
  int mode = i & 4095, r = i >> 12, ck = r % 20, b = r / 20;
  const float2* p = in + (size_t)b * 81920 + mode;
  float2 acc = make_float2(0.f, 0.f);
  int idx = 0;
  for (int c = 0; c < 20; c++) {
    cfma(acc, p[(size_t)c * 4096], tw[idx]);
    idx += ck; if (idx >= 20) idx -= 20;
  }
  out[i] = acc;
}

__global__ void k_fwd_b(const float2* __restrict__ in, const float2* __restrict__ T,
                        float2* __restrict__ out, int n) {
  __shared__ float2 tw[4];
  if (threadIdx.x < 4) tw[threadIdx.x] = T[68 + threadIdx.x];
  __syncthreads();
  int i = blockIdx.x * 256 + threadIdx.x;
  if (i >= n) return;
  int mode = i & 4095, r = i >> 12, ck = r % 20, bk = r / 20;
  const float2* p = in + (size_t)ck * 4096 + mode;
  float2 acc = make_float2(0.f, 0.f);
#pragma unroll
  for (int b = 0; b < 4; b++) cfma(acc, p[(size_t)b * 81920], tw[(b * bk) & 3]);
  out[i] = acc;
}

__global__ void k_smul(const float2* __restrict__ in,
                       const float* __restrict__ sw1, const float* __restrict__ sw2,
                       const float* __restrict__ sw3, const float* __restrict__ sw4,
                       float2* __restrict__ out, int n) {
  int i = blockIdx.x * 256 + threadIdx.x;
  if (i >= n) return;
  int mode = i & 4095, r = i >> 12, o = r % 20, bk = r / 20;
  int ti = mode >> 9, xi = (mode >> 5) & 15, yk = (mode >> 2) & 7, zk = mode & 3;
  const float* w = (ti < 4) ? ((xi < 8) ? sw1 : sw3) : ((xi < 8) ? sw2 : sw4);
  int tl = ti & 3, xl = xi & 7;
  const float2* wp = (const float2*)w;
  const float2* ip = in + (size_t)bk * 81920 + mode;
  size_t wsub = (size_t)o * 1024 + (size_t)tl * 256 + (size_t)xl * 32 + yk * 4 + zk;
  float2 acc = make_float2(0.f, 0.f);
  for (int ci = 0; ci < 20; ci++) cfma(acc, ip[(size_t)ci * 4096], wp[(size_t)ci * 20480 + wsub]);
  out[i] = acc;
}

// ---------------- spectral inverse ----------------
__global__ void k_inv_t(const float2* __restrict__ in, const float2* __restrict__ T,
                        float2* __restrict__ out, int n) {
  __shared__ float2 tw[16];
  if (threadIdx.x < 16) tw[threadIdx.x] = T[32 + threadIdx.x];
  __syncthreads();
  int i = blockIdx.x * 256 + threadIdx.x;
  if (i >= n) return;
  int zk = i & 3, yk = (i >> 2) & 7, xi = (i >> 5) & 15, tp = (i >> 9) & 15, bc = i >> 13;
  const float2* p = in + (size_t)bc * 4096 + xi * 32 + yk * 4 + zk;
  float2 acc = make_float2(0.f, 0.f);
#pragma unroll
  for (int ti = 0; ti < 8; ti++) {
    int tk = (ti < 4) ? ti : ti + 8;
    cfmac(acc, p[ti * 512], tw[(tk * tp) & 15]);
  }
  out[i] = acc;
}

__global__ void k_inv_x(const float2* __restrict__ in, const float2* __restrict__ T,
                        float2* __restrict__ out, int n) {
  __shared__ float2 tw[32];
  if (threadIdx.x < 32) tw[threadIdx.x] = T[threadIdx.x];
  __syncthreads();
  int i = blockIdx.x * 256 + threadIdx.x;
  if (i >= n) return;
  int zk = i & 3, yk = (i >> 2) & 7, xp = (i >> 5) & 31, tp = (i >> 10) & 15, bc = i >> 14;
  const float2* p = in + (size_t)bc * 8192 + tp * 512 + yk * 4 + zk;
  float2 acc = make_float2(0.f, 0.f);
#pragma unroll
  for (int xi = 0; xi < 16; xi++) {
    int xk = (xi < 8) ? xi : xi + 16;
    cfmac(acc, p[xi * 32], tw[(xk * xp) & 31]);
  }
  out[i] = acc;
}

// fused inverse-y + c2r-z: thread per (bc,tp,xp,yp), emits full 16-z real row.
__global__ void k_inv_yz(const float2* __restrict__ in, const float2* __restrict__ T,
                         float* __restrict__ out, int n) {
  __shared__ float2 tw[48];  // 0..31: N32, 32..47: N16
  if (threadIdx.x < 48) tw[threadIdx.x] = T[threadIdx.x];
  __syncthreads();
  int i = blockIdx.x * 256 + threadIdx.x;
  if (i >= n) return;
  int yp = i & 31;
  const float2* p = in + (size_t)(i >> 5) * 32;  // [bc][tp][xp] slab: [yk8][zk4]
  float2 Ay[4];
#pragma unroll
  for (int zk = 0; zk < 4; zk++) Ay[zk] = make_float2(0.f, 0.f);
#pragma unroll
  for (int yk = 0; yk < 8; yk++) {
    float2 w = tw[(yk * yp) & 31];
#pragma unroll
    for (int zk = 0; zk < 4; zk++) cfmac(Ay[zk], p[yk * 4 + zk], w);
  }
  float res[16];
#pragma unroll
  for (int zp = 0; zp < 16; zp++) {
    float v = Ay[0].x;
#pragma unroll
    for (int zk = 1; zk < 4; zk++) {
      float2 t = tw[32 + ((zk * zp) & 15)];
      v += 2.f * (Ay[zk].x * t.x + Ay[zk].y * t.y);
    }
    res[zp] = v * (1.f / 262144.f);
  }
  float4* o4 = (float4*)(out + (size_t)i * 16);
#pragma unroll
  for (int q = 0; q < 4; q++)
    o4[q] = make_float4(res[q * 4], res[q * 4 + 1], res[q * 4 + 2], res[q * 4 + 3]);
}

// ---------------- U-Net: convs ----------------
__global__ void k_conv4d_pos(const float* __restrict__ in1, int Ci1,
                             const float* __restrict__ in2, int Ci2,
                             const float* __restrict__ W, float* __restrict__ out,
                             int Ti, int Xi, int Yi, int Zi,
                             int To, int Xo, int Yo, int Zo, int stride, int n) {
  int idx = blockIdx.x * 256 + threadIdx.x;
  if (idx >= n) return;
  int zo = idx % Zo; int r = idx / Zo;
  int yo = r % Yo; r /= Yo;
  int xo = r % Xo; r /= Xo;
  int to = r % To; int b = r / To;
  float acc[20];
#pragma unroll
  for (int o = 0; o < 20; o++) acc[o] = 0.f;
  int Ci = Ci1 + Ci2;
  size_t in_sp = (size_t)Ti * Xi * Yi * Zi;
  for (int ci = 0; ci < Ci; ci++) {
    const float* base = (ci < Ci1) ? in1 + ((size_t)b * Ci1 + ci) * in_sp
                                   : in2 + ((size_t)b * Ci2 + (ci - Ci1)) * in_sp;
    const float* wc = W + (size_t)ci * 81;
    for (int kt = 0; kt < 3; kt++) {
      int t = to * stride + kt - 1; if (t < 0 || t >= Ti) continue;
      for (int kx = 0; kx < 3; kx++) {
        int xx = xo * stride + kx - 1; if (xx < 0 || xx >= Xi) continue;
        for (int ky = 0; ky < 3; ky++) {
          int y = yo * stride + ky - 1; if (y < 0 || y >= Yi) continue;
          for (int kz = 0; kz < 3; kz++) {
            int z = zo * stride + kz - 1; if (z < 0 || z >= Zi) continue;
            float v = base[(((size_t)t * Xi + xx) * Yi + y) * Zi + z];
            int tap = ((kt * 3 + kx) * 3 + ky) * 3 + kz;
#pragma unroll
            for (int o = 0; o < 20; o++) acc[o] += v * wc[(size_t)o * Ci * 81 + tap];
          }
        }
      }
    }
  }
  size_t osp = (size_t)To * Xo * Yo * Zo;
  size_t obase = (size_t)b * 20 * osp + (((size_t)to * Xo + xo) * Yo + yo) * Zo + zo;
#pragma unroll
  for (int o = 0; o < 20; o++) out[obase + (size_t)o * osp] = acc[o];
}

__global__ void k_conv4d_elem(const float* __restrict__ in, const float* __restrict__ W,
                              float* __restrict__ out, int Ci,
                              int Ti, int Xi, int Yi, int Zi,
                              int To, int Xo, int Yo, int Zo, int stride, int n) {
  int idx = blockIdx.x * 256 + threadIdx.x;
  if (idx >= n) return;
  int zo = idx % Zo; int r = idx / Zo;
  int yo = r % Yo; r /= Yo;
  int xo = r % Xo; r /= Xo;
  int to = r % To; r /= To;
  int o = r % 20; int b = r / 20;
  float acc = 0.f;
  size_t in_sp = (size_t)Ti * Xi * Yi * Zi;
  for (int ci = 0; ci < Ci; ci++) {
    const float* base = in + ((size_t)b * Ci + ci) * in_sp;
    const float* wc = W + ((size_t)o * Ci + ci) * 81;
    for (int kt = 0; kt < 3; kt++) {
      int t = to * stride + kt - 1; if (t < 0 || t >= Ti) continue;
      for (int kx = 0; kx < 3; kx++) {
        int xx = xo * stride + kx - 1; if (xx < 0 || xx >= Xi) continue;
        for (int ky = 0; ky < 3; ky++) {
          int y = yo * stride + ky - 1; if (y < 0 || y >= Yi) continue;
          for (int kz = 0; kz < 3; kz++) {
            int z = zo * stride + kz - 1; if (z < 0 || z >= Zi) continue;
            acc += base[(((size_t)t * Xi + xx) * Yi + y) * Zi + z] * wc[((kt * 3 + kx) * 3 + ky) * 3 + kz];
          }
        }
      }
    }
  }
  out[idx] = acc;
}

// ---------------- BN ----------------
__global__ void k_bn_stats(const float* __restrict__ d, int S, float* __restrict__ stats) {
  int c = blockIdx.x;
  int tid = threadIdx.x;
  float s = 0.f, s2 = 0.f;
  for (int b = 0; b < 4; b++) {
    const float* p = d + ((size_t)b * 20 + c) * S;
    for (int i = tid; i < S; i += 256) { float v = p[i]; s += v; s2 += v * v; }
  }
  __shared__ float ls[256], lq[256];
  ls[tid] = s; lq[tid] = s2;
  __syncthreads();
  for (int off = 128; off > 0; off >>= 1) {
    if (tid < off) { ls[tid] += ls[tid + off]; lq[tid] += lq[tid + off]; }
    __syncthreads();
  }
  if (tid == 0) {
    float cnt = 4.f * (float)S;
    float mean = ls[0] / cnt;
    float var = lq[0] / cnt - mean * mean;
    stats[2 * c] = mean;
    stats[2 * c + 1] = rsqrtf(var + 1e-5f);
  }
}

__global__ void k_bn_apply(float* __restrict__ d, int S, const float* __restrict__ stats,
                           const float* __restrict__ g, const float* __restrict__ bb, int n) {
  int idx = blockIdx.x * 256 + threadIdx.x;
  if (idx >= n) return;
  int c = (idx / S) % 20;
  float v = d[idx];
  v = (v - stats[2 * c]) * stats[2 * c + 1] * g[c] + bb[c];
  d[idx] = (v >= 0.f) ? v : 0.1f * v;
}

// BN apply for oc1 + bf16 channels-last copy into CLd0 ci 0..19
__global__ void k_bn_apply_cl(float* __restrict__ d, const float* __restrict__ stats,
                              const float* __restrict__ g, const float* __restrict__ bb,
                              short* __restrict__ CL, int n) {
  int idx = blockIdx.x * 256 + threadIdx.x;
  if (idx >= n) return;
  int s = idx & 16383;
  int r = idx >> 14;
  int c = r % 20, b = r / 20;
  float v = d[idx];
  v = (v - stats[2 * c]) * stats[2 * c + 1] * g[c] + bb[c];
  v = (v >= 0.f) ? v : 0.1f * v;
  d[idx] = v;
  CL[((size_t)(b * 16384 + s)) * 40 + c] = f2bf(v);
}

// ---------------- deconv (ConvTranspose4d k=4 s=2 p=1), bias+lrelu fused ----------------
__device__ __forceinline__ int dcands(int p, int n_in, int* q, int* k) {
  int cnt = 0;
  int q0 = (p + 1) >> 1, k0 = p + 1 - 2 * q0;
  if (q0 >= 0 && q0 < n_in) { q[cnt] = q0; k[cnt] = k0; cnt++; }
  int q1 = q0 - 1, k1 = k0 + 2;
  if (q1 >= 0 && q1 < n_in) { q[cnt] = q1; k[cnt] = k1; cnt++; }
  return cnt;
}

__global__ void k_deconv4d(const float* __restrict__ in1, int Ci1,
                           const float* __restrict__ in2, int Ci2,
                           const float* __restrict__ W, const float* __restrict__ bias,
                           float* __restrict__ out,
                           int Ti, int Xi, int Yi, int Zi, int n) {
  int idx = blockIdx.x * 256 + threadIdx.x;
  if (idx >= n) return;
  int To = 2 * Ti, Xo = 2 * Xi, Yo = 2 * Yi, Zo = 2 * Zi;
  int zo = idx % Zo; int r = idx / Zo;
  int yo = r % Yo; r /= Yo;
  int xo = r % Xo; r /= Xo;
  int to = r % To; int b = r / To;
  int qt[2], kt[2], qx[2], kx[2], qy[2], ky[2], qz[2], kz[2];
  int nt = dcands(to, Ti, qt, kt), nx = dcands(xo, Xi, qx, kx);
  int ny = dcands(yo, Yi, qy, ky), nz = dcands(zo, Zi, qz, kz);
  float acc[20];
#pragma unroll
  for (int o = 0; o < 20; o++) acc[o] = 0.f;
  int Ci = Ci1 + Ci2;
  size_t in_sp = (size_t)Ti * Xi * Yi * Zi;
  for (int ci = 0; ci < Ci; ci++) {
    const float* base = (ci < Ci1) ? in1 + ((size_t)b * Ci1 + ci) * in_sp
                                   : in2 + ((size_t)b * Ci2 + (ci - Ci1)) * in_sp;
    const float* wc = W + (size_t)ci * 5120;  // [ci][o(20)][256]
    for (int it = 0; it < nt; it++)
      for (int ix = 0; ix < nx; ix++)
        for (int iy = 0; iy < ny; iy++)
          for (int iz = 0; iz < nz; iz++) {
            float v = base[(((size_t)qt[it] * Xi + qx[ix]) * Yi + qy[iy]) * Zi + qz[iz]];
            int tap = ((kt[it] * 4 + kx[ix]) * 4 + ky[iy]) * 4 + kz[iz];
#pragma unroll
            for (int o = 0; o < 20; o++) acc[o] += v * wc[o * 256 + tap];
          }
  }
  size_t osp = (size_t)To * Xo * Yo * Zo;
  size_t obase = (size_t)b * 20 * osp + (((size_t)to * Xo + xo) * Yo + yo) * Zo + zo;
#pragma unroll
  for (int o = 0; o < 20; o++) {
    float v2 = acc[o] + bias[o];
    out[obase + (size_t)o * osp] = (v2 >= 0.f) ? v2 : 0.1f * v2;
  }
}

// d1 deconv: in 4x8x8x4 (oc2|od2, Ci=40) -> out 8x16x16x8 written bf16 CL ci 20..39
__global__ void k_deconv_d1_cl(const float* __restrict__ in1, const float* __restrict__ in2,
                               const float* __restrict__ W, const float* __restrict__ bias,
                               short* __restrict__ CL, int n) {
  int idx = blockIdx.x * 256 + threadIdx.x;
  if (idx >= n) return;
  int zo = idx & 7; int r = idx >> 3;
  int yo = r & 15; r >>= 4;
  int xo = r & 15; r >>= 4;
  int to = r & 7; int b = r >> 3;
  int qt[2], kt[2], qx[2], kx[2], qy[2], ky[2], qz[2], kz[2];
  int nt = dcands(to, 4, qt, kt), nx = dcands(xo, 8, qx, kx);
  int ny = dcands(yo, 8, qy, ky), nz = dcands(zo, 4, qz, kz);
  float acc[20];
#pragma unroll
  for (int o = 0; o < 20; o++) acc[o] = 0.f;
  const size_t in_sp = 4 * 8 * 8 * 4;
  for (int ci = 0; ci < 40; ci++) {
    const float* base = (ci < 20) ? in1 + ((size_t)b * 20 + ci) * in_sp
                                  : in2 + ((size_t)b * 20 + (ci - 20)) * in_sp;
    const float* wc = W + (size_t)ci * 5120;
    for (int it = 0; it < nt; it++)
      for (int ix = 0; ix < nx; ix++)
        for (int iy = 0; iy < ny; iy++)
          for (int iz = 0; iz < nz; iz++) {
            float v = base[(((size_t)qt[it] * 8 + qx[ix]) * 8 + qy[iy]) * 4 + qz[iz]];
            int tap = ((kt[it] * 4 + kx[ix]) * 4 + ky[iy]) * 4 + kz[iz];
#pragma unroll
            for (int o = 0; o < 20; o++) acc[o] += v * wc[o * 256 + tap];
          }
  }
  size_t pos = (((size_t)b * 8 + to) * 16 + xo) * 16 * 8 + (size_t)yo * 8 + zo;
  short* dst = CL + pos * 40 + 20;
#pragma unroll
  for (int o = 0; o < 20; o++) {
    float v2 = acc[o] + bias[o];
    v2 = (v2 >= 0.f) ? v2 : 0.1f * v2;
    dst[o] = f2bf(v2);
  }
}

// fill Xcl ci 0..19 from x
__global__ void k_xcl_x(const float* __restrict__ x, short* __restrict__ Xcl, int n) {
  int i = blockIdx.x * 256 + threadIdx.x;
  if (i >= n) return;
  int s = i & 262143, b = i >> 18;
  short* dst = Xcl + (size_t)i * 40;
  const float* src = x + (size_t)b * 20 * 262144 + s;
#pragma unroll
  for (int c = 0; c < 20; c++) dst[c] = f2bf(src[(size_t)c * 262144]);
}

// pack out_w [20][40][81] + w_pw [20][20] -> Wp[tap(82)][mt(2)][m(16)][k(64)] bf16,
// bank-swizzled for LDS staging: short index i -> i ^ ((m&7)<<3)  (byte ^ ((m&7)<<4)).
// tap 81 = pointwise (x2) weights.
__global__ void k_pack_w(const float* __restrict__ out_w, const float* __restrict__ w_pw,
                         short* __restrict__ Wp, short* __restrict__ zp, int n) {
  int i = blockIdx.x * 256 + threadIdx.x;
  if (i >= n) return;
  int k = i & 63, m = (i >> 6) & 15, mt = (i >> 10) & 1, tap = i >> 11;
  int o = mt * 16 + m;
  float v = 0.f;
  if (o < 20 && k < 40) {
    if (tap < 81) v = out_w[((size_t)o * 40 + k) * 81 + tap];
    else if (k < 20) v = w_pw[o * 20 + k];
  }
  Wp[i ^ ((m & 7) << 3)] = f2bf(v);
  if (i < 64) zp[i] = 0;
}

// pack d0_w [40][20][256] -> Wd parity-class-major:
// [h(32)=cls*2+it][sub(8)=ix*4+iz*2+iy][mt(2)][m(16)][k(64)] bf16,
// bank-swizzled: element index i -> i ^ ((m&7)<<3)  (byte ^ ((row&7)<<4)).
__global__ void k_pack_wd(const float* __restrict__ d0_w, short* __restrict__ Wd, int n) {
  int i = blockIdx.x * 256 + threadIdx.x;
  if (i >= n) return;
  int k = i & 63, m = (i >> 6) & 15, mt = (i >> 10) & 1, sub = (i >> 11) & 7, h = i >> 14;
  int it = h & 1, cls = h >> 1;
  int ez = cls & 1, ey = (cls >> 1) & 1, ex = (cls >> 2) & 1, et = (cls >> 3) & 1;
  int iy = sub & 1, iz = (sub >> 1) & 1, ix = (sub >> 2) & 1;
  int kt = et ? (2 * it) : (1 + 2 * it);
  int kx = ex ? (2 * ix) : (1 + 2 * ix);
  int ky = ey ? (2 * iy) : (1 + 2 * iy);
  int kz = ez ? (2 * iz) : (1 + 2 * iz);
  int tap = ((kt * 4 + kx) * 4 + ky) * 4 + kz;
  int o = mt * 16 + m;
  float v = (o < 20 && k < 40) ? d0_w[((size_t)k * 20 + o) * 256 + tap] : 0.f;
  Wd[i ^ ((m & 7) << 3)] = f2bf(v);
}

// ---------------- d0 deconv via MFMA (parity-class, LDS-staged) ----------------
// Block = (b, ut, ux): 512 threads = 8 waves, wave = uz. B working set = 9 (qt,qx)
// y-z planes x 10240B staged once into LDS (bank-swizzled via pre-swizzled global src).
// A (weights) staged per half-class phase (32KB contiguous, pre-swizzled pack),
// double-buffered: stage h+1 overlaps compute h. All operand reads are ds_read_b128.
__global__ __launch_bounds__(512) void k_d0_mfma(
    const short* __restrict__ CLd0, const short* __restrict__ Wd,
    const float* __restrict__ bias, short* __restrict__ Xcl) {
  __shared__ __align__(16) char lds[157696];  // 9*10240 B-planes + 2*32768 A dbuf
  char* lds_a = lds + 92160;
  int bid = blockIdx.x;
  int ux = bid & 15, ut = (bid >> 4) & 7, b = bid >> 7;
  int tid = threadIdx.x;
  int uz = tid >> 6;
  int lane = tid & 63, ln15 = lane & 15, kg = lane >> 4;  // ln15 = uy

  const char* xb = (const char*)CLd0;
  const char* wb = (const char*)Wd;

  auto gld = [](const char* src, char* dst) {
    __builtin_amdgcn_global_load_lds(
        (const __attribute__((address_space(1))) void*)src,
        (__attribute__((address_space(3))) void*)dst, 16, 0, 0);
  };

  // ---- prologue: stage B planes (swizzle baked into per-lane global src) ----
#pragma unroll
  for (int pt = 0; pt < 3; pt++) {
    int qt = ut - 1 + pt;
    if (qt < 0 || qt > 7) continue;
#pragma unroll
    for (int px = 0; px < 3; px++) {
      int qx = ux - 1 + px;
      if (qx < 0 || qx > 15) continue;
      const char* src = xb + (size_t)((b * 8 + qt) * 16 + qx) * 10240;
      char* dst = lds + (pt * 3 + px) * 10240;
      for (int g = tid; g < 640; g += 512) {
        int key = ((g / 40) & 7) << 4;
        gld(src + ((g * 16) ^ key), dst + g * 16);
      }
    }
  }
  // stage A half-block h=0 (pack is pre-swizzled -> linear copy)
  for (int g = tid; g < 2048; g += 512) gld(wb + g * 16, lds_a + g * 16);
  asm volatile("s_waitcnt vmcnt(0)" ::: "memory");
  __syncthreads();

  bf16x8 zv = {0, 0, 0, 0, 0, 0, 0, 0};
  int aswz = ((ln15 * 128 + kg * 16) ^ ((ln15 & 7) << 4));

#pragma unroll 1
  for (int cls = 0; cls < 16; cls++) {
    int ez = cls & 1, ey = (cls >> 1) & 1, ex = (cls >> 2) & 1, et = (cls >> 3) & 1;
    f32x4 acc0, acc1;
#pragma unroll
    for (int j = 0; j < 4; j++) { acc0[j] = 0.f; acc1[j] = 0.f; }
#pragma unroll
    for (int it = 0; it < 2; it++) {
      int h = cls * 2 + it;
      // stage next A half-block into the other buffer
      if (h + 1 < 32) {
        const char* asrc = wb + (size_t)(h + 1) * 32768;
        char* adst = lds_a + (it ^ 1) * 32768;
        for (int g = tid; g < 2048; g += 512) gld(asrc + g * 16, adst + g * 16);
      }
      const char* ab = lds_a + it * 32768;
      int kt_q = ut + (et ? (1 - it) : (-it));
      if (kt_q >= 0 && kt_q <= 7) {
        int pt = kt_q - ut + 1;
#pragma unroll
        for (int ix = 0; ix < 2; ix++) {
          int qx = ux + (ex ? (1 - ix) : (-ix));
          if (qx < 0 || qx > 15) continue;
          int px = qx - ux + 1;
          const char* pbase = lds + (pt * 3 + px) * 10240;
#pragma unroll
          for (int iz = 0; iz < 2; iz++) {
            int qz = uz + (ez ? (1 - iz) : (-iz));
            if (qz < 0 || qz > 7) continue;
#pragma unroll
            for (int iy = 0; iy < 2; iy++) {
              int qy = ln15 + (ey ? (1 - iy) : (-iy));
              bool yok = (qy >= 0) && (qy < 16);
              int qyc = yok ? qy : 0;
              int bkey = (qyc & 7) << 4;
              const char* abase = ab + (ix * 4 + iz * 2 + iy) * 4096;
#pragma unroll
              for (int ch = 0; ch < 2; ch++) {
                int co = ch ? 64 : kg * 16;  // ch=1: broadcast ci 32..39 (k>=40 wts are 0)
                int boff = (qyc * 640 + qz * 80 + co) ^ bkey;
                bf16x8 bvv = *(const bf16x8*)(pbase + boff);
                bf16x8 bv = yok ? bvv : zv;
                int aoff = (ch ? (aswz ^ 64) : aswz);
                bf16x8 a0 = *(const bf16x8*)(abase + aoff);
                bf16x8 a1 = *(const bf16x8*)(abase + 2048 + aoff);
                acc0 = __builtin_amdgcn_mfma_f32_16x16x32_bf16(a0, bv, acc0, 0, 0, 0);
                acc1 = __builtin_amdgcn_mfma_f32_16x16x32_bf16(a1, bv, acc1, 0, 0, 0);
              }
            }
          }
        }
      }
      asm volatile("s_waitcnt vmcnt(0)" ::: "memory");
      __syncthreads();
    }
    int to = 2 * ut + et, xo = 2 * ux + ex, zo = 2 * uz + ez, yo = 2 * ln15 + ey;
    long opos = ((((long)b * 16 + to) * 32 + xo) * 32 + yo) * 16 + zo;
    short* dst = Xcl + opos * 40 + 20;
    {
      unsigned hh[4];
#pragma unroll
      for (int r = 0; r < 4; r++) {
        float v = acc0[r] + bias[kg * 4 + r];
        v = (v >= 0.f) ? v : 0.1f * v;
        hh[r] = (unsigned)(unsigned short)f2bf(v);
      }
      uint2 u;
      u.x = hh[0] | (hh[1] << 16);
      u.y = hh[2] | (hh[3] << 16);
      *(uint2*)(dst + kg * 4) = u;
    }
    if (kg == 0) {
      unsigned hh[4];
#pragma unroll
      for (int r = 0; r < 4; r++) {
        float v = acc1[r] + bias[16 + r];
        v = (v >= 0.f) ? v : 0.1f * v;
        hh[r] = (unsigned)(unsigned short)f2bf(v);
      }
      uint2 u;
      u.x = hh[0] | (hh[1] << 16);
      u.y = hh[2] | (hh[3] << 16);
      *(uint2*)(dst + 16) = u;
    }
  }
}

// ---------------- final conv: fully LDS-staged bf16 MFMA implicit GEMM ----------------
// Block = (b,t0,x0), 512 threads. Per valid (kt,kx) slab, BOTH the 40KB B run and the
// 36KB contiguous 9-tap weight run are staged into LDS (double-buffered, 2-phase).
// Weight pack is pre-swizzled in global (byte ^ ((m&7)<<4)); reads apply the same XOR.
__global__ __launch_bounds__(512) void k_fconv_mfma(
    const short* __restrict__ Xcl, const short* __restrict__ Wp,
    const float* __restrict__ bias, const float* __restrict__ bpw,
    float* __restrict__ io) {
  __shared__ __align__(16) char ldsB[2][40960];
  __shared__ __align__(16) char ldsW[2][36864];
  int bid = blockIdx.x;
  int xcd = bid & 7, idx = bid >> 3;
  int b = xcd >> 1, xh = xcd & 1;
  // t0-major within each XCD: working set 3 xi-slabs x 16 ti x 40KB ~ 1.9MB < 4MB L2
  int t0 = idx & 15, x0 = xh * 16 + ((idx >> 4) & 15);
  int tid = threadIdx.x;
  int lane = tid & 63;
  int ln15 = lane & 15, kg = lane >> 4;
  int ybase = (tid >> 6) * 4;

  // valid (kt,kx) slab list, 4 bits per entry (code = kt*4+kx; center = 5)
  unsigned long long codes = 0ull;
  int ns = 0;
  for (int kt = 0; kt < 3; kt++) {
    int ti = t0 + kt - 1;
    if (ti < 0 || ti > 15) continue;
    for (int kx = 0; kx < 3; kx++) {
      int xi = x0 + kx - 1;
      if (xi < 0 || xi > 31) continue;
      codes |= (unsigned long long)(kt * 4 + kx) << (4 * ns);
      ns++;
    }
  }

  const char* xb = (const char*)Xcl;
  const char* wb = (const char*)Wp;

  auto gld = [](const char* src, char* dst) {
    __builtin_amdgcn_global_load_lds(
        (const __attribute__((address_space(1))) void*)src,
        (__attribute__((address_space(3))) void*)dst, 16, 0, 0);
  };

  auto stage = [&](int buf, int code) {
    int kt = code >> 2, kx = code & 3;
    int ti = t0 + kt - 1, xi = x0 + kx - 1;
    const char* src = xb + (size_t)((b * 16 + ti) * 32 + xi) * 512 * 80;
    char* dstB = ldsB[buf];
#pragma unroll
    for (int s = 0; s < 5; s++) {
      int off = s * 8192 + tid * 16;
      gld(src + off, dstB + off);
    }
    // 9-tap contiguous weight run for this slab: taps (kt*3+kx)*9 .. +8
    const char* wsrc = wb + (size_t)(kt * 3 + kx) * 9 * 4096;
    char* dstW = ldsW[buf];
    for (int g = tid; g < 2304; g += 512) gld(wsrc + g * 16, dstW + g * 16);
  };

  f32x4 acc[2][4];
#pragma unroll
  for (int mt = 0; mt < 2; mt++)
#pragma unroll
    for (int nt = 0; nt < 4; nt++)
#pragma unroll
      for (int j = 0; j < 4; j++) acc[mt][nt][j] = 0.f;

  int awz0 = (ln15 * 128 + kg * 16) ^ ((ln15 & 7) << 4);
  int awz1 = (ln15 * 128 + 64 + kg * 16) ^ ((ln15 & 7) << 4);

  stage(0, (int)(codes & 15));
  asm volatile("s_waitcnt vmcnt(0)" ::: "memory");
  __syncthreads();

  int cur = 0;
#pragma unroll 1
  for (int i = 0; i < ns; i++) {
    const char* bufB = ldsB[cur];
    const char* bufW = ldsW[cur];
    if (i + 1 < ns) stage(cur ^ 1, (int)((codes >> (4 * (i + 1))) & 15));
    int code = (int)((codes >> (4 * i)) & 15);
    bf16x8 zv = {0, 0, 0, 0, 0, 0, 0, 0};
#pragma unroll
    for (int kz = 0; kz < 3; kz++) {
      int zi = ln15 + kz - 1;
      bool zok = (zi >= 0) && (zi < 16);
      int zc = zok ? zi : 0;
#pragma unroll
      for (int ch = 0; ch < 2; ch++) {
        int co = ch ? 64 : kg * 16;  // ch=1: broadcast ci 32..39 chunk to all kg
        bf16x8 bv[6];
#pragma unroll
        for (int j = 0; j < 6; j++) {
          int yi = ybase + j - 1;
          int yc = (yi < 0) ? 0 : ((yi > 31) ? 31 : yi);
          bf16x8 v = *(const bf16x8*)(bufB + (size_t)(yc * 16 + zc) * 80 + co);
          bool ok = zok && (yi >= 0) && (yi < 32);
          bv[j] = ok ? v : zv;
        }
        int awz = ch ? awz1 : awz0;
        bf16x8 av[3][2];
#pragma unroll
        for (int ky = 0; ky < 3; ky++) {
          const char* wt = bufW + (size_t)(ky * 3 + kz) * 4096;
          av[ky][0] = *(const bf16x8*)(wt + awz);
          av[ky][1] = *(const bf16x8*)(wt + 2048 + awz);
        }
#pragma unroll
        for (int ky = 0; ky < 3; ky++)
#pragma unroll
          for (int nt = 0; nt < 4; nt++) {
            acc[0][nt] = __builtin_amdgcn_mfma_f32_16x16x32_bf16(av[ky][0], bv[nt + ky], acc[0][nt], 0, 0, 0);
            acc[1][nt] = __builtin_amdgcn_mfma_f32_16x16x32_bf16(av[ky][1], bv[nt + ky], acc[1][nt], 0, 0, 0);
          }
      }
    }
    if (code == 5) {
      // center slab: fused pointwise (x2) tap, ci 0..19 (weights zero for k>=20)
      const char* wt = wb + (size_t)81 * 4096;
      bf16x8 a0 = *(const bf16x8*)(wt + awz0);
      bf16x8 a1 = *(const bf16x8*)(wt + 2048 + awz0);
#pragma unroll
      for (int nt = 0; nt < 4; nt++) {
        bf16x8 bv = *(const bf16x8*)(bufB + (size_t)((ybase + nt) * 16 + ln15) * 80 + kg * 16);
        acc[0][nt] = __builtin_amdgcn_mfma_f32_16x16x32_bf16(a0, bv, acc[0][nt], 0, 0, 0);
        acc[1][nt] = __builtin_amdgcn_mfma_f32_16x16x32_bf16(a1, bv, acc[1][nt], 0, 0, 0);
      }
    }
    asm volatile("s_waitcnt vmcnt(0)" ::: "memory");
    __syncthreads();
    cur ^= 1;
  }

#pragma unroll
  for (int mt = 0; mt < 2; mt++)
#pragma unroll
    for (int r = 0; r < 4; r++) {
      int o = mt * 16 + kg * 4 + r;
      if (o >= 20) continue;
      float bo = bias[o] + bpw[o];
#pragma unroll
      for (int nt = 0; nt < 4; nt++) {
        int y = ybase + nt;
        size_t oidx = ((size_t)(b * 20 + o)) * 262144 +
                      ((((size_t)t0 * 32 + x0) * 32 + y) * 16 + ln15);
        float v = acc[mt][nt][r] + bo + io[oidx];
        io[oidx] = fmaxf(v, 0.f);
      }
    }
}

extern "C" void kernel_launch(void* const* d_in, const int* in_sizes, int n_in,
                              void* d_out, int out_size, void* d_ws, size_t ws_size,
                              hipStream_t stream) {
  const float* x     = (const float*)d_in[0];
  const float* sw1   = (const float*)d_in[1];
  const float* sw2   = (const float*)d_in[2];
  const float* sw3   = (const float*)d_in[3];
  const float* sw4   = (const float*)d_in[4];
  const float* w_pw  = (const float*)d_in[5];
  const float* b_pw  = (const float*)d_in[6];
  const float* c1_w  = (const float*)d_in[7];
  const float* c2_w  = (const float*)d_in[8];
  const float* c21_w = (const float*)d_in[9];
  const float* c3_w  = (const float*)d_in[10];
  const float* c31_w = (const float*)d_in[11];
  const float* bn1_g = (const float*)d_in[12];
  const float* bn1_b = (const float*)d_in[13];
  const float* bn2_g = (const float*)d_in[14];
  const float* bn2_b = (const float*)d_in[15];
  const float* bn21_g = (const float*)d_in[16];
  const float* bn21_b = (const float*)d_in[17];
  const float* bn3_g = (const float*)d_in[18];
  const float* bn3_b = (const float*)d_in[19];
  const float* bn31_g = (const float*)d_in[20];
  const float* bn31_b = (const float*)d_in[21];
  const float* d2_w  = (const float*)d_in[22];
  const float* d2_b  = (const float*)d_in[23];
  const float* d1_w  = (const float*)d_in[24];
  const float* d1_b  = (const float*)d_in[25];
  const float* d0_w  = (const float*)d_in[26];
  const float* d0_b  = (const float*)d_in[27];
  const float* out_w = (const float*)d_in[28];
  const float* out_b = (const float*)d_in[29];
  float* out = (float*)d_out;
  float* ws = (float*)d_ws;

  // spectral arena (phase 1 only)
  float2* A  = (float2*)(ws);
  float2* Bb = (float2*)(ws + 10485760);
  float2* Cb = (float2*)(ws + 13107200);
  float2* Dd = (float2*)(ws + 14417920);
  float2* Ee = (float2*)(ws + 15073280);
  float2* Ff = (float2*)(ws + 15728640);
  float2* Gg = (float2*)(ws + 16384000);
  // twiddle tables: live only during spectral phase; region inside Xcl span,
  // beyond the spectral arena end (17,039,360 fl), overwritten later by k_xcl_x.
  float2* Twid = (float2*)(ws + 23000000);

  // U-Net arena
  float* oc1   = ws;
  short* CLd0  = (short*)(ws + 1310720);
  float* oc2a  = ws + 2621440;
  float* oc2   = ws + 2703360;
  float* oc3a  = ws + 2785280;
  float* oc3   = ws + 2790400;
  float* od2   = ws + 2795520;
  short* Xcl   = (short*)(ws + 2877440);
  float* stats = ws + 23848960;
  short* Wd = (short*)(ws);
  short* Wp = (short*)(ws + 262144);
  short* zp = (short*)(ws + 349184);

  auto nb = [](int n) { return (n + 255) / 256; };
  dim3 blk(256);

  // ---- twiddle tables ----
  k_twid<<<1, 64, 0, stream>>>(Twid);

  // ---- spectral path: x1 -> d_out ----
  k_fwd_z<<<nb(1310720), blk, 0, stream>>>(x, Twid, A, 1310720);
  k_fwd_y<<<nb(1310720), blk, 0, stream>>>(A, Twid, Bb, 1310720);
  k_fwd_x<<<nb(655360), blk, 0, stream>>>(Bb, Twid, Cb, 655360);
  k_fwd_t<<<nb(327680), blk, 0, stream>>>(Cb, Twid, Dd, 327680);
  k_fwd_c<<<nb(327680), blk, 0, stream>>>(Dd, Twid, Ee, 327680);
  k_fwd_b<<<nb(327680), blk, 0, stream>>>(Ee, Twid, Ff, 327680);
  k_smul<<<nb(327680), blk, 0, stream>>>(Ff, sw1, sw2, sw3, sw4, Gg, 327680);
  k_inv_t<<<nb(655360), blk, 0, stream>>>(Gg, Twid, Cb, 655360);
  k_inv_x<<<nb(1310720), blk, 0, stream>>>(Cb, Twid, Bb, 1310720);
  k_inv_yz<<<nb(1310720), blk, 0, stream>>>(Bb, Twid, out, 1310720);

  // ---- Xcl ci 0..19 from x ----
  k_xcl_x<<<nb(1048576), blk, 0, stream>>>(x, Xcl, 1048576);

  // ---- U-Net encoder ----
  k_conv4d_pos<<<nb(65536), blk, 0, stream>>>(x, 20, nullptr, 0, c1_w, oc1,
                                              16, 32, 32, 16, 8, 16, 16, 8, 2, 65536);
  k_bn_stats<<<20, blk, 0, stream>>>(oc1, 16384, stats);
  k_bn_apply_cl<<<nb(1310720), blk, 0, stream>>>(oc1, stats, bn1_g, bn1_b, CLd0, 1310720);

  k_conv4d_elem<<<nb(81920), blk, 0, stream>>>(oc1, c2_w, oc2a, 20,
                                               8, 16, 16, 8, 4, 8, 8, 4, 2, 81920);
  k_bn_stats<<<20, blk, 0, stream>>>(oc2a, 1024, stats);
  k_bn_apply<<<nb(81920), blk, 0, stream>>>(oc2a, 1024, stats, bn2_g, bn2_b, 81920);

  k_conv4d_elem<<<nb(81920), blk, 0, stream>>>(oc2a, c21_w, oc2, 20,
                                               4, 8, 8, 4, 4, 8, 8, 4, 1, 81920);
  k_bn_stats<<<20, blk, 0, stream>>>(oc2, 1024, stats);
  k_bn_apply<<<nb(81920), blk, 0, stream>>>(oc2, 1024, stats, bn21_g, bn21_b, 81920);

  k_conv4d_elem<<<nb(5120), blk, 0, stream>>>(oc2, c3_w, oc3a, 20,
                                              4, 8, 8, 4, 2, 4, 4, 2, 2, 5120);
  k_bn_stats<<<20, blk, 0, stream>>>(oc3a, 64, stats);
  k_bn_apply<<<nb(5120), blk, 0, stream>>>(oc3a, 64, stats, bn3_g, bn3_b, 5120);

  k_conv4d_elem<<<nb(5120), blk, 0, stream>>>(oc3a, c31_w, oc3, 20,
                                              2, 4, 4, 2, 2, 4, 4, 2, 1, 5120);
  k_bn_stats<<<20, blk, 0, stream>>>(oc3, 64, stats);
  k_bn_apply<<<nb(5120), blk, 0, stream>>>(oc3, 64, stats, bn31_g, bn31_b, 5120);

  // ---- decoder ----
  k_deconv4d<<<nb(4096), blk, 0, stream>>>(oc3, 20, nullptr, 0, d2_w, d2_b, od2,
                                           2, 4, 4, 2, 4096);
  k_deconv_d1_cl<<<nb(65536), blk, 0, stream>>>(oc2, od2, d1_w, d1_b, CLd0, 65536);

  // weight packs
  k_pack_w<<<nb(167936), blk, 0, stream>>>(out_w, w_pw, Wp, zp, 167936);
  k_pack_wd<<<nb(524288), blk, 0, stream>>>(d0_w, Wd, 524288);

  // d0 deconv via MFMA (LDS-staged) -> Xcl ci 20..39
  k_d0_mfma<<<512, dim3(512), 0, stream>>>(CLd0, Wd, d0_b, Xcl);

  // final conv via MFMA (fully LDS-staged), fused +bias +x1 +x2(pointwise) +relu into d_out
  k_fconv_mfma<<<2048, dim3(512), 0, stream>>>(Xcl, Wp, out_b, b_pw, out);
}

// Round 4
// 2194.608 us; speedup vs baseline: 1.5487x; 1.1370x over previous
//
#include <hip/hip_runtime.h>

#define PI2 6.28318530717958647692f

typedef __attribute__((ext_vector_type(8))) short bf16x8;
typedef __attribute__((ext_vector_type(4))) float f32x4;

__device__ __forceinline__ void cfma(float2& acc, float2 a, float2 t) {
  acc.x += a.x * t.x - a.y * t.y;
  acc.y += a.x * t.y + a.y * t.x;
}
// multiply by conj(t) (inverse twiddle), t = e^{-i\theta}
__device__ __forceinline__ void cfmac(float2& acc, float2 a, float2 t) {
  acc.x += a.x * t.x + a.y * t.y;
  acc.y += a.y * t.x - a.x * t.y;
}

__device__ __forceinline__ short f2bf(float f) {
  unsigned u = __float_as_uint(f);
  unsigned r = (u + 0x7fff + ((u >> 16) & 1)) >> 16;
  return (short)r;
}

// twiddle tables: T[0..31]=e^{-2pi i m/32}, T[32..47]=N16, T[48..67]=N20, T[68..71]=N4
__global__ void k_twid(float2* __restrict__ T) {
  int i = threadIdx.x;
  float s, c;
  if (i < 32) { __sincosf(-PI2 * (float)i / 32.f, &s, &c); T[i] = make_float2(c, s); }
  if (i < 16) { __sincosf(-PI2 * (float)i / 16.f, &s, &c); T[32 + i] = make_float2(c, s); }
  if (i < 20) { __sincosf(-PI2 * (float)i / 20.f, &s, &c); T[48 + i] = make_float2(c, s); }
  if (i < 4)  { __sincosf(-PI2 * (float)i / 4.f,  &s, &c); T[68 + i] = make_float2(c, s); }
}

// ---------------- spectral forward ----------------
__global__ void k_fwd_z(const float* __restrict__ x, const float2* __restrict__ T,
                        float2* __restrict__ out, int nrows) {
  __shared__ float2 tw[16];
  if (threadIdx.x < 16) tw[threadIdx.x] = T[32 + threadIdx.x];
  __syncthreads();
  int r = blockIdx.x * 256 + threadIdx.x;
  if (r >= nrows) return;
  const float* p = x + (size_t)r * 16;
  float v[16];
#pragma unroll
  for (int z = 0; z < 16; z++) v[z] = p[z];
#pragma unroll
  for (int zk = 0; zk < 4; zk++) {
    float re = 0.f, im = 0.f;
#pragma unroll
    for (int z = 0; z < 16; z++) {
      float2 t = tw[(z * zk) & 15];
      re += v[z] * t.x;
      im += v[z] * t.y;
    }
    out[(size_t)r * 4 + zk] = make_float2(re, im);
  }
}

__global__ void k_fwd_y(const float2* __restrict__ in, const float2* __restrict__ T,
                        float2* __restrict__ out, int n) {
  __shared__ float2 tw[32];
  if (threadIdx.x < 32) tw[threadIdx.x] = T[threadIdx.x];
  __syncthreads();
  int i = blockIdx.x * 256 + threadIdx.x;
  if (i >= n) return;
  int zk = i & 3, yk = (i >> 2) & 7, slab = i >> 5;
  const float2* p = in + (size_t)slab * 128 + zk;
  float2 acc = make_float2(0.f, 0.f);
  for (int y = 0; y < 32; y++) cfma(acc, p[y * 4], tw[(y * yk) & 31]);
  out[i] = acc;
}

__global__ void k_fwd_x(const float2* __restrict__ in, const float2* __restrict__ T,
                        float2* __restrict__ out, int n) {
  __shared__ float2 tw[32];
  if (threadIdx.x < 32) tw[threadIdx.x] = T[threadIdx.x];
  __syncthreads();
  int i = blockIdx.x * 256 + threadIdx.x;
  if (i >= n) return;
  int zk = i & 3, yk = (i >> 2) & 7, xi = (i >> 5) & 15, slab = i >> 9;
  int xk = (xi < 8) ? xi : xi + 16;
  const float2* p = in + (size_t)slab * 1024 + yk * 4 + zk;
  float2 acc = make_float2(0.f, 0.f);
  for (int xx = 0; xx < 32; xx++) cfma(acc, p[xx * 32], tw[(xx * xk) & 31]);
  out[i] = acc;
}

__global__ void k_fwd_t(const float2* __restrict__ in, const float2* __restrict__ T,
                        float2* __restrict__ out, int n) {
  __shared__ float2 tw[16];
  if (threadIdx.x < 16) tw[threadIdx.x] = T[32 + threadIdx.x];
  __syncthreads();
  int i = blockIdx.x * 256 + threadIdx.x;
  if (i >= n) return;
  int zk = i & 3, yk = (i >> 2) & 7, xi = (i >> 5) & 15, ti = (i >> 9) & 7, bc = i >> 12;
  int tk = (ti < 4) ? ti : ti + 8;
  const float2* p = in + (size_t)bc * 8192 + xi * 32 + yk * 4 + zk;
  float2 acc = make_float2(0.f, 0.f);
  for (int t = 0; t < 16; t++) cfma(acc, p[t * 512], tw[(t * tk) & 15]);
  out[i] = acc;
}

__global__ void k_fwd_c(const float2* __restrict__ in, const float2* __restrict__ T,
                        float2* __restrict__ out, int n) {
  __shared__ float2 tw[20];
  if (threadIdx.x < 20) tw[threadIdx.x] = T[48 + threadIdx.x];
  __syncthreads();
  int i = blockIdx.x * 256 + threadIdx.x;
  if (i >= n) return;
  int mode = i & 4095, r = i >> 12, ck = r % 20, b = r / 20;
  const float2* p = in + (size_t)b * 81920 + mode;
  float2 acc = make_float2(0.f, 0.f);
  int idx = 0;
  for (int c = 0; c < 20; c++) {
    cfma(acc, p[(size_t)c * 4096], tw[idx]);
    idx += ck; if (idx >= 20) idx -= 20;
  }
  out[i] = acc;
}

__global__ void k_fwd_b(const float2* __restrict__ in, const float2* __restrict__ T,
                        float2* __restrict__ out, int n) {
  __shared__ float2 tw[4];
  if (threadIdx.x < 4) tw[threadIdx.x] = T[68 + threadIdx.x];
  __syncthreads();
  int i = blockIdx.x * 256 + threadIdx.x;
  if (i >= n) return;
  int mode = i & 4095, r = i >> 12, ck = r % 20, bk = r / 20;
  const float2* p = in + (size_t)ck * 4096 + mode;
  float2 acc = make_float2(0.f, 0.f);
#pragma unroll
  for (int b = 0; b < 4; b++) cfma(acc, p[(size_t)b * 81920], tw[(b * bk) & 3]);
  out[i] = acc;
}

__global__ void k_smul(const float2* __restrict__ in,
                       const float* __restrict__ sw1, const float* __restrict__ sw2,
                       const float* __restrict__ sw3, const float* __restrict__ sw4,
                       float2* __restrict__ out, int n) {
  int i = blockIdx.x * 256 + threadIdx.x;
  if (i >= n) return;
  int mode = i & 4095, r = i >> 12, o = r % 20, bk = r / 20;
  int ti = mode >> 9, xi = (mode >> 5) & 15, yk = (mode >> 2) & 7, zk = mode & 3;
  const float* w = (ti < 4) ? ((xi < 8) ? sw1 : sw3) : ((xi < 8) ? sw2 : sw4);
  int tl = ti & 3, xl = xi & 7;
  const float2* wp = (const float2*)w;
  const float2* ip = in + (size_t)bk * 81920 + mode;
  size_t wsub = (size_t)o * 1024 + (size_t)tl * 256 + (size_t)xl * 32 + yk * 4 + zk;
  float2 acc = make_float2(0.f, 0.f);
  for (int ci = 0; ci < 20; ci++) cfma(acc, ip[(size_t)ci * 4096], wp[(size_t)ci * 20480 + wsub]);
  out[i] = acc;
}

// ---------------- spectral inverse ----------------
__global__ void k_inv_t(const float2* __restrict__ in, const float2* __restrict__ T,
                        float2* __restrict__ out, int n) {
  __shared__ float2 tw[16];
  if (threadIdx.x < 16) tw[threadIdx.x] = T[32 + threadIdx.x];
  __syncthreads();
  int i = blockIdx.x * 256 + threadIdx.x;
  if (i >= n) return;
  int zk = i & 3, yk = (i >> 2) & 7, xi = (i >> 5) & 15, tp = (i >> 9) & 15, bc = i >> 13;
  const float2* p = in + (size_t)bc * 4096 + xi * 32 + yk * 4 + zk;
  float2 acc = make_float2(0.f, 0.f);
#pragma unroll
  for (int ti = 0; ti < 8; ti++) {
    int tk = (ti < 4) ? ti : ti + 8;
    cfmac(acc, p[ti * 512], tw[(tk * tp) & 15]);
  }
  out[i] = acc;
}

__global__ void k_inv_x(const float2* __restrict__ in, const float2* __restrict__ T,
                        float2* __restrict__ out, int n) {
  __shared__ float2 tw[32];
  if (threadIdx.x < 32) tw[threadIdx.x] = T[threadIdx.x];
  __syncthreads();
  int i = blockIdx.x * 256 + threadIdx.x;
  if (i >= n) return;
  int zk = i & 3, yk = (i >> 2) & 7, xp = (i >> 5) & 31, tp = (i >> 10) & 15, bc = i >> 14;
  const float2* p = in + (size_t)bc * 8192 + tp * 512 + yk * 4 + zk;
  float2 acc = make_float2(0.f, 0.f);
#pragma unroll
  for (int xi = 0; xi < 16; xi++) {
    int xk = (xi < 8) ? xi : xi + 16;
    cfmac(acc, p[xi * 32], tw[(xk * xp) & 31]);
  }
  out[i] = acc;
}

// fused inverse-y + c2r-z: thread per (bc,tp,xp,yp), emits full 16-z real row.
__global__ void k_inv_yz(const float2* __restrict__ in, const float2* __restrict__ T,
                         float* __restrict__ out, int n) {
  __shared__ float2 tw[48];  // 0..31: N32, 32..47: N16
  if (threadIdx.x < 48) tw[threadIdx.x] = T[threadIdx.x];
  __syncthreads();
  int i = blockIdx.x * 256 + threadIdx.x;
  if (i >= n) return;
  int yp = i & 31;
  const float2* p = in + (size_t)(i >> 5) * 32;  // [bc][tp][xp] slab: [yk8][zk4]
  float2 Ay[4];
#pragma unroll
  for (int zk = 0; zk < 4; zk++) Ay[zk] = make_float2(0.f, 0.f);
#pragma unroll
  for (int yk = 0; yk < 8; yk++) {
    float2 w = tw[(yk * yp) & 31];
#pragma unroll
    for (int zk = 0; zk < 4; zk++) cfmac(Ay[zk], p[yk * 4 + zk], w);
  }
  float res[16];
#pragma unroll
  for (int zp = 0; zp < 16; zp++) {
    float v = Ay[0].x;
#pragma unroll
    for (int zk = 1; zk < 4; zk++) {
      float2 t = tw[32 + ((zk * zp) & 15)];
      v += 2.f * (Ay[zk].x * t.x + Ay[zk].y * t.y);
    }
    res[zp] = v * (1.f / 262144.f);
  }
  float4* o4 = (float4*)(out + (size_t)i * 16);
#pragma unroll
  for (int q = 0; q < 4; q++)
    o4[q] = make_float4(res[q * 4], res[q * 4 + 1], res[q * 4 + 2], res[q * 4 + 3]);
}

// ---------------- c1 conv (stride 2, 20->20) LDS-tiled, fp32-exact ----------------
// pack c1_w [o][ci][81] -> Wc1p[ci][tap][o] (contiguous per ci)
__global__ void k_pack_c1(const float* __restrict__ c1_w, float* __restrict__ Wc, int n) {
  int i = blockIdx.x * 256 + threadIdx.x;
  if (i >= n) return;
  int o = i % 20; int r = i / 20;
  int tap = r % 81; int ci = r / 81;
  Wc[i] = c1_w[((size_t)o * 20 + ci) * 81 + tap];
}

// Block = (b,to,xop): 4*8*8 = 256 blocks x 256 threads (zo8, yo16, j2).
// Per ci, the needed input is 15 contiguous (t,x) rows x 512 f staged into LDS
// (global_load_lds, double-buffered; boundary rows zero-filled once -> zero-adds
// keep fp32 accumulation bit-identical to the skip-based original).
// Weights read from global with uniform indices (scalarizes to s_load).
__global__ __launch_bounds__(256) void k_c1(
    const float* __restrict__ x, const float* __restrict__ Wc,
    float* __restrict__ out) {
  __shared__ __align__(16) float tile[2][7680];  // [tt3][xx5][y32][z16]
  int bid = blockIdx.x;
  int xop = bid & 7, to = (bid >> 3) & 7, b = bid >> 6;
  int tid = threadIdx.x;
  int zo = tid & 7, yo = (tid >> 3) & 15, j = tid >> 7;

  auto gld = [](const char* src, char* dst) {
    __builtin_amdgcn_global_load_lds(
        (const __attribute__((address_space(1))) void*)src,
        (__attribute__((address_space(3))) void*)dst, 16, 0, 0);
  };

  // zero pad rows (invalid t or x planes) in BOTH buffers once
  for (int g = tid; g < 1920; g += 256) {
    int r = g >> 7, l = g & 127;
    int tt = r / 5, xx = r - tt * 5;
    int t = 2 * to - 1 + tt, xg = 4 * xop - 1 + xx;
    if (t < 0 || t > 15 || xg < 0 || xg > 31) {
      f32x4 z = {0.f, 0.f, 0.f, 0.f};
      *(f32x4*)&tile[0][r * 512 + l * 4] = z;
      *(f32x4*)&tile[1][r * 512 + l * 4] = z;
    }
  }

  auto stage = [&](int buf, int ci) {
    const float* base = x + (size_t)(b * 20 + ci) * 262144;
    for (int g = tid; g < 1920; g += 256) {
      int r = g >> 7, l = g & 127;
      int tt = r / 5, xx = r - tt * 5;
      int t = 2 * to - 1 + tt, xg = 4 * xop - 1 + xx;
      if (t >= 0 && t <= 15 && xg >= 0 && xg <= 31) {  // wave-uniform branch
        const char* src = (const char*)(base + (size_t)t * 16384 + (size_t)xg * 512) + l * 16;
        gld(src, (char*)&tile[buf][r * 512] + l * 16);
      }
    }
  };

  float acc[20];
#pragma unroll
  for (int o = 0; o < 20; o++) acc[o] = 0.f;

  stage(0, 0);
  asm volatile("s_waitcnt vmcnt(0)" ::: "memory");
  __syncthreads();

#pragma unroll 1
  for (int ci = 0; ci < 20; ci++) {
    int cur = ci & 1;
    if (ci + 1 < 20) stage(cur ^ 1, ci + 1);
    const float* tb = tile[cur];
    const float* wcc = Wc + ci * 1620;
#pragma unroll
    for (int kt = 0; kt < 3; kt++)
#pragma unroll
      for (int kx = 0; kx < 3; kx++) {
        int rbase = (kt * 5 + 2 * j + kx) * 512;
#pragma unroll
        for (int ky = 0; ky < 3; ky++) {
          int yc = 2 * yo + ky - 1;
          bool yok = yc >= 0;
          int ycc = yok ? yc : 0;
          int ebase = rbase + ycc * 16;
          // kz = 0,1,2 -> z = 2zo-1, 2zo, 2zo+1
          float2 vz = *(const float2*)&tb[ebase + 2 * zo];
          int zlo = (zo > 0) ? (2 * zo - 1) : 0;
          float vl = tb[ebase + zlo];
          float v0 = (yok && zo > 0) ? vl : 0.f;
          float v1 = yok ? vz.x : 0.f;
          float v2 = yok ? vz.y : 0.f;
          int tap0 = ((kt * 3 + kx) * 3 + ky) * 3;
          const float* wp = wcc + tap0 * 20;  // uniform -> s_load
#pragma unroll
          for (int o = 0; o < 20; o++) {
            acc[o] += v0 * wp[o];
            acc[o] += v1 * wp[20 + o];
            acc[o] += v2 * wp[40 + o];
          }
        }
      }
    asm volatile("s_waitcnt vmcnt(0)" ::: "memory");
    __syncthreads();
  }

  int xo = 2 * xop + j;
  size_t obase = (size_t)b * 20 * 16384 + (((size_t)to * 16 + xo) * 16 + yo) * 8 + zo;
#pragma unroll
  for (int o = 0; o < 20; o++) out[obase + (size_t)o * 16384] = acc[o];
}

// ---------------- U-Net: convs (generic fallback, used for c2/c21/c3/c31) ----------------
__global__ void k_conv4d_elem(const float* __restrict__ in, const float* __restrict__ W,
                              float* __restrict__ out, int Ci,
                              int Ti, int Xi, int Yi, int Zi,
                              int To, int Xo, int Yo, int Zo, int stride, int n) {
  int idx = blockIdx.x * 256 + threadIdx.x;
  if (idx >= n) return;
  int zo = idx % Zo; int r = idx / Zo;
  int yo = r % Yo; r /= Yo;
  int xo = r % Xo; r /= Xo;
  int to = r % To; r /= To;
  int o = r % 20; int b = r / 20;
  float acc = 0.f;
  size_t in_sp = (size_t)Ti * Xi * Yi * Zi;
  for (int ci = 0; ci < Ci; ci++) {
    const float* base = in + ((size_t)b * Ci + ci) * in_sp;
    const float* wc = W + ((size_t)o * Ci + ci) * 81;
    for (int kt = 0; kt < 3; kt++) {
      int t = to * stride + kt - 1; if (t < 0 || t >= Ti) continue;
      for (int kx = 0; kx < 3; kx++) {
        int xx = xo * stride + kx - 1; if (xx < 0 || xx >= Xi) continue;
        for (int ky = 0; ky < 3; ky++) {
          int y = yo * stride + ky - 1; if (y < 0 || y >= Yi) continue;
          for (int kz = 0; kz < 3; kz++) {
            int z = zo * stride + kz - 1; if (z < 0 || z >= Zi) continue;
            acc += base[(((size_t)t * Xi + xx) * Yi + y) * Zi + z] * wc[((kt * 3 + kx) * 3 + ky) * 3 + kz];
          }
        }
      }
    }
  }
  out[idx] = acc;
}

// ---------------- BN ----------------
__global__ void k_bn_stats(const float* __restrict__ d, int S, float* __restrict__ stats) {
  int c = blockIdx.x;
  int tid = threadIdx.x;
  float s = 0.f, s2 = 0.f;
  for (int b = 0; b < 4; b++) {
    const float* p = d + ((size_t)b * 20 + c) * S;
    for (int i = tid; i < S; i += 256) { float v = p[i]; s += v; s2 += v * v; }
  }
  __shared__ float ls[256], lq[256];
  ls[tid] = s; lq[tid] = s2;
  __syncthreads();
  for (int off = 128; off > 0; off >>= 1) {
    if (tid < off) { ls[tid] += ls[tid + off]; lq[tid] += lq[tid + off]; }
    __syncthreads();
  }
  if (tid == 0) {
    float cnt = 4.f * (float)S;
    float mean = ls[0] / cnt;
    float var = lq[0] / cnt - mean * mean;
    stats[2 * c] = mean;
    stats[2 * c + 1] = rsqrtf(var + 1e-5f);
  }
}

__global__ void k_bn_apply(float* __restrict__ d, int S, const float* __restrict__ stats,
                           const float* __restrict__ g, const float* __restrict__ bb, int n) {
  int idx = blockIdx.x * 256 + threadIdx.x;
  if (idx >= n) return;
  int c = (idx / S) % 20;
  float v = d[idx];
  v = (v - stats[2 * c]) * stats[2 * c + 1] * g[c] + bb[c];
  d[idx] = (v >= 0.f) ? v : 0.1f * v;
}

// BN apply for oc1 + bf16 channels-last copy into CLd0 ci 0..19
__global__ void k_bn_apply_cl(float* __restrict__ d, const float* __restrict__ stats,
                              const float* __restrict__ g, const float* __restrict__ bb,
                              short* __restrict__ CL, int n) {
  int idx = blockIdx.x * 256 + threadIdx.x;
  if (idx >= n) return;
  int s = idx & 16383;
  int r = idx >> 14;
  int c = r % 20, b = r / 20;
  float v = d[idx];
  v = (v - stats[2 * c]) * stats[2 * c + 1] * g[c] + bb[c];
  v = (v >= 0.f) ? v : 0.1f * v;
  d[idx] = v;
  CL[((size_t)(b * 16384 + s)) * 40 + c] = f2bf(v);
}

// ---------------- deconv (ConvTranspose4d k=4 s=2 p=1), bias+lrelu fused ----------------
__device__ __forceinline__ int dcands(int p, int n_in, int* q, int* k) {
  int cnt = 0;
  int q0 = (p + 1) >> 1, k0 = p + 1 - 2 * q0;
  if (q0 >= 0 && q0 < n_in) { q[cnt] = q0; k[cnt] = k0; cnt++; }
  int q1 = q0 - 1, k1 = k0 + 2;
  if (q1 >= 0 && q1 < n_in) { q[cnt] = q1; k[cnt] = k1; cnt++; }
  return cnt;
}

__global__ void k_deconv4d(const float* __restrict__ in1, int Ci1,
                           const float* __restrict__ in2, int Ci2,
                           const float* __restrict__ W, const float* __restrict__ bias,
                           float* __restrict__ out,
                           int Ti, int Xi, int Yi, int Zi, int n) {
  int idx = blockIdx.x * 256 + threadIdx.x;
  if (idx >= n) return;
  int To = 2 * Ti, Xo = 2 * Xi, Yo = 2 * Yi, Zo = 2 * Zi;
  int zo = idx % Zo; int r = idx / Zo;
  int yo = r % Yo; r /= Yo;
  int xo = r % Xo; r /= Xo;
  int to = r % To; int b = r / To;
  int qt[2], kt[2], qx[2], kx[2], qy[2], ky[2], qz[2], kz[2];
  int nt = dcands(to, Ti, qt, kt), nx = dcands(xo, Xi, qx, kx);
  int ny = dcands(yo, Yi, qy, ky), nz = dcands(zo, Zi, qz, kz);
  float acc[20];
#pragma unroll
  for (int o = 0; o < 20; o++) acc[o] = 0.f;
  int Ci = Ci1 + Ci2;
  size_t in_sp = (size_t)Ti * Xi * Yi * Zi;
  for (int ci = 0; ci < Ci; ci++) {
    const float* base = (ci < Ci1) ? in1 + ((size_t)b * Ci1 + ci) * in_sp
                                   : in2 + ((size_t)b * Ci2 + (ci - Ci1)) * in_sp;
    const float* wc = W + (size_t)ci * 5120;  // [ci][o(20)][256]
    for (int it = 0; it < nt; it++)
      for (int ix = 0; ix < nx; ix++)
        for (int iy = 0; iy < ny; iy++)
          for (int iz = 0; iz < nz; iz++) {
            float v = base[(((size_t)qt[it] * Xi + qx[ix]) * Yi + qy[iy]) * Zi + qz[iz]];
            int tap = ((kt[it] * 4 + kx[ix]) * 4 + ky[iy]) * 4 + kz[iz];
#pragma unroll
            for (int o = 0; o < 20; o++) acc[o] += v * wc[o * 256 + tap];
          }
  }
  size_t osp = (size_t)To * Xo * Yo * Zo;
  size_t obase = (size_t)b * 20 * osp + (((size_t)to * Xo + xo) * Yo + yo) * Zo + zo;
#pragma unroll
  for (int o = 0; o < 20; o++) {
    float v2 = acc[o] + bias[o];
    out[obase + (size_t)o * osp] = (v2 >= 0.f) ? v2 : 0.1f * v2;
  }
}

// d1 deconv: in 4x8x8x4 (oc2|od2, Ci=40) -> out 8x16x16x8 written bf16 CL ci 20..39
__global__ void k_deconv_d1_cl(const float* __restrict__ in1, const float* __restrict__ in2,
                               const float* __restrict__ W, const float* __restrict__ bias,
                               short* __restrict__ CL, int n) {
  int idx = blockIdx.x * 256 + threadIdx.x;
  if (idx >= n) return;
  int zo = idx & 7; int r = idx >> 3;
  int yo = r & 15; r >>= 4;
  int xo = r & 15; r >>= 4;
  int to = r & 7; int b = r >> 3;
  int qt[2], kt[2], qx[2], kx[2], qy[2], ky[2], qz[2], kz[2];
  int nt = dcands(to, 4, qt, kt), nx = dcands(xo, 8, qx, kx);
  int ny = dcands(yo, 8, qy, ky), nz = dcands(zo, 4, qz, kz);
  float acc[20];
#pragma unroll
  for (int o = 0; o < 20; o++) acc[o] = 0.f;
  const size_t in_sp = 4 * 8 * 8 * 4;
  for (int ci = 0; ci < 40; ci++) {
    const float* base = (ci < 20) ? in1 + ((size_t)b * 20 + ci) * in_sp
                                  : in2 + ((size_t)b * 20 + (ci - 20)) * in_sp;
    const float* wc = W + (size_t)ci * 5120;
    for (int it = 0; it < nt; it++)
      for (int ix = 0; ix < nx; ix++)
        for (int iy = 0; iy < ny; iy++)
          for (int iz = 0; iz < nz; iz++) {
            float v = base[(((size_t)qt[it] * 8 + qx[ix]) * 8 + qy[iy]) * 4 + qz[iz]];
            int tap = ((kt[it] * 4 + kx[ix]) * 4 + ky[iy]) * 4 + kz[iz];
#pragma unroll
            for (int o = 0; o < 20; o++) acc[o] += v * wc[o * 256 + tap];
          }
  }
  size_t pos = (((size_t)b * 8 + to) * 16 + xo) * 16 * 8 + (size_t)yo * 8 + zo;
  short* dst = CL + pos * 40 + 20;
#pragma unroll
  for (int o = 0; o < 20; o++) {
    float v2 = acc[o] + bias[o];
    v2 = (v2 >= 0.f) ? v2 : 0.1f * v2;
    dst[o] = f2bf(v2);
  }
}

// fill Xcl ci 0..19 from x
__global__ void k_xcl_x(const float* __restrict__ x, short* __restrict__ Xcl, int n) {
  int i = blockIdx.x * 256 + threadIdx.x;
  if (i >= n) return;
  int s = i & 262143, b = i >> 18;
  short* dst = Xcl + (size_t)i * 40;
  const float* src = x + (size_t)b * 20 * 262144 + s;
#pragma unroll
  for (int c = 0; c < 20; c++) dst[c] = f2bf(src[(size_t)c * 262144]);
}

// pack out_w [20][40][81] + w_pw [20][20] -> Wp[tap(82)][mt(2)][m(16)][k(64)] bf16,
// bank-swizzled for LDS staging: short index i -> i ^ ((m&7)<<3)  (byte ^ ((m&7)<<4)).
// tap 81 = pointwise (x2) weights.
__global__ void k_pack_w(const float* __restrict__ out_w, const float* __restrict__ w_pw,
                         short* __restrict__ Wp, short* __restrict__ zp, int n) {
  int i = blockIdx.x * 256 + threadIdx.x;
  if (i >= n) return;
  int k = i & 63, m = (i >> 6) & 15, mt = (i >> 10) & 1, tap = i >> 11;
  int o = mt * 16 + m;
  float v = 0.f;
  if (o < 20 && k < 40) {
    if (tap < 81) v = out_w[((size_t)o * 40 + k) * 81 + tap];
    else if (k < 20) v = w_pw[o * 20 + k];
  }
  Wp[i ^ ((m & 7) << 3)] = f2bf(v);
  if (i < 64) zp[i] = 0;
}

// pack d0_w [40][20][256] -> Wd parity-class-major:
// [h(32)=cls*2+it][sub(8)=ix*4+iz*2+iy][mt(2)][m(16)][k(64)] bf16,
// bank-swizzled: element index i -> i ^ ((m&7)<<3)  (byte ^ ((row&7)<<4)).
__global__ void k_pack_wd(const float* __restrict__ d0_w, short* __restrict__ Wd, int n) {
  int i = blockIdx.x * 256 + threadIdx.x;
  if (i >= n) return;
  int k = i & 63, m = (i >> 6) & 15, mt = (i >> 10) & 1, sub = (i >> 11) & 7, h = i >> 14;
  int it = h & 1, cls = h >> 1;
  int ez = cls & 1, ey = (cls >> 1) & 1, ex = (cls >> 2) & 1, et = (cls >> 3) & 1;
  int iy = sub & 1, iz = (sub >> 1) & 1, ix = (sub >> 2) & 1;
  int kt = et ? (2 * it) : (1 + 2 * it);
  int kx = ex ? (2 * ix) : (1 + 2 * ix);
  int ky = ey ? (2 * iy) : (1 + 2 * iy);
  int kz = ez ? (2 * iz) : (1 + 2 * iz);
  int tap = ((kt * 4 + kx) * 4 + ky) * 4 + kz;
  int o = mt * 16 + m;
  float v = (o < 20 && k < 40) ? d0_w[((size_t)k * 20 + o) * 256 + tap] : 0.f;
  Wd[i ^ ((m & 7) << 3)] = f2bf(v);
}

// ---------------- d0 deconv via MFMA (parity-class, LDS-staged) ----------------
__global__ __launch_bounds__(512) void k_d0_mfma(
    const short* __restrict__ CLd0, const short* __restrict__ Wd,
    const float* __restrict__ bias, short* __restrict__ Xcl) {
  __shared__ __align__(16) char lds[157696];  // 9*10240 B-planes + 2*32768 A dbuf
  char* lds_a = lds + 92160;
  int bid = blockIdx.x;
  int ux = bid & 15, ut = (bid >> 4) & 7, b = bid >> 7;
  int tid = threadIdx.x;
  int uz = tid >> 6;
  int lane = tid & 63, ln15 = lane & 15, kg = lane >> 4;  // ln15 = uy

  const char* xb = (const char*)CLd0;
  const char* wb = (const char*)Wd;

  auto gld = [](const char* src, char* dst) {
    __builtin_amdgcn_global_load_lds(
        (const __attribute__((address_space(1))) void*)src,
        (__attribute__((address_space(3))) void*)dst, 16, 0, 0);
  };

  // ---- prologue: stage B planes (swizzle baked into per-lane global src) ----
#pragma unroll
  for (int pt = 0; pt < 3; pt++) {
    int qt = ut - 1 + pt;
    if (qt < 0 || qt > 7) continue;
#pragma unroll
    for (int px = 0; px < 3; px++) {
      int qx = ux - 1 + px;
      if (qx < 0 || qx > 15) continue;
      const char* src = xb + (size_t)((b * 8 + qt) * 16 + qx) * 10240;
      char* dst = lds + (pt * 3 + px) * 10240;
      for (int g = tid; g < 640; g += 512) {
        int key = ((g / 40) & 7) << 4;
        gld(src + ((g * 16) ^ key), dst + g * 16);
      }
    }
  }
  // stage A half-block h=0 (pack is pre-swizzled -> linear copy)
  for (int g = tid; g < 2048; g += 512) gld(wb + g * 16, lds_a + g * 16);
  asm volatile("s_waitcnt vmcnt(0)" ::: "memory");
  __syncthreads();

  bf16x8 zv = {0, 0, 0, 0, 0, 0, 0, 0};
  int aswz = ((ln15 * 128 + kg * 16) ^ ((ln15 & 7) << 4));

#pragma unroll 1
  for (int cls = 0; cls < 16; cls++) {
    int ez = cls & 1, ey = (cls >> 1) & 1, ex = (cls >> 2) & 1, et = (cls >> 3) & 1;
    f32x4 acc0, acc1;
#pragma unroll
    for (int j = 0; j < 4; j++) { acc0[j] = 0.f; acc1[j] = 0.f; }
#pragma unroll
    for (int it = 0; it < 2; it++) {
      int h = cls * 2 + it;
      // stage next A half-block into the other buffer
      if (h + 1 < 32) {
        const char* asrc = wb + (size_t)(h + 1) * 32768;
        char* adst = lds_a + (it ^ 1) * 32768;
        for (int g = tid; g < 2048; g += 512) gld(asrc + g * 16, adst + g * 16);
      }
      const char* ab = lds_a + it * 32768;
      int kt_q = ut + (et ? (1 - it) : (-it));
      if (kt_q >= 0 && kt_q <= 7) {
        int pt = kt_q - ut + 1;
#pragma unroll
        for (int ix = 0; ix < 2; ix++) {
          int qx = ux + (ex ? (1 - ix) : (-ix));
          if (qx < 0 || qx > 15) continue;
          int px = qx - ux + 1;
          const char* pbase = lds + (pt * 3 + px) * 10240;
#pragma unroll
          for (int iz = 0; iz < 2; iz++) {
            int qz = uz + (ez ? (1 - iz) : (-iz));
            if (qz < 0 || qz > 7) continue;
#pragma unroll
            for (int iy = 0; iy < 2; iy++) {
              int qy = ln15 + (ey ? (1 - iy) : (-iy));
              bool yok = (qy >= 0) && (qy < 16);
              int qyc = yok ? qy : 0;
              int bkey = (qyc & 7) << 4;
              const char* abase = ab + (ix * 4 + iz * 2 + iy) * 4096;
#pragma unroll
              for (int ch = 0; ch < 2; ch++) {
                int co = ch ? 64 : kg * 16;  // ch=1: broadcast ci 32..39 (k>=40 wts are 0)
                int boff = (qyc * 640 + qz * 80 + co) ^ bkey;
                bf16x8 bvv = *(const bf16x8*)(pbase + boff);
                bf16x8 bv = yok ? bvv : zv;
                int aoff = (ch ? (aswz ^ 64) : aswz);
                bf16x8 a0 = *(const bf16x8*)(abase + aoff);
                bf16x8 a1 = *(const bf16x8*)(abase + 2048 + aoff);
                acc0 = __builtin_amdgcn_mfma_f32_16x16x32_bf16(a0, bv, acc0, 0, 0, 0);
                acc1 = __builtin_amdgcn_mfma_f32_16x16x32_bf16(a1, bv, acc1, 0, 0, 0);
              }
            }
          }
        }
      }
      asm volatile("s_waitcnt vmcnt(0)" ::: "memory");
      __syncthreads();
    }
    int to = 2 * ut + et, xo = 2 * ux + ex, zo = 2 * uz + ez, yo = 2 * ln15 + ey;
    long opos = ((((long)b * 16 + to) * 32 + xo) * 32 + yo) * 16 + zo;
    short* dst = Xcl + opos * 40 + 20;
    {
      unsigned hh[4];
#pragma unroll
      for (int r = 0; r < 4; r++) {
        float v = acc0[r] + bias[kg * 4 + r];
        v = (v >= 0.f) ? v : 0.1f * v;
        hh[r] = (unsigned)(unsigned short)f2bf(v);
      }
      uint2 u;
      u.x = hh[0] | (hh[1] << 16);
      u.y = hh[2] | (hh[3] << 16);
      *(uint2*)(dst + kg * 4) = u;
    }
    if (kg == 0) {
      unsigned hh[4];
#pragma unroll
      for (int r = 0; r < 4; r++) {
        float v = acc1[r] + bias[16 + r];
        v = (v >= 0.f) ? v : 0.1f * v;
        hh[r] = (unsigned)(unsigned short)f2bf(v);
      }
      uint2 u;
      u.x = hh[0] | (hh[1] << 16);
      u.y = hh[2] | (hh[3] << 16);
      *(uint2*)(dst + 16) = u;
    }
  }
}

// ---------------- final conv: fully LDS-staged bf16 MFMA implicit GEMM ----------------
__global__ __launch_bounds__(512) void k_fconv_mfma(
    const short* __restrict__ Xcl, const short* __restrict__ Wp,
    const float* __restrict__ bias, const float* __restrict__ bpw,
    float* __restrict__ io) {
  __shared__ __align__(16) char ldsB[2][40960];
  __shared__ __align__(16) char ldsW[2][36864];
  int bid = blockIdx.x;
  int xcd = bid & 7, idx = bid >> 3;
  int b = xcd >> 1, xh = xcd & 1;
  // t0-major within each XCD: working set 3 xi-slabs x 16 ti x 40KB ~ 1.9MB < 4MB L2
  int t0 = idx & 15, x0 = xh * 16 + ((idx >> 4) & 15);
  int tid = threadIdx.x;
  int lane = tid & 63;
  int ln15 = lane & 15, kg = lane >> 4;
  int ybase = (tid >> 6) * 4;

  // valid (kt,kx) slab list, 4 bits per entry (code = kt*4+kx; center = 5)
  unsigned long long codes = 0ull;
  int ns = 0;
  for (int kt = 0; kt < 3; kt++) {
    int ti = t0 + kt - 1;
    if (ti < 0 || ti > 15) continue;
    for (int kx = 0; kx < 3; kx++) {
      int xi = x0 + kx - 1;
      if (xi < 0 || xi > 31) continue;
      codes |= (unsigned long long)(kt * 4 + kx) << (4 * ns);
      ns++;
    }
  }

  const char* xb = (const char*)Xcl;
  const char* wb = (const char*)Wp;

  auto gld = [](const char* src, char* dst) {
    __builtin_amdgcn_global_load_lds(
        (const __attribute__((address_space(1))) void*)src,
        (__attribute__((address_space(3))) void*)dst, 16, 0, 0);
  };

  auto stage = [&](int buf, int code) {
    int kt = code >> 2, kx = code & 3;
    int ti = t0 + kt - 1, xi = x0 + kx - 1;
    const char* src = xb + (size_t)((b * 16 + ti) * 32 + xi) * 512 * 80;
    char* dstB = ldsB[buf];
#pragma unroll
    for (int s = 0; s < 5; s++) {
      int off = s * 8192 + tid * 16;
      gld(src + off, dstB + off);
    }
    // 9-tap contiguous weight run for this slab: taps (kt*3+kx)*9 .. +8
    const char* wsrc = wb + (size_t)(kt * 3 + kx) * 9 * 4096;
    char* dstW = ldsW[buf];
    for (int g = tid; g < 2304; g += 512) gld(wsrc + g * 16, dstW + g * 16);
  };

  f32x4 acc[2][4];
#pragma unroll
  for (int mt = 0; mt < 2; mt++)
#pragma unroll
    for (int nt = 0; nt < 4; nt++)
#pragma unroll
      for (int j = 0; j < 4; j++) acc[mt][nt][j] = 0.f;

  int awz0 = (ln15 * 128 + kg * 16) ^ ((ln15 & 7) << 4);
  int awz1 = (ln15 * 128 + 64 + kg * 16) ^ ((ln15 & 7) << 4);

  stage(0, (int)(codes & 15));
  asm volatile("s_waitcnt vmcnt(0)" ::: "memory");
  __syncthreads();

  int cur = 0;
#pragma unroll 1
  for (int i = 0; i < ns; i++) {
    const char* bufB = ldsB[cur];
    const char* bufW = ldsW[cur];
    if (i + 1 < ns) stage(cur ^ 1, (int)((codes >> (4 * (i + 1))) & 15));
    int code = (int)((codes >> (4 * i)) & 15);
    bf16x8 zv = {0, 0, 0, 0, 0, 0, 0, 0};
#pragma unroll
    for (int kz = 0; kz < 3; kz++) {
      int zi = ln15 + kz - 1;
      bool zok = (zi >= 0) && (zi < 16);
      int zc = zok ? zi : 0;
#pragma unroll
      for (int ch = 0; ch < 2; ch++) {
        int co = ch ? 64 : kg * 16;  // ch=1: broadcast ci 32..39 chunk to all kg
        bf16x8 bv[6];
#pragma unroll
        for (int j = 0; j < 6; j++) {
          int yi = ybase + j - 1;
          int yc = (yi < 0) ? 0 : ((yi > 31) ? 31 : yi);
          bf16x8 v = *(const bf16x8*)(bufB + (size_t)(yc * 16 + zc) * 80 + co);
          bool ok = zok && (yi >= 0) && (yi < 32);
          bv[j] = ok ? v : zv;
        }
        int awz = ch ? awz1 : awz0;
        bf16x8 av[3][2];
#pragma unroll
        for (int ky = 0; ky < 3; ky++) {
          const char* wt = bufW + (size_t)(ky * 3 + kz) * 4096;
          av[ky][0] = *(const bf16x8*)(wt + awz);
          av[ky][1] = *(const bf16x8*)(wt + 2048 + awz);
        }
#pragma unroll
        for (int ky = 0; ky < 3; ky++)
#pragma unroll
          for (int nt = 0; nt < 4; nt++) {
            acc[0][nt] = __builtin_amdgcn_mfma_f32_16x16x32_bf16(av[ky][0], bv[nt + ky], acc[0][nt], 0, 0, 0);
            acc[1][nt] = __builtin_amdgcn_mfma_f32_16x16x32_bf16(av[ky][1], bv[nt + ky], acc[1][nt], 0, 0, 0);
          }
      }
    }
    if (code == 5) {
      // center slab: fused pointwise (x2) tap, ci 0..19 (weights zero for k>=20)
      const char* wt = wb + (size_t)81 * 4096;
      bf16x8 a0 = *(const bf16x8*)(wt + awz0);
      bf16x8 a1 = *(const bf16x8*)(wt + 2048 + awz0);
#pragma unroll
      for (int nt = 0; nt < 4; nt++) {
        bf16x8 bv = *(const bf16x8*)(bufB + (size_t)((ybase + nt) * 16 + ln15) * 80 + kg * 16);
        acc[0][nt] = __builtin_amdgcn_mfma_f32_16x16x32_bf16(a0, bv, acc[0][nt], 0, 0, 0);
        acc[1][nt] = __builtin_amdgcn_mfma_f32_16x16x32_bf16(a1, bv, acc[1][nt], 0, 0, 0);
      }
    }
    asm volatile("s_waitcnt vmcnt(0)" ::: "memory");
    __syncthreads();
    cur ^= 1;
  }

#pragma unroll
  for (int mt = 0; mt < 2; mt++)
#pragma unroll
    for (int r = 0; r < 4; r++) {
      int o = mt * 16 + kg * 4 + r;
      if (o >= 20) continue;
      float bo = bias[o] + bpw[o];
#pragma unroll
      for (int nt = 0; nt < 4; nt++) {
        int y = ybase + nt;
        size_t oidx = ((size_t)(b * 20 + o)) * 262144 +
                      ((((size_t)t0 * 32 + x0) * 32 + y) * 16 + ln15);
        float v = acc[mt][nt][r] + bo + io[oidx];
        io[oidx] = fmaxf(v, 0.f);
      }
    }
}

extern "C" void kernel_launch(void* const* d_in, const int* in_sizes, int n_in,
                              void* d_out, int out_size, void* d_ws, size_t ws_size,
                              hipStream_t stream) {
  const float* x     = (const float*)d_in[0];
  const float* sw1   = (const float*)d_in[1];
  const float* sw2   = (const float*)d_in[2];
  const float* sw3   = (const float*)d_in[3];
  const float* sw4   = (const float*)d_in[4];
  const float* w_pw  = (const float*)d_in[5];
  const float* b_pw  = (const float*)d_in[6];
  const float* c1_w  = (const float*)d_in[7];
  const float* c2_w  = (const float*)d_in[8];
  const float* c21_w = (const float*)d_in[9];
  const float* c3_w  = (const float*)d_in[10];
  const float* c31_w = (const float*)d_in[11];
  const float* bn1_g = (const float*)d_in[12];
  const float* bn1_b = (const float*)d_in[13];
  const float* bn2_g = (const float*)d_in[14];
  const float* bn2_b = (const float*)d_in[15];
  const float* bn21_g = (const float*)d_in[16];
  const float* bn21_b = (const float*)d_in[17];
  const float* bn3_g = (const float*)d_in[18];
  const float* bn3_b = (const float*)d_in[19];
  const float* bn31_g = (const float*)d_in[20];
  const float* bn31_b = (const float*)d_in[21];
  const float* d2_w  = (const float*)d_in[22];
  const float* d2_b  = (const float*)d_in[23];
  const float* d1_w  = (const float*)d_in[24];
  const float* d1_b  = (const float*)d_in[25];
  const float* d0_w  = (const float*)d_in[26];
  const float* d0_b  = (const float*)d_in[27];
  const float* out_w = (const float*)d_in[28];
  const float* out_b = (const float*)d_in[29];
  float* out = (float*)d_out;
  float* ws = (float*)d_ws;

  // spectral arena (phase 1 only)
  float2* A  = (float2*)(ws);
  float2* Bb = (float2*)(ws + 10485760);
  float2* Cb = (float2*)(ws + 13107200);
  float2* Dd = (float2*)(ws + 14417920);
  float2* Ee = (float2*)(ws + 15073280);
  float2* Ff = (float2*)(ws + 15728640);
  float2* Gg = (float2*)(ws + 16384000);
  // twiddle tables: live only during spectral phase; region inside Xcl span,
  // beyond the spectral arena end (17,039,360 fl), overwritten later by k_xcl_x.
  float2* Twid = (float2*)(ws + 23000000);

  // U-Net arena
  float* oc1   = ws;
  short* CLd0  = (short*)(ws + 1310720);
  float* Wc1   = ws + 1310720;  // aliases CLd0 region: used only between pack and bn_apply_cl
  float* oc2a  = ws + 2621440;
  float* oc2   = ws + 2703360;
  float* oc3a  = ws + 2785280;
  float* oc3   = ws + 2790400;
  float* od2   = ws + 2795520;
  short* Xcl   = (short*)(ws + 2877440);
  float* stats = ws + 23848960;
  short* Wd = (short*)(ws);
  short* Wp = (short*)(ws + 262144);
  short* zp = (short*)(ws + 349184);

  auto nb = [](int n) { return (n + 255) / 256; };
  dim3 blk(256);

  // ---- twiddle tables ----
  k_twid<<<1, 64, 0, stream>>>(Twid);

  // ---- spectral path: x1 -> d_out ----
  k_fwd_z<<<nb(1310720), blk, 0, stream>>>(x, Twid, A, 1310720);
  k_fwd_y<<<nb(1310720), blk, 0, stream>>>(A, Twid, Bb, 1310720);
  k_fwd_x<<<nb(655360), blk, 0, stream>>>(Bb, Twid, Cb, 655360);
  k_fwd_t<<<nb(327680), blk, 0, stream>>>(Cb, Twid, Dd, 327680);
  k_fwd_c<<<nb(327680), blk, 0, stream>>>(Dd, Twid, Ee, 327680);
  k_fwd_b<<<nb(327680), blk, 0, stream>>>(Ee, Twid, Ff, 327680);
  k_smul<<<nb(327680), blk, 0, stream>>>(Ff, sw1, sw2, sw3, sw4, Gg, 327680);
  k_inv_t<<<nb(655360), blk, 0, stream>>>(Gg, Twid, Cb, 655360);
  k_inv_x<<<nb(1310720), blk, 0, stream>>>(Cb, Twid, Bb, 1310720);
  k_inv_yz<<<nb(1310720), blk, 0, stream>>>(Bb, Twid, out, 1310720);

  // ---- Xcl ci 0..19 from x; c1 weight pack (into dead CLd0 region) ----
  k_pack_c1<<<nb(32400), blk, 0, stream>>>(c1_w, Wc1, 32400);
  k_xcl_x<<<nb(1048576), blk, 0, stream>>>(x, Xcl, 1048576);

  // ---- U-Net encoder ----
  k_c1<<<256, blk, 0, stream>>>(x, Wc1, oc1);
  k_bn_stats<<<20, blk, 0, stream>>>(oc1, 16384, stats);
  k_bn_apply_cl<<<nb(1310720), blk, 0, stream>>>(oc1, stats, bn1_g, bn1_b, CLd0, 1310720);

  k_conv4d_elem<<<nb(81920), blk, 0, stream>>>(oc1, c2_w, oc2a, 20,
                                               8, 16, 16, 8, 4, 8, 8, 4, 2, 81920);
  k_bn_stats<<<20, blk, 0, stream>>>(oc2a, 1024, stats);
  k_bn_apply<<<nb(81920), blk, 0, stream>>>(oc2a, 1024, stats, bn2_g, bn2_b, 81920);

  k_conv4d_elem<<<nb(81920), blk, 0, stream>>>(oc2a, c21_w, oc2, 20,
                                               4, 8, 8, 4, 4, 8, 8, 4, 1, 81920);
  k_bn_stats<<<20, blk, 0, stream>>>(oc2, 1024, stats);
  k_bn_apply<<<nb(81920), blk, 0, stream>>>(oc2, 1024, stats, bn21_g, bn21_b, 81920);

  k_conv4d_elem<<<nb(5120), blk, 0, stream>>>(oc2, c3_w, oc3a, 20,
                                              4, 8, 8, 4, 2, 4, 4, 2, 2, 5120);
  k_bn_stats<<<20, blk, 0, stream>>>(oc3a, 64, stats);
  k_bn_apply<<<nb(5120), blk, 0, stream>>>(oc3a, 64, stats, bn3_g, bn3_b, 5120);

  k_conv4d_elem<<<nb(5120), blk, 0, stream>>>(oc3a, c31_w, oc3, 20,
                                              2, 4, 4, 2, 2, 4, 4, 2, 1, 5120);
  k_bn_stats<<<20, blk, 0, stream>>>(oc3, 64, stats);
  k_bn_apply<<<nb(5120), blk, 0, stream>>>(oc3, 64, stats, bn31_g, bn31_b, 5120);

  // ---- decoder ----
  k_deconv4d<<<nb(4096), blk, 0, stream>>>(oc3, 20, nullptr, 0, d2_w, d2_b, od2,
                                           2, 4, 4, 2, 4096);
  k_deconv_d1_cl<<<nb(65536), blk, 0, stream>>>(oc2, od2, d1_w, d1_b, CLd0, 65536);

  // weight packs
  k_pack_w<<<nb(167936), blk, 0, stream>>>(out_w, w_pw, Wp, zp, 167936);
  k_pack_wd<<<nb(524288), blk, 0, stream>>>(d0_w, Wd, 524288);

  // d0 deconv via MFMA (LDS-staged) -> Xcl ci 20..39
  k_d0_mfma<<<512, dim3(512), 0, stream>>>(CLd0, Wd, d0_b, Xcl);

  // final conv via MFMA (fully LDS-staged), fused +bias +x1 +x2(pointwise) +relu into d_out
  k_fconv_mfma<<<2048, dim3(512), 0, stream>>>(Xcl, Wp, out_b, b_pw, out);
}

// Round 5
// 2064.519 us; speedup vs baseline: 1.6462x; 1.0630x over previous
//
#include <hip/hip_runtime.h>

#define PI2 6.28318530717958647692f

typedef __attribute__((ext_vector_type(8))) short bf16x8;
typedef __attribute__((ext_vector_type(4))) float f32x4;

__device__ __forceinline__ void cfma(float2& acc, float2 a, float2 t) {
  acc.x += a.x * t.x - a.y * t.y;
  acc.y += a.x * t.y + a.y * t.x;
}
// multiply by conj(t) (inverse twiddle), t = e^{-i\theta}
__device__ __forceinline__ void cfmac(float2& acc, float2 a, float2 t) {
  acc.x += a.x * t.x + a.y * t.y;
  acc.y += a.y * t.x - a.x * t.y;
}

__device__ __forceinline__ short f2bf(float f) {
  unsigned u = __float_as_uint(f);
  unsigned r = (u + 0x7fff + ((u >> 16) & 1)) >> 16;
  return (short)r;
}

// twiddle tables: T[0..31]=e^{-2pi i m/32}, T[32..47]=N16, T[48..67]=N20, T[68..71]=N4
__global__ void k_twid(float2* __restrict__ T) {
  int i = threadIdx.x;
  float s, c;
  if (i < 32) { __sincosf(-PI2 * (float)i / 32.f, &s, &c); T[i] = make_float2(c, s); }
  if (i < 16) { __sincosf(-PI2 * (float)i / 16.f, &s, &c); T[32 + i] = make_float2(c, s); }
  if (i < 20) { __sincosf(-PI2 * (float)i / 20.f, &s, &c); T[48 + i] = make_float2(c, s); }
  if (i < 4)  { __sincosf(-PI2 * (float)i / 4.f,  &s, &c); T[68 + i] = make_float2(c, s); }
}

// ---------------- spectral forward ----------------
__global__ void k_fwd_z(const float* __restrict__ x, const float2* __restrict__ T,
                        float2* __restrict__ out, int nrows) {
  __shared__ float2 tw[16];
  if (threadIdx.x < 16) tw[threadIdx.x] = T[32 + threadIdx.x];
  __syncthreads();
  int r = blockIdx.x * 256 + threadIdx.x;
  if (r >= nrows) return;
  const float* p = x + (size_t)r * 16;
  float v[16];
#pragma unroll
  for (int z = 0; z < 16; z++) v[z] = p[z];
#pragma unroll
  for (int zk = 0; zk < 4; zk++) {
    float re = 0.f, im = 0.f;
#pragma unroll
    for (int z = 0; z < 16; z++) {
      float2 t = tw[(z * zk) & 15];
      re += v[z] * t.x;
      im += v[z] * t.y;
    }
    out[(size_t)r * 4 + zk] = make_float2(re, im);
  }
}

__global__ void k_fwd_y(const float2* __restrict__ in, const float2* __restrict__ T,
                        float2* __restrict__ out, int n) {
  __shared__ float2 tw[32];
  if (threadIdx.x < 32) tw[threadIdx.x] = T[threadIdx.x];
  __syncthreads();
  int i = blockIdx.x * 256 + threadIdx.x;
  if (i >= n) return;
  int zk = i & 3, yk = (i >> 2) & 7, slab = i >> 5;
  const float2* p = in + (size_t)slab * 128 + zk;
  float2 acc = make_float2(0.f, 0.f);
  for (int y = 0; y < 32; y++) cfma(acc, p[y * 4], tw[(y * yk) & 31]);
  out[i] = acc;
}

__global__ void k_fwd_x(const float2* __restrict__ in, const float2* __restrict__ T,
                        float2* __restrict__ out, int n) {
  __shared__ float2 tw[32];
  if (threadIdx.x < 32) tw[threadIdx.x] = T[threadIdx.x];
  __syncthreads();
  int i = blockIdx.x * 256 + threadIdx.x;
  if (i >= n) return;
  int zk = i & 3, yk = (i >> 2) & 7, xi = (i >> 5) & 15, slab = i >> 9;
  int xk = (xi < 8) ? xi : xi + 16;
  const float2* p = in + (size_t)slab * 1024 + yk * 4 + zk;
  float2 acc = make_float2(0.f, 0.f);
  for (int xx = 0; xx < 32; xx++) cfma(acc, p[xx * 32], tw[(xx * xk) & 31]);
  out[i] = acc;
}

__global__ void k_fwd_t(const float2* __restrict__ in, const float2* __restrict__ T,
                        float2* __restrict__ out, int n) {
  __shared__ float2 tw[16];
  if (threadIdx.x < 16) tw[threadIdx.x] = T[32 + threadIdx.x];
  __syncthreads();
  int i = blockIdx.x * 256 + threadIdx.x;
  if (i >= n) return;
  int zk = i & 3, yk = (i >> 2) & 7, xi = (i >> 5) & 15, ti = (i >> 9) & 7, bc = i >> 12;
  int tk = (ti < 4) ? ti : ti + 8;
  const float2* p = in + (size_t)bc * 8192 + xi * 32 + yk * 4 + zk;
  float2 acc = make_float2(0.f, 0.f);
  for (int t = 0; t < 16; t++) cfma(acc, p[t * 512], tw[(t * tk) & 15]);
  out[i] = acc;
}

__global__ void k_fwd_c(const float2* __restrict__ in, const float2* __restrict__ T,
                        float2* __restrict__ out, int n) {
  __shared__ float2 tw[20];
  if (threadIdx.x < 20) tw[threadIdx.x] = T[48 + threadIdx.x];
  __syncthreads();
  int i = blockIdx.x * 256 + threadIdx.x;
  if (i >= n) return;
  int mode = i & 4095, r = i >> 12, ck = r % 20, b = r / 20;
  const float2* p = in + (size_t)b * 81920 + mode;
  float2 acc = make_float2(0.f, 0.f);
  int idx = 0;
  for (int c = 0; c < 20; c++) {
    cfma(acc, p[(size_t)c * 4096], tw[idx]);
    idx += ck; if (idx >= 20) idx -= 20;
  }
  out[i] = acc;
}

__global__ void k_fwd_b(const float2* __restrict__ in, const float2* __restrict__ T,
                        float2* __restrict__ out, int n) {
  __shared__ float2 tw[4];
  if (threadIdx.x < 4) tw[threadIdx.x] = T[68 + threadIdx.x];
  __syncthreads();
  int i = blockIdx.x * 256 + threadIdx.x;
  if (i >= n) return;
  int mode = i & 4095, r = i >> 12, ck = r % 20, bk = r / 20;
  const float2* p = in + (size_t)ck * 4096 + mode;
  float2 acc = make_float2(0.f, 0.f);
#pragma unroll
  for (int b = 0; b < 4; b++) cfma(acc, p[(size_t)b * 81920], tw[(b * bk) & 3]);
  out[i] = acc;
}

__global__ void k_smul(const float2* __restrict__ in,
                       const float* __restrict__ sw1, const float* __restrict__ sw2,
                       const float* __restrict__ sw3, const float* __restrict__ sw4,
                       float2* __restrict__ out, int n) {
  int i = blockIdx.x * 256 + threadIdx.x;
  if (i >= n) return;
  int mode = i & 4095, r = i >> 12, o = r % 20, bk = r / 20;
  int ti = mode >> 9, xi = (mode >> 5) & 15, yk = (mode >> 2) & 7, zk = mode & 3;
  const float* w = (ti < 4) ? ((xi < 8) ? sw1 : sw3) : ((xi < 8) ? sw2 : sw4);
  int tl = ti & 3, xl = xi & 7;
  const float2* wp = (const float2*)w;
  const float2* ip = in + (size_t)bk * 81920 + mode;
  size_t wsub = (size_t)o * 1024 + (size_t)tl * 256 + (size_t)xl * 32 + yk * 4 + zk;
  float2 acc = make_float2(0.f, 0.f);
  for (int ci = 0; ci < 20; ci++) cfma(acc, ip[(size_t)ci * 4096], wp[(size_t)ci * 20480 + wsub]);
  out[i] = acc;
}

// ---------------- spectral inverse ----------------
__global__ void k_inv_t(const float2* __restrict__ in, const float2* __restrict__ T,
                        float2* __restrict__ out, int n) {
  __shared__ float2 tw[16];
  if (threadIdx.x < 16) tw[threadIdx.x] = T[32 + threadIdx.x];
  __syncthreads();
  int i = blockIdx.x * 256 + threadIdx.x;
  if (i >= n) return;
  int zk = i & 3, yk = (i >> 2) & 7, xi = (i >> 5) & 15, tp = (i >> 9) & 15, bc = i >> 13;
  const float2* p = in + (size_t)bc * 4096 + xi * 32 + yk * 4 + zk;
  float2 acc = make_float2(0.f, 0.f);
#pragma unroll
  for (int ti = 0; ti < 8; ti++) {
    int tk = (ti < 4) ? ti : ti + 8;
    cfmac(acc, p[ti * 512], tw[(tk * tp) & 15]);
  }
  out[i] = acc;
}

__global__ void k_inv_x(const float2* __restrict__ in, const float2* __restrict__ T,
                        float2* __restrict__ out, int n) {
  __shared__ float2 tw[32];
  if (threadIdx.x < 32) tw[threadIdx.x] = T[threadIdx.x];
  __syncthreads();
  int i = blockIdx.x * 256 + threadIdx.x;
  if (i >= n) return;
  int zk = i & 3, yk = (i >> 2) & 7, xp = (i >> 5) & 31, tp = (i >> 10) & 15, bc = i >> 14;
  const float2* p = in + (size_t)bc * 8192 + tp * 512 + yk * 4 + zk;
  float2 acc = make_float2(0.f, 0.f);
#pragma unroll
  for (int xi = 0; xi < 16; xi++) {
    int xk = (xi < 8) ? xi : xi + 16;
    cfmac(acc, p[xi * 32], tw[(xk * xp) & 31]);
  }
  out[i] = acc;
}

// fused inverse-y + c2r-z: thread per (bc,tp,xp,yp), emits full 16-z real row.
__global__ void k_inv_yz(const float2* __restrict__ in, const float2* __restrict__ T,
                         float* __restrict__ out, int n) {
  __shared__ float2 tw[48];  // 0..31: N32, 32..47: N16
  if (threadIdx.x < 48) tw[threadIdx.x] = T[threadIdx.x];
  __syncthreads();
  int i = blockIdx.x * 256 + threadIdx.x;
  if (i >= n) return;
  int yp = i & 31;
  const float2* p = in + (size_t)(i >> 5) * 32;  // [bc][tp][xp] slab: [yk8][zk4]
  float2 Ay[4];
#pragma unroll
  for (int zk = 0; zk < 4; zk++) Ay[zk] = make_float2(0.f, 0.f);
#pragma unroll
  for (int yk = 0; yk < 8; yk++) {
    float2 w = tw[(yk * yp) & 31];
#pragma unroll
    for (int zk = 0; zk < 4; zk++) cfmac(Ay[zk], p[yk * 4 + zk], w);
  }
  float res[16];
#pragma unroll
  for (int zp = 0; zp < 16; zp++) {
    float v = Ay[0].x;
#pragma unroll
    for (int zk = 1; zk < 4; zk++) {
      float2 t = tw[32 + ((zk * zp) & 15)];
      v += 2.f * (Ay[zk].x * t.x + Ay[zk].y * t.y);
    }
    res[zp] = v * (1.f / 262144.f);
  }
  float4* o4 = (float4*)(out + (size_t)i * 16);
#pragma unroll
  for (int q = 0; q < 4; q++)
    o4[q] = make_float4(res[q * 4], res[q * 4 + 1], res[q * 4 + 2], res[q * 4 + 3]);
}

// ---------------- c1 conv (stride 2, 20->20) LDS-tiled, fp32-exact ----------------
// pack c1_w [o][ci][81] -> Wc1p[ci][tap][o] (contiguous per ci)
__global__ void k_pack_c1(const float* __restrict__ c1_w, float* __restrict__ Wc, int n) {
  int i = blockIdx.x * 256 + threadIdx.x;
  if (i >= n) return;
  int o = i % 20; int r = i / 20;
  int tap = r % 81; int ci = r / 81;
  Wc[i] = c1_w[((size_t)o * 20 + ci) * 81 + tap];
}

// Block = (b,to,xo): 4*8*16 = 512 blocks x 128 threads (zo8, yo16), one output each.
// Per ci: input = 9 contiguous (t,x) rows x 512 f AND the 1620 weights, both staged
// into LDS via global_load_lds (double-buffered). Weight reads are bulk ds_read_b128
// into registers (60 per tap-unit), data reads b64/b32. Boundary rows zero-filled
// once -> zero-adds keep fp32 accumulation order identical to the reference skip.
__global__ __launch_bounds__(128) void k_c1(
    const float* __restrict__ x, const float* __restrict__ Wc,
    float* __restrict__ out) {
  __shared__ __align__(16) float tileX[2][4608];  // [tt3][xx3][y32][z16]
  __shared__ __align__(16) float tileW[2][1620];
  int bid = blockIdx.x;
  int xo = bid & 15, to = (bid >> 4) & 7, b = bid >> 7;
  int tid = threadIdx.x;
  int zo = tid & 7, yo = tid >> 3;

  auto gld = [](const char* src, char* dst) {
    __builtin_amdgcn_global_load_lds(
        (const __attribute__((address_space(1))) void*)src,
        (__attribute__((address_space(3))) void*)dst, 16, 0, 0);
  };

  // zero-fill invalid (t,x) rows in BOTH buffers once
  for (int g = tid; g < 1152; g += 128) {
    int r = g >> 7, l = g & 127;
    int tt = r / 3, xx = r - tt * 3;
    int t = 2 * to - 1 + tt, xg = 2 * xo - 1 + xx;
    if (t < 0 || t > 15 || xg < 0 || xg > 31) {
      f32x4 z = {0.f, 0.f, 0.f, 0.f};
      *(f32x4*)&tileX[0][r * 512 + l * 4] = z;
      *(f32x4*)&tileX[1][r * 512 + l * 4] = z;
    }
  }

  auto stage = [&](int buf, int ci) {
    const float* base = x + (size_t)(b * 20 + ci) * 262144;
    for (int g = tid; g < 1152; g += 128) {
      int r = g >> 7, l = g & 127;
      int tt = r / 3, xx = r - tt * 3;
      int t = 2 * to - 1 + tt, xg = 2 * xo - 1 + xx;
      if (t >= 0 && t <= 15 && xg >= 0 && xg <= 31) {  // wave-uniform branch
        const char* src = (const char*)(base + (size_t)t * 16384 + (size_t)xg * 512) + l * 16;
        gld(src, (char*)&tileX[buf][r * 512] + l * 16);
      }
    }
    const char* wsrc = (const char*)(Wc + (size_t)ci * 1620);
    for (int g = tid; g < 405; g += 128)
      gld(wsrc + g * 16, (char*)&tileW[buf][0] + g * 16);
  };

  float acc[20];
#pragma unroll
  for (int o = 0; o < 20; o++) acc[o] = 0.f;

  stage(0, 0);
  asm volatile("s_waitcnt vmcnt(0)" ::: "memory");
  __syncthreads();

#pragma unroll 1
  for (int ci = 0; ci < 20; ci++) {
    int cur = ci & 1;
    if (ci + 1 < 20) stage(cur ^ 1, ci + 1);
    const float* tb = tileX[cur];
    const float* wcc = tileW[cur];
#pragma unroll
    for (int kt = 0; kt < 3; kt++)
#pragma unroll
      for (int kx = 0; kx < 3; kx++) {
        int rbase = (kt * 3 + kx) * 512;
#pragma unroll
        for (int ky = 0; ky < 3; ky++) {
          int yc = 2 * yo + ky - 1;
          bool yok = yc >= 0;
          int ycc = yok ? yc : 0;
          int ebase = rbase + ycc * 16;
          // kz = 0,1,2 -> z = 2zo-1, 2zo, 2zo+1
          float2 vz = *(const float2*)&tb[ebase + 2 * zo];
          int zlo = (zo > 0) ? (2 * zo - 1) : 0;
          float vl = tb[ebase + zlo];
          float v0 = (yok && zo > 0) ? vl : 0.f;
          float v1 = yok ? vz.x : 0.f;
          float v2 = yok ? vz.y : 0.f;
          int tap0 = ((kt * 3 + kx) * 3 + ky) * 3;
          // bulk-load 60 weights (3 kz-taps x 20 o) from LDS into registers
          float w[60];
          const f32x4* wv = (const f32x4*)(wcc + tap0 * 20);
#pragma unroll
          for (int q = 0; q < 15; q++) *(f32x4*)&w[q * 4] = wv[q];
#pragma unroll
          for (int o = 0; o < 20; o++) {
            acc[o] += v0 * w[o];
            acc[o] += v1 * w[20 + o];
            acc[o] += v2 * w[40 + o];
          }
        }
      }
    asm volatile("s_waitcnt vmcnt(0)" ::: "memory");
    __syncthreads();
  }

  size_t obase = (size_t)b * 20 * 16384 + (((size_t)to * 16 + xo) * 16 + yo) * 8 + zo;
#pragma unroll
  for (int o = 0; o < 20; o++) out[obase + (size_t)o * 16384] = acc[o];
}

// ---------------- U-Net: convs (generic fallback, used for c2/c21/c3/c31) ----------------
__global__ void k_conv4d_elem(const float* __restrict__ in, const float* __restrict__ W,
                              float* __restrict__ out, int Ci,
                              int Ti, int Xi, int Yi, int Zi,
                              int To, int Xo, int Yo, int Zo, int stride, int n) {
  int idx = blockIdx.x * 256 + threadIdx.x;
  if (idx >= n) return;
  int zo = idx % Zo; int r = idx / Zo;
  int yo = r % Yo; r /= Yo;
  int xo = r % Xo; r /= Xo;
  int to = r % To; r /= To;
  int o = r % 20; int b = r / 20;
  float acc = 0.f;
  size_t in_sp = (size_t)Ti * Xi * Yi * Zi;
  for (int ci = 0; ci < Ci; ci++) {
    const float* base = in + ((size_t)b * Ci + ci) * in_sp;
    const float* wc = W + ((size_t)o * Ci + ci) * 81;
    for (int kt = 0; kt < 3; kt++) {
      int t = to * stride + kt - 1; if (t < 0 || t >= Ti) continue;
      for (int kx = 0; kx < 3; kx++) {
        int xx = xo * stride + kx - 1; if (xx < 0 || xx >= Xi) continue;
        for (int ky = 0; ky < 3; ky++) {
          int y = yo * stride + ky - 1; if (y < 0 || y >= Yi) continue;
          for (int kz = 0; kz < 3; kz++) {
            int z = zo * stride + kz - 1; if (z < 0 || z >= Zi) continue;
            acc += base[(((size_t)t * Xi + xx) * Yi + y) * Zi + z] * wc[((kt * 3 + kx) * 3 + ky) * 3 + kz];
          }
        }
      }
    }
  }
  out[idx] = acc;
}

// ---------------- BN ----------------
__global__ void k_bn_stats(const float* __restrict__ d, int S, float* __restrict__ stats) {
  int c = blockIdx.x;
  int tid = threadIdx.x;
  float s = 0.f, s2 = 0.f;
  for (int b = 0; b < 4; b++) {
    const float* p = d + ((size_t)b * 20 + c) * S;
    for (int i = tid; i < S; i += 256) { float v = p[i]; s += v; s2 += v * v; }
  }
  __shared__ float ls[256], lq[256];
  ls[tid] = s; lq[tid] = s2;
  __syncthreads();
  for (int off = 128; off > 0; off >>= 1) {
    if (tid < off) { ls[tid] += ls[tid + off]; lq[tid] += lq[tid + off]; }
    __syncthreads();
  }
  if (tid == 0) {
    float cnt = 4.f * (float)S;
    float mean = ls[0] / cnt;
    float var = lq[0] / cnt - mean * mean;
    stats[2 * c] = mean;
    stats[2 * c + 1] = rsqrtf(var + 1e-5f);
  }
}

__global__ void k_bn_apply(float* __restrict__ d, int S, const float* __restrict__ stats,
                           const float* __restrict__ g, const float* __restrict__ bb, int n) {
  int idx = blockIdx.x * 256 + threadIdx.x;
  if (idx >= n) return;
  int c = (idx / S) % 20;
  float v = d[idx];
  v = (v - stats[2 * c]) * stats[2 * c + 1] * g[c] + bb[c];
  d[idx] = (v >= 0.f) ? v : 0.1f * v;
}

// channels-last bf16 fill of CLd0 ci 0..19 from post-BN oc1: thread per (b,s),
// 20 strided coalesced reads -> one packed 40B vector store (5 x uint2).
__global__ void k_cl20(const float* __restrict__ oc1, short* __restrict__ CL, int n) {
  int i = blockIdx.x * 256 + threadIdx.x;
  if (i >= n) return;
  int s = i & 16383, b = i >> 14;
  const float* src = oc1 + (size_t)b * 20 * 16384 + s;
  unsigned h[20];
#pragma unroll
  for (int c = 0; c < 20; c++) h[c] = (unsigned)(unsigned short)f2bf(src[(size_t)c * 16384]);
  uint2* dst = (uint2*)(CL + (size_t)i * 40);
#pragma unroll
  for (int q = 0; q < 5; q++) dst[q] = make_uint2(h[4 * q] | (h[4 * q + 1] << 16),
                                                  h[4 * q + 2] | (h[4 * q + 3] << 16));
}

// ---------------- deconv (ConvTranspose4d k=4 s=2 p=1), bias+lrelu fused ----------------
__device__ __forceinline__ int dcands(int p, int n_in, int* q, int* k) {
  int cnt = 0;
  int q0 = (p + 1) >> 1, k0 = p + 1 - 2 * q0;
  if (q0 >= 0 && q0 < n_in) { q[cnt] = q0; k[cnt] = k0; cnt++; }
  int q1 = q0 - 1, k1 = k0 + 2;
  if (q1 >= 0 && q1 < n_in) { q[cnt] = q1; k[cnt] = k1; cnt++; }
  return cnt;
}

__global__ void k_deconv4d(const float* __restrict__ in1, int Ci1,
                           const float* __restrict__ in2, int Ci2,
                           const float* __restrict__ W, const float* __restrict__ bias,
                           float* __restrict__ out,
                           int Ti, int Xi, int Yi, int Zi, int n) {
  int idx = blockIdx.x * 256 + threadIdx.x;
  if (idx >= n) return;
  int To = 2 * Ti, Xo = 2 * Xi, Yo = 2 * Yi, Zo = 2 * Zi;
  int zo = idx % Zo; int r = idx / Zo;
  int yo = r % Yo; r /= Yo;
  int xo = r % Xo; r /= Xo;
  int to = r % To; int b = r / To;
  int qt[2], kt[2], qx[2], kx[2], qy[2], ky[2], qz[2], kz[2];
  int nt = dcands(to, Ti, qt, kt), nx = dcands(xo, Xi, qx, kx);
  int ny = dcands(yo, Yi, qy, ky), nz = dcands(zo, Zi, qz, kz);
  float acc[20];
#pragma unroll
  for (int o = 0; o < 20; o++) acc[o] = 0.f;
  int Ci = Ci1 + Ci2;
  size_t in_sp = (size_t)Ti * Xi * Yi * Zi;
  for (int ci = 0; ci < Ci; ci++) {
    const float* base = (ci < Ci1) ? in1 + ((size_t)b * Ci1 + ci) * in_sp
                                   : in2 + ((size_t)b * Ci2 + (ci - Ci1)) * in_sp;
    const float* wc = W + (size_t)ci * 5120;  // [ci][o(20)][256]
    for (int it = 0; it < nt; it++)
      for (int ix = 0; ix < nx; ix++)
        for (int iy = 0; iy < ny; iy++)
          for (int iz = 0; iz < nz; iz++) {
            float v = base[(((size_t)qt[it] * Xi + qx[ix]) * Yi + qy[iy]) * Zi + qz[iz]];
            int tap = ((kt[it] * 4 + kx[ix]) * 4 + ky[iy]) * 4 + kz[iz];
#pragma unroll
            for (int o = 0; o < 20; o++) acc[o] += v * wc[o * 256 + tap];
          }
  }
  size_t osp = (size_t)To * Xo * Yo * Zo;
  size_t obase = (size_t)b * 20 * osp + (((size_t)to * Xo + xo) * Yo + yo) * Zo + zo;
#pragma unroll
  for (int o = 0; o < 20; o++) {
    float v2 = acc[o] + bias[o];
    out[obase + (size_t)o * osp] = (v2 >= 0.f) ? v2 : 0.1f * v2;
  }
}

// d1 deconv: in 4x8x8x4 (oc2|od2, Ci=40) -> out 8x16x16x8 written bf16 CL ci 20..39
__global__ void k_deconv_d1_cl(const float* __restrict__ in1, const float* __restrict__ in2,
                               const float* __restrict__ W, const float* __restrict__ bias,
                               short* __restrict__ CL, int n) {
  int idx = blockIdx.x * 256 + threadIdx.x;
  if (idx >= n) return;
  int zo = idx & 7; int r = idx >> 3;
  int yo = r & 15; r >>= 4;
  int xo = r & 15; r >>= 4;
  int to = r & 7; int b = r >> 3;
  int qt[2], kt[2], qx[2], kx[2], qy[2], ky[2], qz[2], kz[2];
  int nt = dcands(to, 4, qt, kt), nx = dcands(xo, 8, qx, kx);
  int ny = dcands(yo, 8, qy, ky), nz = dcands(zo, 4, qz, kz);
  float acc[20];
#pragma unroll
  for (int o = 0; o < 20; o++) acc[o] = 0.f;
  const size_t in_sp = 4 * 8 * 8 * 4;
  for (int ci = 0; ci < 40; ci++) {
    const float* base = (ci < 20) ? in1 + ((size_t)b * 20 + ci) * in_sp
                                  : in2 + ((size_t)b * 20 + (ci - 20)) * in_sp;
    const float* wc = W + (size_t)ci * 5120;
    for (int it = 0; it < nt; it++)
      for (int ix = 0; ix < nx; ix++)
        for (int iy = 0; iy < ny; iy++)
          for (int iz = 0; iz < nz; iz++) {
            float v = base[(((size_t)qt[it] * 8 + qx[ix]) * 8 + qy[iy]) * 4 + qz[iz]];
            int tap = ((kt[it] * 4 + kx[ix]) * 4 + ky[iy]) * 4 + kz[iz];
#pragma unroll
            for (int o = 0; o < 20; o++) acc[o] += v * wc[o * 256 + tap];
          }
  }
  size_t pos = (((size_t)b * 8 + to) * 16 + xo) * 16 * 8 + (size_t)yo * 8 + zo;
  unsigned h[20];
#pragma unroll
  for (int o = 0; o < 20; o++) {
    float v2 = acc[o] + bias[o];
    v2 = (v2 >= 0.f) ? v2 : 0.1f * v2;
    h[o] = (unsigned)(unsigned short)f2bf(v2);
  }
  uint2* dst = (uint2*)(CL + pos * 40 + 20);
#pragma unroll
  for (int q = 0; q < 5; q++) dst[q] = make_uint2(h[4 * q] | (h[4 * q + 1] << 16),
                                                  h[4 * q + 2] | (h[4 * q + 3] << 16));
}

// fill Xcl ci 0..19 from x (packed 40B vector stores)
__global__ void k_xcl_x(const float* __restrict__ x, short* __restrict__ Xcl, int n) {
  int i = blockIdx.x * 256 + threadIdx.x;
  if (i >= n) return;
  int s = i & 262143, b = i >> 18;
  const float* src = x + (size_t)b * 20 * 262144 + s;
  unsigned h[20];
#pragma unroll
  for (int c = 0; c < 20; c++) h[c] = (unsigned)(unsigned short)f2bf(src[(size_t)c * 262144]);
  uint2* dst = (uint2*)(Xcl + (size_t)i * 40);
#pragma unroll
  for (int q = 0; q < 5; q++) dst[q] = make_uint2(h[4 * q] | (h[4 * q + 1] << 16),
                                                  h[4 * q + 2] | (h[4 * q + 3] << 16));
}

// pack out_w [20][40][81] + w_pw [20][20] -> Wp[tap(82)][mt(2)][m(16)][k(64)] bf16,
// bank-swizzled for LDS staging: short index i -> i ^ ((m&7)<<3)  (byte ^ ((m&7)<<4)).
// tap 81 = pointwise (x2) weights.
__global__ void k_pack_w(const float* __restrict__ out_w, const float* __restrict__ w_pw,
                         short* __restrict__ Wp, short* __restrict__ zp, int n) {
  int i = blockIdx.x * 256 + threadIdx.x;
  if (i >= n) return;
  int k = i & 63, m = (i >> 6) & 15, mt = (i >> 10) & 1, tap = i >> 11;
  int o = mt * 16 + m;
  float v = 0.f;
  if (o < 20 && k < 40) {
    if (tap < 81) v = out_w[((size_t)o * 40 + k) * 81 + tap];
    else if (k < 20) v = w_pw[o * 20 + k];
  }
  Wp[i ^ ((m & 7) << 3)] = f2bf(v);
  if (i < 64) zp[i] = 0;
}

// pack d0_w [40][20][256] -> Wd parity-class-major:
// [h(32)=cls*2+it][sub(8)=ix*4+iz*2+iy][mt(2)][m(16)][k(64)] bf16,
// bank-swizzled: element index i -> i ^ ((m&7)<<3)  (byte ^ ((row&7)<<4)).
__global__ void k_pack_wd(const float* __restrict__ d0_w, short* __restrict__ Wd, int n) {
  int i = blockIdx.x * 256 + threadIdx.x;
  if (i >= n) return;
  int k = i & 63, m = (i >> 6) & 15, mt = (i >> 10) & 1, sub = (i >> 11) & 7, h = i >> 14;
  int it = h & 1, cls = h >> 1;
  int ez = cls & 1, ey = (cls >> 1) & 1, ex = (cls >> 2) & 1, et = (cls >> 3) & 1;
  int iy = sub & 1, iz = (sub >> 1) & 1, ix = (sub >> 2) & 1;
  int kt = et ? (2 * it) : (1 + 2 * it);
  int kx = ex ? (2 * ix) : (1 + 2 * ix);
  int ky = ey ? (2 * iy) : (1 + 2 * iy);
  int kz = ez ? (2 * iz) : (1 + 2 * iz);
  int tap = ((kt * 4 + kx) * 4 + ky) * 4 + kz;
  int o = mt * 16 + m;
  float v = (o < 20 && k < 40) ? d0_w[((size_t)k * 20 + o) * 256 + tap] : 0.f;
  Wd[i ^ ((m & 7) << 3)] = f2bf(v);
}

// ---------------- d0 deconv via MFMA (parity-class, LDS-staged) ----------------
__global__ __launch_bounds__(512) void k_d0_mfma(
    const short* __restrict__ CLd0, const short* __restrict__ Wd,
    const float* __restrict__ bias, short* __restrict__ Xcl) {
  __shared__ __align__(16) char lds[157696];  // 9*10240 B-planes + 2*32768 A dbuf
  char* lds_a = lds + 92160;
  int bid = blockIdx.x;
  int ux = bid & 15, ut = (bid >> 4) & 7, b = bid >> 7;
  int tid = threadIdx.x;
  int uz = tid >> 6;
  int lane = tid & 63, ln15 = lane & 15, kg = lane >> 4;  // ln15 = uy

  const char* xb = (const char*)CLd0;
  const char* wb = (const char*)Wd;

  auto gld = [](const char* src, char* dst) {
    __builtin_amdgcn_global_load_lds(
        (const __attribute__((address_space(1))) void*)src,
        (__attribute__((address_space(3))) void*)dst, 16, 0, 0);
  };

  // ---- prologue: stage B planes (swizzle baked into per-lane global src) ----
#pragma unroll
  for (int pt = 0; pt < 3; pt++) {
    int qt = ut - 1 + pt;
    if (qt < 0 || qt > 7) continue;
#pragma unroll
    for (int px = 0; px < 3; px++) {
      int qx = ux - 1 + px;
      if (qx < 0 || qx > 15) continue;
      const char* src = xb + (size_t)((b * 8 + qt) * 16 + qx) * 10240;
      char* dst = lds + (pt * 3 + px) * 10240;
      for (int g = tid; g < 640; g += 512) {
        int key = ((g / 40) & 7) << 4;
        gld(src + ((g * 16) ^ key), dst + g * 16);
      }
    }
  }
  // stage A half-block h=0 (pack is pre-swizzled -> linear copy)
  for (int g = tid; g < 2048; g += 512) gld(wb + g * 16, lds_a + g * 16);
  asm volatile("s_waitcnt vmcnt(0)" ::: "memory");
  __syncthreads();

  bf16x8 zv = {0, 0, 0, 0, 0, 0, 0, 0};
  int aswz = ((ln15 * 128 + kg * 16) ^ ((ln15 & 7) << 4));

#pragma unroll 1
  for (int cls = 0; cls < 16; cls++) {
    int ez = cls & 1, ey = (cls >> 1) & 1, ex = (cls >> 2) & 1, et = (cls >> 3) & 1;
    f32x4 acc0, acc1;
#pragma unroll
    for (int j = 0; j < 4; j++) { acc0[j] = 0.f; acc1[j] = 0.f; }
#pragma unroll
    for (int it = 0; it < 2; it++) {
      int h = cls * 2 + it;
      // stage next A half-block into the other buffer
      if (h + 1 < 32) {
        const char* asrc = wb + (size_t)(h + 1) * 32768;
        char* adst = lds_a + (it ^ 1) * 32768;
        for (int g = tid; g < 2048; g += 512) gld(asrc + g * 16, adst + g * 16);
      }
      const char* ab = lds_a + it * 32768;
      int kt_q = ut + (et ? (1 - it) : (-it));
      if (kt_q >= 0 && kt_q <= 7) {
        int pt = kt_q - ut + 1;
#pragma unroll
        for (int ix = 0; ix < 2; ix++) {
          int qx = ux + (ex ? (1 - ix) : (-ix));
          if (qx < 0 || qx > 15) continue;
          int px = qx - ux + 1;
          const char* pbase = lds + (pt * 3 + px) * 10240;
#pragma unroll
          for (int iz = 0; iz < 2; iz++) {
            int qz = uz + (ez ? (1 - iz) : (-iz));
            if (qz < 0 || qz > 7) continue;
#pragma unroll
            for (int iy = 0; iy < 2; iy++) {
              int qy = ln15 + (ey ? (1 - iy) : (-iy));
              bool yok = (qy >= 0) && (qy < 16);
              int qyc = yok ? qy : 0;
              int bkey = (qyc & 7) << 4;
              const char* abase = ab + (ix * 4 + iz * 2 + iy) * 4096;
#pragma unroll
              for (int ch = 0; ch < 2; ch++) {
                int co = ch ? 64 : kg * 16;  // ch=1: broadcast ci 32..39 (k>=40 wts are 0)
                int boff = (qyc * 640 + qz * 80 + co) ^ bkey;
                bf16x8 bvv = *(const bf16x8*)(pbase + boff);
                bf16x8 bv = yok ? bvv : zv;
                int aoff = (ch ? (aswz ^ 64) : aswz);
                bf16x8 a0 = *(const bf16x8*)(abase + aoff);
                bf16x8 a1 = *(const bf16x8*)(abase + 2048 + aoff);
                acc0 = __builtin_amdgcn_mfma_f32_16x16x32_bf16(a0, bv, acc0, 0, 0, 0);
                acc1 = __builtin_amdgcn_mfma_f32_16x16x32_bf16(a1, bv, acc1, 0, 0, 0);
              }
            }
          }
        }
      }
      asm volatile("s_waitcnt vmcnt(0)" ::: "memory");
      __syncthreads();
    }
    int to = 2 * ut + et, xo = 2 * ux + ex, zo = 2 * uz + ez, yo = 2 * ln15 + ey;
    long opos = ((((long)b * 16 + to) * 32 + xo) * 32 + yo) * 16 + zo;
    short* dst = Xcl + opos * 40 + 20;
    {
      unsigned hh[4];
#pragma unroll
      for (int r = 0; r < 4; r++) {
        float v = acc0[r] + bias[kg * 4 + r];
        v = (v >= 0.f) ? v : 0.1f * v;
        hh[r] = (unsigned)(unsigned short)f2bf(v);
      }
      uint2 u;
      u.x = hh[0] | (hh[1] << 16);
      u.y = hh[2] | (hh[3] << 16);
      *(uint2*)(dst + kg * 4) = u;
    }
    if (kg == 0) {
      unsigned hh[4];
#pragma unroll
      for (int r = 0; r < 4; r++) {
        float v = acc1[r] + bias[16 + r];
        v = (v >= 0.f) ? v : 0.1f * v;
        hh[r] = (unsigned)(unsigned short)f2bf(v);
      }
      uint2 u;
      u.x = hh[0] | (hh[1] << 16);
      u.y = hh[2] | (hh[3] << 16);
      *(uint2*)(dst + 16) = u;
    }
  }
}

// ---------------- final conv: fully LDS-staged bf16 MFMA implicit GEMM ----------------
__global__ __launch_bounds__(512) void k_fconv_mfma(
    const short* __restrict__ Xcl, const short* __restrict__ Wp,
    const float* __restrict__ bias, const float* __restrict__ bpw,
    float* __restrict__ io) {
  __shared__ __align__(16) char ldsB[2][40960];
  __shared__ __align__(16) char ldsW[2][36864];
  int bid = blockIdx.x;
  int xcd = bid & 7, idx = bid >> 3;
  int b = xcd >> 1, xh = xcd & 1;
  // t0-major within each XCD: working set 3 xi-slabs x 16 ti x 40KB ~ 1.9MB < 4MB L2
  int t0 = idx & 15, x0 = xh * 16 + ((idx >> 4) & 15);
  int tid = threadIdx.x;
  int lane = tid & 63;
  int ln15 = lane & 15, kg = lane >> 4;
  int ybase = (tid >> 6) * 4;

  // valid (kt,kx) slab list, 4 bits per entry (code = kt*4+kx; center = 5)
  unsigned long long codes = 0ull;
  int ns = 0;
  for (int kt = 0; kt < 3; kt++) {
    int ti = t0 + kt - 1;
    if (ti < 0 || ti > 15) continue;
    for (int kx = 0; kx < 3; kx++) {
      int xi = x0 + kx - 1;
      if (xi < 0 || xi > 31) continue;
      codes |= (unsigned long long)(kt * 4 + kx) << (4 * ns);
      ns++;
    }
  }

  const char* xb = (const char*)Xcl;
  const char* wb = (const char*)Wp;

  auto gld = [](const char* src, char* dst) {
    __builtin_amdgcn_global_load_lds(
        (const __attribute__((address_space(1))) void*)src,
        (__attribute__((address_space(3))) void*)dst, 16, 0, 0);
  };

  auto stage = [&](int buf, int code) {
    int kt = code >> 2, kx = code & 3;
    int ti = t0 + kt - 1, xi = x0 + kx - 1;
    const char* src = xb + (size_t)((b * 16 + ti) * 32 + xi) * 512 * 80;
    char* dstB = ldsB[buf];
#pragma unroll
    for (int s = 0; s < 5; s++) {
      int off = s * 8192 + tid * 16;
      gld(src + off, dstB + off);
    }
    // 9-tap contiguous weight run for this slab: taps (kt*3+kx)*9 .. +8
    const char* wsrc = wb + (size_t)(kt * 3 + kx) * 9 * 4096;
    char* dstW = ldsW[buf];
    for (int g = tid; g < 2304; g += 512) gld(wsrc + g * 16, dstW + g * 16);
  };

  f32x4 acc[2][4];
#pragma unroll
  for (int mt = 0; mt < 2; mt++)
#pragma unroll
    for (int nt = 0; nt < 4; nt++)
#pragma unroll
      for (int j = 0; j < 4; j++) acc[mt][nt][j] = 0.f;

  int awz0 = (ln15 * 128 + kg * 16) ^ ((ln15 & 7) << 4);
  int awz1 = (ln15 * 128 + 64 + kg * 16) ^ ((ln15 & 7) << 4);

  stage(0, (int)(codes & 15));
  asm volatile("s_waitcnt vmcnt(0)" ::: "memory");
  __syncthreads();

  int cur = 0;
#pragma unroll 1
  for (int i = 0; i < ns; i++) {
    const char* bufB = ldsB[cur];
    const char* bufW = ldsW[cur];
    if (i + 1 < ns) stage(cur ^ 1, (int)((codes >> (4 * (i + 1))) & 15));
    int code = (int)((codes >> (4 * i)) & 15);
    bf16x8 zv = {0, 0, 0, 0, 0, 0, 0, 0};
#pragma unroll
    for (int kz = 0; kz < 3; kz++) {
      int zi = ln15 + kz - 1;
      bool zok = (zi >= 0) && (zi < 16);
      int zc = zok ? zi : 0;
#pragma unroll
      for (int ch = 0; ch < 2; ch++) {
        int co = ch ? 64 : kg * 16;  // ch=1: broadcast ci 32..39 chunk to all kg
        bf16x8 bv[6];
#pragma unroll
        for (int j = 0; j < 6; j++) {
          int yi = ybase + j - 1;
          int yc = (yi < 0) ? 0 : ((yi > 31) ? 31 : yi);
          bf16x8 v = *(const bf16x8*)(bufB + (size_t)(yc * 16 + zc) * 80 + co);
          bool ok = zok && (yi >= 0) && (yi < 32);
          bv[j] = ok ? v : zv;
        }
        int awz = ch ? awz1 : awz0;
        bf16x8 av[3][2];
#pragma unroll
        for (int ky = 0; ky < 3; ky++) {
          const char* wt = bufW + (size_t)(ky * 3 + kz) * 4096;
          av[ky][0] = *(const bf16x8*)(wt + awz);
          av[ky][1] = *(const bf16x8*)(wt + 2048 + awz);
        }
#pragma unroll
        for (int ky = 0; ky < 3; ky++)
#pragma unroll
          for (int nt = 0; nt < 4; nt++) {
            acc[0][nt] = __builtin_amdgcn_mfma_f32_16x16x32_bf16(av[ky][0], bv[nt + ky], acc[0][nt], 0, 0, 0);
            acc[1][nt] = __builtin_amdgcn_mfma_f32_16x16x32_bf16(av[ky][1], bv[nt + ky], acc[1][nt], 0, 0, 0);
          }
      }
    }
    if (code == 5) {
      // center slab: fused pointwise (x2) tap, ci 0..19 (weights zero for k>=20)
      const char* wt = wb + (size_t)81 * 4096;
      bf16x8 a0 = *(const bf16x8*)(wt + awz0);
      bf16x8 a1 = *(const bf16x8*)(wt + 2048 + awz0);
#pragma unroll
      for (int nt = 0; nt < 4; nt++) {
        bf16x8 bv = *(const bf16x8*)(bufB + (size_t)((ybase + nt) * 16 + ln15) * 80 + kg * 16);
        acc[0][nt] = __builtin_amdgcn_mfma_f32_16x16x32_bf16(a0, bv, acc[0][nt], 0, 0, 0);
        acc[1][nt] = __builtin_amdgcn_mfma_f32_16x16x32_bf16(a1, bv, acc[1][nt], 0, 0, 0);
      }
    }
    asm volatile("s_waitcnt vmcnt(0)" ::: "memory");
    __syncthreads();
    cur ^= 1;
  }

#pragma unroll
  for (int mt = 0; mt < 2; mt++)
#pragma unroll
    for (int r = 0; r < 4; r++) {
      int o = mt * 16 + kg * 4 + r;
      if (o >= 20) continue;
      float bo = bias[o] + bpw[o];
#pragma unroll
      for (int nt = 0; nt < 4; nt++) {
        int y = ybase + nt;
        size_t oidx = ((size_t)(b * 20 + o)) * 262144 +
                      ((((size_t)t0 * 32 + x0) * 32 + y) * 16 + ln15);
        float v = acc[mt][nt][r] + bo + io[oidx];
        io[oidx] = fmaxf(v, 0.f);
      }
    }
}

extern "C" void kernel_launch(void* const* d_in, const int* in_sizes, int n_in,
                              void* d_out, int out_size, void* d_ws, size_t ws_size,
                              hipStream_t stream) {
  const float* x     = (const float*)d_in[0];
  const float* sw1   = (const float*)d_in[1];
  const float* sw2   = (const float*)d_in[2];
  const float* sw3   = (const float*)d_in[3];
  const float* sw4   = (const float*)d_in[4];
  const float* w_pw  = (const float*)d_in[5];
  const float* b_pw  = (const float*)d_in[6];
  const float* c1_w  = (const float*)d_in[7];
  const float* c2_w  = (const float*)d_in[8];
  const float* c21_w = (const float*)d_in[9];
  const float* c3_w  = (const float*)d_in[10];
  const float* c31_w = (const float*)d_in[11];
  const float* bn1_g = (const float*)d_in[12];
  const float* bn1_b = (const float*)d_in[13];
  const float* bn2_g = (const float*)d_in[14];
  const float* bn2_b = (const float*)d_in[15];
  const float* bn21_g = (const float*)d_in[16];
  const float* bn21_b = (const float*)d_in[17];
  const float* bn3_g = (const float*)d_in[18];
  const float* bn3_b = (const float*)d_in[19];
  const float* bn31_g = (const float*)d_in[20];
  const float* bn31_b = (const float*)d_in[21];
  const float* d2_w  = (const float*)d_in[22];
  const float* d2_b  = (const float*)d_in[23];
  const float* d1_w  = (const float*)d_in[24];
  const float* d1_b  = (const float*)d_in[25];
  const float* d0_w  = (const float*)d_in[26];
  const float* d0_b  = (const float*)d_in[27];
  const float* out_w = (const float*)d_in[28];
  const float* out_b = (const float*)d_in[29];
  float* out = (float*)d_out;
  float* ws = (float*)d_ws;

  // spectral arena (phase 1 only)
  float2* A  = (float2*)(ws);
  float2* Bb = (float2*)(ws + 10485760);
  float2* Cb = (float2*)(ws + 13107200);
  float2* Dd = (float2*)(ws + 14417920);
  float2* Ee = (float2*)(ws + 15073280);
  float2* Ff = (float2*)(ws + 15728640);
  float2* Gg = (float2*)(ws + 16384000);
  // twiddle tables: live only during spectral phase; region inside Xcl span,
  // beyond the spectral arena end (17,039,360 fl), overwritten later by k_xcl_x.
  float2* Twid = (float2*)(ws + 23000000);

  // U-Net arena
  float* oc1   = ws;
  short* CLd0  = (short*)(ws + 1310720);
  float* Wc1   = ws + 1310720;  // aliases CLd0 region: used only between pack and cl20
  float* oc2a  = ws + 2621440;
  float* oc2   = ws + 2703360;
  float* oc3a  = ws + 2785280;
  float* oc3   = ws + 2790400;
  float* od2   = ws + 2795520;
  short* Xcl   = (short*)(ws + 2877440);
  float* stats = ws + 23848960;
  short* Wd = (short*)(ws);
  short* Wp = (short*)(ws + 262144);
  short* zp = (short*)(ws + 349184);

  auto nb = [](int n) { return (n + 255) / 256; };
  dim3 blk(256);

  // ---- twiddle tables ----
  k_twid<<<1, 64, 0, stream>>>(Twid);

  // ---- spectral path: x1 -> d_out ----
  k_fwd_z<<<nb(1310720), blk, 0, stream>>>(x, Twid, A, 1310720);
  k_fwd_y<<<nb(1310720), blk, 0, stream>>>(A, Twid, Bb, 1310720);
  k_fwd_x<<<nb(655360), blk, 0, stream>>>(Bb, Twid, Cb, 655360);
  k_fwd_t<<<nb(327680), blk, 0, stream>>>(Cb, Twid, Dd, 327680);
  k_fwd_c<<<nb(327680), blk, 0, stream>>>(Dd, Twid, Ee, 327680);
  k_fwd_b<<<nb(327680), blk, 0, stream>>>(Ee, Twid, Ff, 327680);
  k_smul<<<nb(327680), blk, 0, stream>>>(Ff, sw1, sw2, sw3, sw4, Gg, 327680);
  k_inv_t<<<nb(655360), blk, 0, stream>>>(Gg, Twid, Cb, 655360);
  k_inv_x<<<nb(1310720), blk, 0, stream>>>(Cb, Twid, Bb, 1310720);
  k_inv_yz<<<nb(1310720), blk, 0, stream>>>(Bb, Twid, out, 1310720);

  // ---- Xcl ci 0..19 from x; c1 weight pack (into dead CLd0 region) ----
  k_pack_c1<<<nb(32400), blk, 0, stream>>>(c1_w, Wc1, 32400);
  k_xcl_x<<<nb(1048576), blk, 0, stream>>>(x, Xcl, 1048576);

  // ---- U-Net encoder ----
  k_c1<<<512, dim3(128), 0, stream>>>(x, Wc1, oc1);
  k_bn_stats<<<20, blk, 0, stream>>>(oc1, 16384, stats);
  k_bn_apply<<<nb(1310720), blk, 0, stream>>>(oc1, 16384, stats, bn1_g, bn1_b, 1310720);
  k_cl20<<<nb(65536), blk, 0, stream>>>(oc1, CLd0, 65536);

  k_conv4d_elem<<<nb(81920), blk, 0, stream>>>(oc1, c2_w, oc2a, 20,
                                               8, 16, 16, 8, 4, 8, 8, 4, 2, 81920);
  k_bn_stats<<<20, blk, 0, stream>>>(oc2a, 1024, stats);
  k_bn_apply<<<nb(81920), blk, 0, stream>>>(oc2a, 1024, stats, bn2_g, bn2_b, 81920);

  k_conv4d_elem<<<nb(81920), blk, 0, stream>>>(oc2a, c21_w, oc2, 20,
                                               4, 8, 8, 4, 4, 8, 8, 4, 1, 81920);
  k_bn_stats<<<20, blk, 0, stream>>>(oc2, 1024, stats);
  k_bn_apply<<<nb(81920), blk, 0, stream>>>(oc2, 1024, stats, bn21_g, bn21_b, 81920);

  k_conv4d_elem<<<nb(5120), blk, 0, stream>>>(oc2, c3_w, oc3a, 20,
                                              4, 8, 8, 4, 2, 4, 4, 2, 2, 5120);
  k_bn_stats<<<20, blk, 0, stream>>>(oc3a, 64, stats);
  k_bn_apply<<<nb(5120), blk, 0, stream>>>(oc3a, 64, stats, bn3_g, bn3_b, 5120);

  k_conv4d_elem<<<nb(5120), blk, 0, stream>>>(oc3a, c31_w, oc3, 20,
                                              2, 4, 4, 2, 2, 4, 4, 2, 1, 5120);
  k_bn_stats<<<20, blk, 0, stream>>>(oc3, 64, stats);
  k_bn_apply<<<nb(5120), blk, 0, stream>>>(oc3, 64, stats, bn31_g, bn31_b, 5120);

  // ---- decoder ----
  k_deconv4d<<<nb(4096), blk, 0, stream>>>(oc3, 20, nullptr, 0, d2_w, d2_b, od2,
                                           2, 4, 4, 2, 4096);
  k_deconv_d1_cl<<<nb(65536), blk, 0, stream>>>(oc2, od2, d1_w, d1_b, CLd0, 65536);

  // weight packs
  k_pack_w<<<nb(167936), blk, 0, stream>>>(out_w, w_pw, Wp, zp, 167936);
  k_pack_wd<<<nb(524288), blk, 0, stream>>>(d0_w, Wd, 524288);

  // d0 deconv via MFMA (LDS-staged) -> Xcl ci 20..39
  k_d0_mfma<<<512, dim3(512), 0, stream>>>(CLd0, Wd, d0_b, Xcl);

  // final conv via MFMA (fully LDS-staged), fused +bias +x1 +x2(pointwise) +relu into d_out
  k_fconv_mfma<<<2048, dim3(512), 0, stream>>>(Xcl, Wp, out_b, b_pw, out);
}

// Round 7
// 1648.930 us; speedup vs baseline: 2.0612x; 1.2520x over previous
//
#include <hip/hip_runtime.h>

#define PI2 6.28318530717958647692f

typedef __attribute__((ext_vector_type(8))) short bf16x8;
typedef __attribute__((ext_vector_type(4))) float f32x4;

__device__ __forceinline__ void cfma(float2& acc, float2 a, float2 t) {
  acc.x += a.x * t.x - a.y * t.y;
  acc.y += a.x * t.y + a.y * t.x;
}
// multiply by conj(t) (inverse twiddle), t = e^{-i\theta}
__device__ __forceinline__ void cfmac(float2& acc, float2 a, float2 t) {
  acc.x += a.x * t.x + a.y * t.y;
  acc.y += a.y * t.x - a.x * t.y;
}

__device__ __forceinline__ short f2bf(float f) {
  unsigned u = __float_as_uint(f);
  unsigned r = (u + 0x7fff + ((u >> 16) & 1)) >> 16;
  return (short)r;
}

// twiddle tables: T[0..31]=e^{-2pi i m/32}, T[32..47]=N16, T[48..67]=N20, T[68..71]=N4
__global__ void k_twid(float2* __restrict__ T) {
  int i = threadIdx.x;
  float s, c;
  if (i < 32) { __sincosf(-PI2 * (float)i / 32.f, &s, &c); T[i] = make_float2(c, s); }
  if (i < 16) { __sincosf(-PI2 * (float)i / 16.f, &s, &c); T[32 + i] = make_float2(c, s); }
  if (i < 20) { __sincosf(-PI2 * (float)i / 20.f, &s, &c); T[48 + i] = make_float2(c, s); }
  if (i < 4)  { __sincosf(-PI2 * (float)i / 4.f,  &s, &c); T[68 + i] = make_float2(c, s); }
}

// ---------------- spectral forward ----------------
__global__ void k_fwd_z(const float* __restrict__ x, const float2* __restrict__ T,
                        float2* __restrict__ out, int nrows) {
  __shared__ float2 tw[16];
  if (threadIdx.x < 16) tw[threadIdx.x] = T[32 + threadIdx.x];
  __syncthreads();
  int r = blockIdx.x * 256 + threadIdx.x;
  if (r >= nrows) return;
  const float* p = x + (size_t)r * 16;
  float v[16];
#pragma unroll
  for (int z = 0; z < 16; z++) v[z] = p[z];
#pragma unroll
  for (int zk = 0; zk < 4; zk++) {
    float re = 0.f, im = 0.f;
#pragma unroll
    for (int z = 0; z < 16; z++) {
      float2 t = tw[(z * zk) & 15];
      re += v[z] * t.x;
      im += v[z] * t.y;
    }
    out[(size_t)r * 4 + zk] = make_float2(re, im);
  }
}

__global__ void k_fwd_y(const float2* __restrict__ in, const float2* __restrict__ T,
                        float2* __restrict__ out, int n) {
  __shared__ float2 tw[32];
  if (threadIdx.x < 32) tw[threadIdx.x] = T[threadIdx.x];
  __syncthreads();
  int i = blockIdx.x * 256 + threadIdx.x;
  if (i >= n) return;
  int zk = i & 3, yk = (i >> 2) & 7, slab = i >> 5;
  const float2* p = in + (size_t)slab * 128 + zk;
  float2 acc = make_float2(0.f, 0.f);
  for (int y = 0; y < 32; y++) cfma(acc, p[y * 4], tw[(y * yk) & 31]);
  out[i] = acc;
}

__global__ void k_fwd_x(const float2* __restrict__ in, const float2* __restrict__ T,
                        float2* __restrict__ out, int n) {
  __shared__ float2 tw[32];
  if (threadIdx.x < 32) tw[threadIdx.x] = T[threadIdx.x];
  __syncthreads();
  int i = blockIdx.x * 256 + threadIdx.x;
  if (i >= n) return;
  int zk = i & 3, yk = (i >> 2) & 7, xi = (i >> 5) & 15, slab = i >> 9;
  int xk = (xi < 8) ? xi : xi + 16;
  const float2* p = in + (size_t)slab * 1024 + yk * 4 + zk;
  float2 acc = make_float2(0.f, 0.f);
  for (int xx = 0; xx < 32; xx++) cfma(acc, p[xx * 32], tw[(xx * xk) & 31]);
  out[i] = acc;
}

__global__ void k_fwd_t(const float2* __restrict__ in, const float2* __restrict__ T,
                        float2* __restrict__ out, int n) {
  __shared__ float2 tw[16];
  if (threadIdx.x < 16) tw[threadIdx.x] = T[32 + threadIdx.x];
  __syncthreads();
  int i = blockIdx.x * 256 + threadIdx.x;
  if (i >= n) return;
  int zk = i & 3, yk = (i >> 2) & 7, xi = (i >> 5) & 15, ti = (i >> 9) & 7, bc = i >> 12;
  int tk = (ti < 4) ? ti : ti + 8;
  const float2* p = in + (size_t)bc * 8192 + xi * 32 + yk * 4 + zk;
  float2 acc = make_float2(0.f, 0.f);
  for (int t = 0; t < 16; t++) cfma(acc, p[t * 512], tw[(t * tk) & 15]);
  out[i] = acc;
}

__global__ void k_fwd_c(const float2* __restrict__ in, const float2* __restrict__ T,
                        float2* __restrict__ out, int n) {
  __shared__ float2 tw[20];
  if (threadIdx.x < 20) tw[threadIdx.x] = T[48 + threadIdx.x];
  __syncthreads();
  int i = blockIdx.x * 256 + threadIdx.x;
  if (i >= n) return;
  int mode = i & 4095, r = i >> 12, ck = r % 20, b = r / 20;
  const float2* p = in + (size_t)b * 81920 + mode;
  float2 acc = make_float2(0.f, 0.f);
  int idx = 0;
  for (int c = 0; c < 20; c++) {
    cfma(acc, p[(size_t)c * 4096], tw[idx]);
    idx += ck; if (idx >= 20) idx -= 20;
  }
  out[i] = acc;
}

__global__ void k_fwd_b(const float2* __restrict__ in, const float2* __restrict__ T,
                        float2* __restrict__ out, int n) {
  __shared__ float2 tw[4];
  if (threadIdx.x < 4) tw[threadIdx.x] = T[68 + threadIdx.x];
  __syncthreads();
  int i = blockIdx.x * 256 + threadIdx.x;
  if (i >= n) return;
  int mode = i & 4095, r = i >> 12, ck = r % 20, bk = r / 20;
  const float2* p = in + (size_t)ck * 4096 + mode;
  float2 acc = make_float2(0.f, 0.f);
#pragma unroll
  for (int b = 0; b < 4; b++) cfma(acc, p[(size_t)b * 81920], tw[(b * bk) & 3]);
  out[i] = acc;
}

__global__ void k_smul(const float2* __restrict__ in,
                       const float* __restrict__ sw1, const float* __restrict__ sw2,
                       const float* __restrict__ sw3, const float* __restrict__ sw4,
                       float2* __restrict__ out, int n) {
  int i = blockIdx.x * 256 + threadIdx.x;
  if (i >= n) return;
  int mode = i & 4095, r = i >> 12, o = r % 20, bk = r / 20;
  int ti = mode >> 9, xi = (mode >> 5) & 15, yk = (mode >> 2) & 7, zk = mode & 3;
  const float* w = (ti < 4) ? ((xi < 8) ? sw1 : sw3) : ((xi < 8) ? sw2 : sw4);
  int tl = ti & 3, xl = xi & 7;
  const float2* wp = (const float2*)w;
  const float2* ip = in + (size_t)bk * 81920 + mode;
  size_t wsub = (size_t)o * 1024 + (size_t)tl * 256 + (size_t)xl * 32 + yk * 4 + zk;
  float2 acc = make_float2(0.f, 0.f);
  for (int ci = 0; ci < 20; ci++) cfma(acc, ip[(size_t)ci * 4096], wp[(size_t)ci * 20480 + wsub]);
  out[i] = acc;
}

// ---------------- spectral inverse ----------------
__global__ void k_inv_t(const float2* __restrict__ in, const float2* __restrict__ T,
                        float2* __restrict__ out, int n) {
  __shared__ float2 tw[16];
  if (threadIdx.x < 16) tw[threadIdx.x] = T[32 + threadIdx.x];
  __syncthreads();
  int i = blockIdx.x * 256 + threadIdx.x;
  if (i >= n) return;
  int zk = i & 3, yk = (i >> 2) & 7, xi = (i >> 5) & 15, tp = (i >> 9) & 15, bc = i >> 13;
  const float2* p = in + (size_t)bc * 4096 + xi * 32 + yk * 4 + zk;
  float2 acc = make_float2(0.f, 0.f);
#pragma unroll
  for (int ti = 0; ti < 8; ti++) {
    int tk = (ti < 4) ? ti : ti + 8;
    cfmac(acc, p[ti * 512], tw[(tk * tp) & 15]);
  }
  out[i] = acc;
}

__global__ void k_inv_x(const float2* __restrict__ in, const float2* __restrict__ T,
                        float2* __restrict__ out, int n) {
  __shared__ float2 tw[32];
  if (threadIdx.x < 32) tw[threadIdx.x] = T[threadIdx.x];
  __syncthreads();
  int i = blockIdx.x * 256 + threadIdx.x;
  if (i >= n) return;
  int zk = i & 3, yk = (i >> 2) & 7, xp = (i >> 5) & 31, tp = (i >> 10) & 15, bc = i >> 14;
  const float2* p = in + (size_t)bc * 8192 + tp * 512 + yk * 4 + zk;
  float2 acc = make_float2(0.f, 0.f);
#pragma unroll
  for (int xi = 0; xi < 16; xi++) {
    int xk = (xi < 8) ? xi : xi + 16;
    cfmac(acc, p[xi * 32], tw[(xk * xp) & 31]);
  }
  out[i] = acc;
}

// fused inverse-y + c2r-z: thread per (bc,tp,xp,yp), emits full 16-z real row.
__global__ void k_inv_yz(const float2* __restrict__ in, const float2* __restrict__ T,
                         float* __restrict__ out, int n) {
  __shared__ float2 tw[48];  // 0..31: N32, 32..47: N16
  if (threadIdx.x < 48) tw[threadIdx.x] = T[threadIdx.x];
  __syncthreads();
  int i = blockIdx.x * 256 + threadIdx.x;
  if (i >= n) return;
  int yp = i & 31;
  const float2* p = in + (size_t)(i >> 5) * 32;  // [bc][tp][xp] slab: [yk8][zk4]
  float2 Ay[4];
#pragma unroll
  for (int zk = 0; zk < 4; zk++) Ay[zk] = make_float2(0.f, 0.f);
#pragma unroll
  for (int yk = 0; yk < 8; yk++) {
    float2 w = tw[(yk * yp) & 31];
#pragma unroll
    for (int zk = 0; zk < 4; zk++) cfmac(Ay[zk], p[yk * 4 + zk], w);
  }
  float res[16];
#pragma unroll
  for (int zp = 0; zp < 16; zp++) {
    float v = Ay[0].x;
#pragma unroll
    for (int zk = 1; zk < 4; zk++) {
      float2 t = tw[32 + ((zk * zp) & 15)];
      v += 2.f * (Ay[zk].x * t.x + Ay[zk].y * t.y);
    }
    res[zp] = v * (1.f / 262144.f);
  }
  float4* o4 = (float4*)(out + (size_t)i * 16);
#pragma unroll
  for (int q = 0; q < 4; q++)
    o4[q] = make_float4(res[q * 4], res[q * 4 + 1], res[q * 4 + 2], res[q * 4 + 3]);
}

// ---------------- c1 conv (stride 2, 20->20) LDS-tiled, fp32-exact ----------------
// pack c1_w [o][ci][81] -> Wc1p[ci][tap][o] (contiguous per ci)
__global__ void k_pack_c1(const float* __restrict__ c1_w, float* __restrict__ Wc, int n) {
  int i = blockIdx.x * 256 + threadIdx.x;
  if (i >= n) return;
  int o = i % 20; int r = i / 20;
  int tap = r % 81; int ci = r / 81;
  Wc[i] = c1_w[((size_t)o * 20 + ci) * 81 + tap];
}

// Block = (b,to,xo): 4*8*16 = 512 blocks x 128 threads (zo8, yo16), one output each.
__global__ __launch_bounds__(128) void k_c1(
    const float* __restrict__ x, const float* __restrict__ Wc,
    float* __restrict__ out) {
  __shared__ __align__(16) float tileX[2][4608];  // [tt3][xx3][y32][z16]
  __shared__ __align__(16) float tileW[2][1620];
  int bid = blockIdx.x;
  int xo = bid & 15, to = (bid >> 4) & 7, b = bid >> 7;
  int tid = threadIdx.x;
  int zo = tid & 7, yo = tid >> 3;

  auto gld = [](const char* src, char* dst) {
    __builtin_amdgcn_global_load_lds(
        (const __attribute__((address_space(1))) void*)src,
        (__attribute__((address_space(3))) void*)dst, 16, 0, 0);
  };

  // zero-fill invalid (t,x) rows in BOTH buffers once
  for (int g = tid; g < 1152; g += 128) {
    int r = g >> 7, l = g & 127;
    int tt = r / 3, xx = r - tt * 3;
    int t = 2 * to - 1 + tt, xg = 2 * xo - 1 + xx;
    if (t < 0 || t > 15 || xg < 0 || xg > 31) {
      f32x4 z = {0.f, 0.f, 0.f, 0.f};
      *(f32x4*)&tileX[0][r * 512 + l * 4] = z;
      *(f32x4*)&tileX[1][r * 512 + l * 4] = z;
    }
  }

  auto stage = [&](int buf, int ci) {
    const float* base = x + (size_t)(b * 20 + ci) * 262144;
    for (int g = tid; g < 1152; g += 128) {
      int r = g >> 7, l = g & 127;
      int tt = r / 3, xx = r - tt * 3;
      int t = 2 * to - 1 + tt, xg = 2 * xo - 1 + xx;
      if (t >= 0 && t <= 15 && xg >= 0 && xg <= 31) {  // wave-uniform branch
        const char* src = (const char*)(base + (size_t)t * 16384 + (size_t)xg * 512) + l * 16;
        gld(src, (char*)&tileX[buf][r * 512] + l * 16);
      }
    }
    const char* wsrc = (const char*)(Wc + (size_t)ci * 1620);
    for (int g = tid; g < 405; g += 128)
      gld(wsrc + g * 16, (char*)&tileW[buf][0] + g * 16);
  };

  float acc[20];
#pragma unroll
  for (int o = 0; o < 20; o++) acc[o] = 0.f;

  stage(0, 0);
  asm volatile("s_waitcnt vmcnt(0)" ::: "memory");
  __syncthreads();

#pragma unroll 1
  for (int ci = 0; ci < 20; ci++) {
    int cur = ci & 1;
    if (ci + 1 < 20) stage(cur ^ 1, ci + 1);
    const float* tb = tileX[cur];
    const float* wcc = tileW[cur];
#pragma unroll
    for (int kt = 0; kt < 3; kt++)
#pragma unroll
      for (int kx = 0; kx < 3; kx++) {
        int rbase = (kt * 3 + kx) * 512;
#pragma unroll
        for (int ky = 0; ky < 3; ky++) {
          int yc = 2 * yo + ky - 1;
          bool yok = yc >= 0;
          int ycc = yok ? yc : 0;
          int ebase = rbase + ycc * 16;
          float2 vz = *(const float2*)&tb[ebase + 2 * zo];
          int zlo = (zo > 0) ? (2 * zo - 1) : 0;
          float vl = tb[ebase + zlo];
          float v0 = (yok && zo > 0) ? vl : 0.f;
          float v1 = yok ? vz.x : 0.f;
          float v2 = yok ? vz.y : 0.f;
          int tap0 = ((kt * 3 + kx) * 3 + ky) * 3;
          float w[60];
          const f32x4* wv = (const f32x4*)(wcc + tap0 * 20);
#pragma unroll
          for (int q = 0; q < 15; q++) *(f32x4*)&w[q * 4] = wv[q];
#pragma unroll
          for (int o = 0; o < 20; o++) {
            acc[o] += v0 * w[o];
            acc[o] += v1 * w[20 + o];
            acc[o] += v2 * w[40 + o];
          }
        }
      }
    asm volatile("s_waitcnt vmcnt(0)" ::: "memory");
    __syncthreads();
  }

  size_t obase = (size_t)b * 20 * 16384 + (((size_t)to * 16 + xo) * 16 + yo) * 8 + zo;
#pragma unroll
  for (int o = 0; o < 20; o++) out[obase + (size_t)o * 16384] = acc[o];
}

// ---------------- specialized encoder convs (weights-in-LDS, fp32-exact) ----------------
// c2: 3^4 stride-2 conv, in [b][ci20][8][16][16][8] -> out [b][o20][4][8][8][4].
// Block = (to,o,b) (grid 320), 256 thr = (xo8,yo8,zo4); per-o weight slice (1620 f) in LDS.
__global__ __launch_bounds__(256) void k_c2(
    const float* __restrict__ in, const float* __restrict__ W,
    float* __restrict__ out) {
  __shared__ __align__(16) float wsl[1620];
  int bid = blockIdx.x;
  int to = bid & 3, o = (bid >> 2) % 20, b = bid / 80;
  int tid = threadIdx.x;
  int zo = tid & 3, yo = (tid >> 2) & 7, xo = tid >> 5;
  const char* wsrc = (const char*)(W + (size_t)o * 1620);
  for (int g = tid; g < 405; g += 256)
    __builtin_amdgcn_global_load_lds(
        (const __attribute__((address_space(1))) void*)(wsrc + g * 16),
        (__attribute__((address_space(3))) void*)((char*)&wsl[0] + g * 16), 16, 0, 0);
  asm volatile("s_waitcnt vmcnt(0)" ::: "memory");
  __syncthreads();
  float acc = 0.f;
#pragma unroll 2
  for (int ci = 0; ci < 20; ci++) {
    const float* base = in + (size_t)(b * 20 + ci) * 16384;
    const float* wc = wsl + ci * 81;
#pragma unroll
    for (int kt = 0; kt < 3; kt++) {
      int t = 2 * to + kt - 1;
      if (t < 0) continue;  // wave-uniform (to uniform per block)
#pragma unroll
      for (int kx = 0; kx < 3; kx++) {
        int xx = 2 * xo + kx - 1;
        bool xok = xx >= 0; int xc = xok ? xx : 0;
#pragma unroll
        for (int ky = 0; ky < 3; ky++) {
          int yy = 2 * yo + ky - 1;
          bool yok = yy >= 0; int yc = yok ? yy : 0;
          const float* p = base + t * 2048 + xc * 128 + yc * 8;
          float2 vz = *(const float2*)(p + 2 * zo);
          float vl = p[(zo > 0) ? (2 * zo - 1) : 0];
          bool m = xok && yok;
          float v0 = (m && zo > 0) ? vl : 0.f;
          float v1 = m ? vz.x : 0.f;
          float v2 = m ? vz.y : 0.f;
          const float* wp = wc + ((kt * 3 + kx) * 3 + ky) * 3;
          acc += v0 * wp[0];
          acc += v1 * wp[1];
          acc += v2 * wp[2];
        }
      }
    }
  }
  size_t oidx = ((((size_t)(b * 20 + o) * 4 + to) * 8 + xo) * 8 + yo) * 4 + zo;
  out[oidx] = acc;
}

// c21: 3^4 stride-1 conv, in/out [b][20][4][8][8][4]. Block = (to,o,b) grid 320.
__global__ __launch_bounds__(256) void k_c21(
    const float* __restrict__ in, const float* __restrict__ W,
    float* __restrict__ out) {
  __shared__ __align__(16) float wsl[1620];
  int bid = blockIdx.x;
  int to = bid & 3, o = (bid >> 2) % 20, b = bid / 80;
  int tid = threadIdx.x;
  int zo = tid & 3, yo = (tid >> 2) & 7, xo = tid >> 5;
  const char* wsrc = (const char*)(W + (size_t)o * 1620);
  for (int g = tid; g < 405; g += 256)
    __builtin_amdgcn_global_load_lds(
        (const __attribute__((address_space(1))) void*)(wsrc + g * 16),
        (__attribute__((address_space(3))) void*)((char*)&wsl[0] + g * 16), 16, 0, 0);
  asm volatile("s_waitcnt vmcnt(0)" ::: "memory");
  __syncthreads();
  float acc = 0.f;
#pragma unroll 2
  for (int ci = 0; ci < 20; ci++) {
    const float* base = in + (size_t)(b * 20 + ci) * 1024;
    const float* wc = wsl + ci * 81;
#pragma unroll
    for (int kt = 0; kt < 3; kt++) {
      int t = to + kt - 1;
      if (t < 0 || t > 3) continue;  // wave-uniform
#pragma unroll
      for (int kx = 0; kx < 3; kx++) {
        int xx = xo + kx - 1;
        bool xok = (xx >= 0) && (xx < 8); int xc = xok ? xx : 0;
#pragma unroll
        for (int ky = 0; ky < 3; ky++) {
          int yy = yo + ky - 1;
          bool yok = (yy >= 0) && (yy < 8); int yc = yok ? yy : 0;
          const float* p = base + t * 256 + xc * 32 + yc * 4;
          float vl = p[(zo > 0) ? (zo - 1) : 0];
          float vm = p[zo];
          float vh = p[zo + 1];  // overread by <=1 elem at zo==3: masked, in-arena
          bool m = xok && yok;
          float v0 = (m && zo > 0) ? vl : 0.f;
          float v1 = m ? vm : 0.f;
          float v2 = (m && zo < 3) ? vh : 0.f;
          const float* wp = wc + ((kt * 3 + kx) * 3 + ky) * 3;
          acc += v0 * wp[0];
          acc += v1 * wp[1];
          acc += v2 * wp[2];
        }
      }
    }
  }
  size_t oidx = ((((size_t)(b * 20 + o) * 4 + to) * 8 + xo) * 8 + yo) * 4 + zo;
  out[oidx] = acc;
}

// c3: 3^4 stride-2 conv, in [b][ci20][4][8][8][4] -> out [b][o20][2][4][4][2].
// Block = (o,b) grid 80, 64 thr = (to2,xo4,yo4,zo2).
__global__ __launch_bounds__(64) void k_c3(
    const float* __restrict__ in, const float* __restrict__ W,
    float* __restrict__ out) {
  __shared__ __align__(16) float wsl[1620];
  int bid = blockIdx.x;
  int o = bid % 20, b = bid / 20;
  int tid = threadIdx.x;
  int zo = tid & 1, yo = (tid >> 1) & 3, xo = (tid >> 3) & 3, to = tid >> 5;
  const char* wsrc = (const char*)(W + (size_t)o * 1620);
  for (int g = tid; g < 405; g += 64)
    __builtin_amdgcn_global_load_lds(
        (const __attribute__((address_space(1))) void*)(wsrc + g * 16),
        (__attribute__((address_space(3))) void*)((char*)&wsl[0] + g * 16), 16, 0, 0);
  asm volatile("s_waitcnt vmcnt(0)" ::: "memory");
  __syncthreads();
  float acc = 0.f;
#pragma unroll 2
  for (int ci = 0; ci < 20; ci++) {
    const float* base = in + (size_t)(b * 20 + ci) * 1024;
    const float* wc = wsl + ci * 81;
#pragma unroll
    for (int kt = 0; kt < 3; kt++) {
      int t = 2 * to + kt - 1;
      bool tok = t >= 0; int tc = tok ? t : 0;
#pragma unroll
      for (int kx = 0; kx < 3; kx++) {
        int xx = 2 * xo + kx - 1;
        bool xok = xx >= 0; int xc = xok ? xx : 0;
#pragma unroll
        for (int ky = 0; ky < 3; ky++) {
          int yy = 2 * yo + ky - 1;
          bool yok = yy >= 0; int yc = yok ? yy : 0;
          const float* p = base + tc * 256 + xc * 32 + yc * 4;
          float2 vz = *(const float2*)(p + 2 * zo);
          float vl = p[(zo > 0) ? (2 * zo - 1) : 0];
          bool m = tok && xok && yok;
          float v0 = (m && zo > 0) ? vl : 0.f;
          float v1 = m ? vz.x : 0.f;
          float v2 = m ? vz.y : 0.f;
          const float* wp = wc + ((kt * 3 + kx) * 3 + ky) * 3;
          acc += v0 * wp[0];
          acc += v1 * wp[1];
          acc += v2 * wp[2];
        }
      }
    }
  }
  size_t oidx = ((((size_t)(b * 20 + o) * 2 + to) * 4 + xo) * 4 + yo) * 2 + zo;
  out[oidx] = acc;
}

// c31: 3^4 stride-1 conv, in/out [b][20][2][4][4][2]. Block = (o,b) grid 80, 64 thr.
__global__ __launch_bounds__(64) void k_c31(
    const float* __restrict__ in, const float* __restrict__ W,
    float* __restrict__ out) {
  __shared__ __align__(16) float wsl[1620];
  int bid = blockIdx.x;
  int o = bid % 20, b = bid / 20;
  int tid = threadIdx.x;
  int zo = tid & 1, yo = (tid >> 1) & 3, xo = (tid >> 3) & 3, to = tid >> 5;
  const char* wsrc = (const char*)(W + (size_t)o * 1620);
  for (int g = tid; g < 405; g += 64)
    __builtin_amdgcn_global_load_lds(
        (const __attribute__((address_space(1))) void*)(wsrc + g * 16),
        (__attribute__((address_space(3))) void*)((char*)&wsl[0] + g * 16), 16, 0, 0);
  asm volatile("s_waitcnt vmcnt(0)" ::: "memory");
  __syncthreads();
  float acc = 0.f;
#pragma unroll 2
  for (int ci = 0; ci < 20; ci++) {
    const float* base = in + (size_t)(b * 20 + ci) * 64;
    const float* wc = wsl + ci * 81;
#pragma unroll
    for (int kt = 0; kt < 3; kt++) {
      int t = to + kt - 1;
      bool tok = (t >= 0) && (t < 2); int tc = tok ? t : 0;
#pragma unroll
      for (int kx = 0; kx < 3; kx++) {
        int xx = xo + kx - 1;
        bool xok = (xx >= 0) && (xx < 4); int xc = xok ? xx : 0;
#pragma unroll
        for (int ky = 0; ky < 3; ky++) {
          int yy = yo + ky - 1;
          bool yok = (yy >= 0) && (yy < 4); int yc = yok ? yy : 0;
          const float* p = base + tc * 32 + xc * 8 + yc * 2;
          float vl = p[(zo > 0) ? (zo - 1) : 0];
          float vm = p[zo];
          float vh = p[zo + 1];  // overread <=1 elem at zo==1: masked, in-arena
          bool m = tok && xok && yok;
          float v0 = (m && zo > 0) ? vl : 0.f;
          float v1 = m ? vm : 0.f;
          float v2 = (m && zo < 1) ? vh : 0.f;
          const float* wp = wc + ((kt * 3 + kx) * 3 + ky) * 3;
          acc += v0 * wp[0];
          acc += v1 * wp[1];
          acc += v2 * wp[2];
        }
      }
    }
  }
  size_t oidx = ((((size_t)(b * 20 + o) * 2 + to) * 4 + xo) * 4 + yo) * 2 + zo;
  out[oidx] = acc;
}

// ---------------- BN ----------------
__global__ void k_bn_stats(const float* __restrict__ d, int S, float* __restrict__ stats) {
  int c = blockIdx.x;
  int tid = threadIdx.x;
  float s = 0.f, s2 = 0.f;
  for (int b = 0; b < 4; b++) {
    const float* p = d + ((size_t)b * 20 + c) * S;
    for (int i = tid; i < S; i += 256) { float v = p[i]; s += v; s2 += v * v; }
  }
  __shared__ float ls[256], lq[256];
  ls[tid] = s; lq[tid] = s2;
  __syncthreads();
  for (int off = 128; off > 0; off >>= 1) {
    if (tid < off) { ls[tid] += ls[tid + off]; lq[tid] += lq[tid + off]; }
    __syncthreads();
  }
  if (tid == 0) {
    float cnt = 4.f * (float)S;
    float mean = ls[0] / cnt;
    float var = lq[0] / cnt - mean * mean;
    stats[2 * c] = mean;
    stats[2 * c + 1] = rsqrtf(var + 1e-5f);
  }
}

__global__ void k_bn_apply(float* __restrict__ d, int S, const float* __restrict__ stats,
                           const float* __restrict__ g, const float* __restrict__ bb, int n) {
  int idx = blockIdx.x * 256 + threadIdx.x;
  if (idx >= n) return;
  int c = (idx / S) % 20;
  float v = d[idx];
  v = (v - stats[2 * c]) * stats[2 * c + 1] * g[c] + bb[c];
  d[idx] = (v >= 0.f) ? v : 0.1f * v;
}

// channels-last bf16 fill of CLd0 ci 0..19 from post-BN oc1: thread per (b,s),
// 20 strided coalesced reads -> one packed 40B vector store (5 x uint2).
__global__ void k_cl20(const float* __restrict__ oc1, short* __restrict__ CL, int n) {
  int i = blockIdx.x * 256 + threadIdx.x;
  if (i >= n) return;
  int s = i & 16383, b = i >> 14;
  const float* src = oc1 + (size_t)b * 20 * 16384 + s;
  unsigned h[20];
#pragma unroll
  for (int c = 0; c < 20; c++) h[c] = (unsigned)(unsigned short)f2bf(src[(size_t)c * 16384]);
  uint2* dst = (uint2*)(CL + (size_t)i * 40);
#pragma unroll
  for (int q = 0; q < 5; q++) dst[q] = make_uint2(h[4 * q] | (h[4 * q + 1] << 16),
                                                  h[4 * q + 2] | (h[4 * q + 3] << 16));
}

// ---------------- deconv (ConvTranspose4d k=4 s=2 p=1), bias+lrelu fused ----------------
__device__ __forceinline__ int dcands(int p, int n_in, int* q, int* k) {
  int cnt = 0;
  int q0 = (p + 1) >> 1, k0 = p + 1 - 2 * q0;
  if (q0 >= 0 && q0 < n_in) { q[cnt] = q0; k[cnt] = k0; cnt++; }
  int q1 = q0 - 1, k1 = k0 + 2;
  if (q1 >= 0 && q1 < n_in) { q[cnt] = q1; k[cnt] = k1; cnt++; }
  return cnt;
}

__global__ void k_deconv4d(const float* __restrict__ in1, int Ci1,
                           const float* __restrict__ in2, int Ci2,
                           const float* __restrict__ W, const float* __restrict__ bias,
                           float* __restrict__ out,
                           int Ti, int Xi, int Yi, int Zi, int n) {
  int idx = blockIdx.x * 256 + threadIdx.x;
  if (idx >= n) return;
  int To = 2 * Ti, Xo = 2 * Xi, Yo = 2 * Yi, Zo = 2 * Zi;
  int zo = idx % Zo; int r = idx / Zo;
  int yo = r % Yo; r /= Yo;
  int xo = r % Xo; r /= Xo;
  int to = r % To; int b = r / To;
  int qt[2], kt[2], qx[2], kx[2], qy[2], ky[2], qz[2], kz[2];
  int nt = dcands(to, Ti, qt, kt), nx = dcands(xo, Xi, qx, kx);
  int ny = dcands(yo, Yi, qy, ky), nz = dcands(zo, Zi, qz, kz);
  float acc[20];
#pragma unroll
  for (int o = 0; o < 20; o++) acc[o] = 0.f;
  int Ci = Ci1 + Ci2;
  size_t in_sp = (size_t)Ti * Xi * Yi * Zi;
  for (int ci = 0; ci < Ci; ci++) {
    const float* base = (ci < Ci1) ? in1 + ((size_t)b * Ci1 + ci) * in_sp
                                   : in2 + ((size_t)b * Ci2 + (ci - Ci1)) * in_sp;
    const float* wc = W + (size_t)ci * 5120;  // [ci][o(20)][256]
    for (int it = 0; it < nt; it++)
      for (int ix = 0; ix < nx; ix++)
        for (int iy = 0; iy < ny; iy++)
          for (int iz = 0; iz < nz; iz++) {
            float v = base[(((size_t)qt[it] * Xi + qx[ix]) * Yi + qy[iy]) * Zi + qz[iz]];
            int tap = ((kt[it] * 4 + kx[ix]) * 4 + ky[iy]) * 4 + kz[iz];
#pragma unroll
            for (int o = 0; o < 20; o++) acc[o] += v * wc[o * 256 + tap];
          }
  }
  size_t osp = (size_t)To * Xo * Yo * Zo;
  size_t obase = (size_t)b * 20 * osp + (((size_t)to * Xo + xo) * Yo + yo) * Zo + zo;
#pragma unroll
  for (int o = 0; o < 20; o++) {
    float v2 = acc[o] + bias[o];
    out[obase + (size_t)o * osp] = (v2 >= 0.f) ? v2 : 0.1f * v2;
  }
}

// d1 deconv: in 4x8x8x4 (oc2|od2, Ci=40) -> out 8x16x16x8 written bf16 CL ci 20..39
__global__ void k_deconv_d1_cl(const float* __restrict__ in1, const float* __restrict__ in2,
                               const float* __restrict__ W, const float* __restrict__ bias,
                               short* __restrict__ CL, int n) {
  int idx = blockIdx.x * 256 + threadIdx.x;
  if (idx >= n) return;
  int zo = idx & 7; int r = idx >> 3;
  int yo = r & 15; r >>= 4;
  int xo = r & 15; r >>= 4;
  int to = r & 7; int b = r >> 3;
  int qt[2], kt[2], qx[2], kx[2], qy[2], ky[2], qz[2], kz[2];
  int nt = dcands(to, 4, qt, kt), nx = dcands(xo, 8, qx, kx);
  int ny = dcands(yo, 8, qy, ky), nz = dcands(zo, 4, qz, kz);
  float acc[20];
#pragma unroll
  for (int o = 0; o < 20; o++) acc[o] = 0.f;
  const size_t in_sp = 4 * 8 * 8 * 4;
  for (int ci = 0; ci < 40; ci++) {
    const float* base = (ci < 20) ? in1 + ((size_t)b * 20 + ci) * in_sp
                                  : in2 + ((size_t)b * 20 + (ci - 20)) * in_sp;
    const float* wc = W + (size_t)ci * 5120;
    for (int it = 0; it < nt; it++)
      for (int ix = 0; ix < nx; ix++)
        for (int iy = 0; iy < ny; iy++)
          for (int iz = 0; iz < nz; iz++) {
            float v = base[(((size_t)qt[it] * 8 + qx[ix]) * 8 + qy[iy]) * 4 + qz[iz]];
            int tap = ((kt[it] * 4 + kx[ix]) * 4 + ky[iy]) * 4 + kz[iz];
#pragma unroll
            for (int o = 0; o < 20; o++) acc[o] += v * wc[o * 256 + tap];
          }
  }
  size_t pos = (((size_t)b * 8 + to) * 16 + xo) * 16 * 8 + (size_t)yo * 8 + zo;
  unsigned h[20];
#pragma unroll
  for (int o = 0; o < 20; o++) {
    float v2 = acc[o] + bias[o];
    v2 = (v2 >= 0.f) ? v2 : 0.1f * v2;
    h[o] = (unsigned)(unsigned short)f2bf(v2);
  }
  uint2* dst = (uint2*)(CL + pos * 40 + 20);
#pragma unroll
  for (int q = 0; q < 5; q++) dst[q] = make_uint2(h[4 * q] | (h[4 * q + 1] << 16),
                                                  h[4 * q + 2] | (h[4 * q + 3] << 16));
}

// fill Xcl ci 0..19 from x (packed 40B vector stores)
__global__ void k_xcl_x(const float* __restrict__ x, short* __restrict__ Xcl, int n) {
  int i = blockIdx.x * 256 + threadIdx.x;
  if (i >= n) return;
  int s = i & 262143, b = i >> 18;
  const float* src = x + (size_t)b * 20 * 262144 + s;
  unsigned h[20];
#pragma unroll
  for (int c = 0; c < 20; c++) h[c] = (unsigned)(unsigned short)f2bf(src[(size_t)c * 262144]);
  uint2* dst = (uint2*)(Xcl + (size_t)i * 40);
#pragma unroll
  for (int q = 0; q < 5; q++) dst[q] = make_uint2(h[4 * q] | (h[4 * q + 1] << 16),
                                                  h[4 * q + 2] | (h[4 * q + 3] << 16));
}

// pack out_w [20][40][81] + w_pw [20][20] -> Wp[tap(82)][mt(2)][m(16)][k(64)] bf16,
// bank-swizzled for LDS staging: short index i -> i ^ ((m&7)<<3)  (byte ^ ((m&7)<<4)).
// tap 81 = pointwise (x2) weights.
__global__ void k_pack_w(const float* __restrict__ out_w, const float* __restrict__ w_pw,
                         short* __restrict__ Wp, short* __restrict__ zp, int n) {
  int i = blockIdx.x * 256 + threadIdx.x;
  if (i >= n) return;
  int k = i & 63, m = (i >> 6) & 15, mt = (i >> 10) & 1, tap = i >> 11;
  int o = mt * 16 + m;
  float v = 0.f;
  if (o < 20 && k < 40) {
    if (tap < 81) v = out_w[((size_t)o * 40 + k) * 81 + tap];
    else if (k < 20) v = w_pw[o * 20 + k];
  }
  Wp[i ^ ((m & 7) << 3)] = f2bf(v);
  if (i < 64) zp[i] = 0;
}

// pack d0_w [40][20][256] -> Wd parity-class-major:
// [h(32)=cls*2+it][sub(8)=ix*4+iz*2+iy][mt(2)][m(16)][k(64)] bf16,
// bank-swizzled: element index i -> i ^ ((m&7)<<3)  (byte ^ ((row&7)<<4)).
__global__ void k_pack_wd(const float* __restrict__ d0_w, short* __restrict__ Wd, int n) {
  int i = blockIdx.x * 256 + threadIdx.x;
  if (i >= n) return;
  int k = i & 63, m = (i >> 6) & 15, mt = (i >> 10) & 1, sub = (i >> 11) & 7, h = i >> 14;
  int it = h & 1, cls = h >> 1;
  int ez = cls & 1, ey = (cls >> 1) & 1, ex = (cls >> 2) & 1, et = (cls >> 3) & 1;
  int iy = sub & 1, iz = (sub >> 1) & 1, ix = (sub >> 2) & 1;
  int kt = et ? (2 * it) : (1 + 2 * it);
  int kx = ex ? (2 * ix) : (1 + 2 * ix);
  int ky = ey ? (2 * iy) : (1 + 2 * iy);
  int kz = ez ? (2 * iz) : (1 + 2 * iz);
  int tap = ((kt * 4 + kx) * 4 + ky) * 4 + kz;
  int o = mt * 16 + m;
  float v = (o < 20 && k < 40) ? d0_w[((size_t)k * 20 + o) * 256 + tap] : 0.f;
  Wd[i ^ ((m & 7) << 3)] = f2bf(v);
}

// ---------------- d0 deconv via MFMA (parity-class, LDS-staged) ----------------
__global__ __launch_bounds__(512) void k_d0_mfma(
    const short* __restrict__ CLd0, const short* __restrict__ Wd,
    const float* __restrict__ bias, short* __restrict__ Xcl) {
  __shared__ __align__(16) char lds[157696];  // 9*10240 B-planes + 2*32768 A dbuf
  char* lds_a = lds + 92160;
  int bid = blockIdx.x;
  int ux = bid & 15, ut = (bid >> 4) & 7, b = bid >> 7;
  int tid = threadIdx.x;
  int uz = tid >> 6;
  int lane = tid & 63, ln15 = lane & 15, kg = lane >> 4;  // ln15 = uy

  const char* xb = (const char*)CLd0;
  const char* wb = (const char*)Wd;

  auto gld = [](const char* src, char* dst) {
    __builtin_amdgcn_global_load_lds(
        (const __attribute__((address_space(1))) void*)src,
        (__attribute__((address_space(3))) void*)dst, 16, 0, 0);
  };

  // ---- prologue: stage B planes (swizzle baked into per-lane global src) ----
#pragma unroll
  for (int pt = 0; pt < 3; pt++) {
    int qt = ut - 1 + pt;
    if (qt < 0 || qt > 7) continue;
#pragma unroll
    for (int px = 0; px < 3; px++) {
      int qx = ux - 1 + px;
      if (qx < 0 || qx > 15) continue;
      const char* src = xb + (size_t)((b * 8 + qt) * 16 + qx) * 10240;
      char* dst = lds + (pt * 3 + px) * 10240;
      for (int g = tid; g < 640; g += 512) {
        int key = ((g / 40) & 7) << 4;
        gld(src + ((g * 16) ^ key), dst + g * 16);
      }
    }
  }
  // stage A half-block h=0 (pack is pre-swizzled -> linear copy)
  for (int g = tid; g < 2048; g += 512) gld(wb + g * 16, lds_a + g * 16);
  asm volatile("s_waitcnt vmcnt(0)" ::: "memory");
  __syncthreads();

  bf16x8 zv = {0, 0, 0, 0, 0, 0, 0, 0};
  int aswz = ((ln15 * 128 + kg * 16) ^ ((ln15 & 7) << 4));

#pragma unroll 1
  for (int cls = 0; cls < 16; cls++) {
    int ez = cls & 1, ey = (cls >> 1) & 1, ex = (cls >> 2) & 1, et = (cls >> 3) & 1;
    f32x4 acc0, acc1;
#pragma unroll
    for (int j = 0; j < 4; j++) { acc0[j] = 0.f; acc1[j] = 0.f; }
#pragma unroll
    for (int it = 0; it < 2; it++) {
      int h = cls * 2 + it;
      // stage next A half-block into the other buffer
      if (h + 1 < 32) {
        const char* asrc = wb + (size_t)(h + 1) * 32768;
        char* adst = lds_a + (it ^ 1) * 32768;
        for (int g = tid; g < 2048; g += 512) gld(asrc + g * 16, adst + g * 16);
      }
      const char* ab = lds_a + it * 32768;
      int kt_q = ut + (et ? (1 - it) : (-it));
      if (kt_q >= 0 && kt_q <= 7) {
        int pt = kt_q - ut + 1;
#pragma unroll
        for (int ix = 0; ix < 2; ix++) {
          int qx = ux + (ex ? (1 - ix) : (-ix));
          if (qx < 0 || qx > 15) continue;
          int px = qx - ux + 1;
          const char* pbase = lds + (pt * 3 + px) * 10240;
#pragma unroll
          for (int iz = 0; iz < 2; iz++) {
            int qz = uz + (ez ? (1 - iz) : (-iz));
            if (qz < 0 || qz > 7) continue;
#pragma unroll
            for (int iy = 0; iy < 2; iy++) {
              int qy = ln15 + (ey ? (1 - iy) : (-iy));
              bool yok = (qy >= 0) && (qy < 16);
              int qyc = yok ? qy : 0;
              int bkey = (qyc & 7) << 4;
              const char* abase = ab + (ix * 4 + iz * 2 + iy) * 4096;
#pragma unroll
              for (int ch = 0; ch < 2; ch++) {
                int co = ch ? 64 : kg * 16;  // ch=1: broadcast ci 32..39 (k>=40 wts are 0)
                int boff = (qyc * 640 + qz * 80 + co) ^ bkey;
                bf16x8 bvv = *(const bf16x8*)(pbase + boff);
                bf16x8 bv = yok ? bvv : zv;
                int aoff = (ch ? (aswz ^ 64) : aswz);
                bf16x8 a0 = *(const bf16x8*)(abase + aoff);
                bf16x8 a1 = *(const bf16x8*)(abase + 2048 + aoff);
                acc0 = __builtin_amdgcn_mfma_f32_16x16x32_bf16(a0, bv, acc0, 0, 0, 0);
                acc1 = __builtin_amdgcn_mfma_f32_16x16x32_bf16(a1, bv, acc1, 0, 0, 0);
              }
            }
          }
        }
      }
      asm volatile("s_waitcnt vmcnt(0)" ::: "memory");
      __syncthreads();
    }
    int to = 2 * ut + et, xo = 2 * ux + ex, zo = 2 * uz + ez, yo = 2 * ln15 + ey;
    long opos = ((((long)b * 16 + to) * 32 + xo) * 32 + yo) * 16 + zo;
    short* dst = Xcl + opos * 40 + 20;
    {
      unsigned hh[4];
#pragma unroll
      for (int r = 0; r < 4; r++) {
        float v = acc0[r] + bias[kg * 4 + r];
        v = (v >= 0.f) ? v : 0.1f * v;
        hh[r] = (unsigned)(unsigned short)f2bf(v);
      }
      uint2 u;
      u.x = hh[0] | (hh[1] << 16);
      u.y = hh[2] | (hh[3] << 16);
      *(uint2*)(dst + kg * 4) = u;
    }
    if (kg == 0) {
      unsigned hh[4];
#pragma unroll
      for (int r = 0; r < 4; r++) {
        float v = acc1[r] + bias[16 + r];
        v = (v >= 0.f) ? v : 0.1f * v;
        hh[r] = (unsigned)(unsigned short)f2bf(v);
      }
      uint2 u;
      u.x = hh[0] | (hh[1] << 16);
      u.y = hh[2] | (hh[3] << 16);
      *(uint2*)(dst + 16) = u;
    }
  }
}

// ---------------- final conv: fully LDS-staged bf16 MFMA implicit GEMM ----------------
__global__ __launch_bounds__(512) void k_fconv_mfma(
    const short* __restrict__ Xcl, const short* __restrict__ Wp,
    const float* __restrict__ bias, const float* __restrict__ bpw,
    float* __restrict__ io) {
  __shared__ __align__(16) char ldsB[2][40960];
  __shared__ __align__(16) char ldsW[2][36864];
  int bid = blockIdx.x;
  int xcd = bid & 7, idx = bid >> 3;
  int b = xcd >> 1, xh = xcd & 1;
  // t0-major within each XCD: working set 3 xi-slabs x 16 ti x 40KB ~ 1.9MB < 4MB L2
  int t0 = idx & 15, x0 = xh * 16 + ((idx >> 4) & 15);
  int tid = threadIdx.x;
  int lane = tid & 63;
  int ln15 = lane & 15, kg = lane >> 4;
  int ybase = (tid >> 6) * 4;

  // valid (kt,kx) slab list, 4 bits per entry (code = kt*4+kx; center = 5)
  unsigned long long codes = 0ull;
  int ns = 0;
  for (int kt = 0; kt < 3; kt++) {
    int ti = t0 + kt - 1;
    if (ti < 0 || ti > 15) continue;
    for (int kx = 0; kx < 3; kx++) {
      int xi = x0 + kx - 1;
      if (xi < 0 || xi > 31) continue;
      codes |= (unsigned long long)(kt * 4 + kx) << (4 * ns);
      ns++;
    }
  }

  const char* xb = (const char*)Xcl;
  const char* wb = (const char*)Wp;

  auto gld = [](const char* src, char* dst) {
    __builtin_amdgcn_global_load_lds(
        (const __attribute__((address_space(1))) void*)src,
        (__attribute__((address_space(3))) void*)dst, 16, 0, 0);
  };

  auto stage = [&](int buf, int code) {
    int kt = code >> 2, kx = code & 3;
    int ti = t0 + kt - 1, xi = x0 + kx - 1;
    const char* src = xb + (size_t)((b * 16 + ti) * 32 + xi) * 512 * 80;
    char* dstB = ldsB[buf];
#pragma unroll
    for (int s = 0; s < 5; s++) {
      int off = s * 8192 + tid * 16;
      gld(src + off, dstB + off);
    }
    // 9-tap contiguous weight run for this slab: taps (kt*3+kx)*9 .. +8
    const char* wsrc = wb + (size_t)(kt * 3 + kx) * 9 * 4096;
    char* dstW = ldsW[buf];
    for (int g = tid; g < 2304; g += 512) gld(wsrc + g * 16, dstW + g * 16);
  };

  f32x4 acc[2][4];
#pragma unroll
  for (int mt = 0; mt < 2; mt++)
#pragma unroll
    for (int nt = 0; nt < 4; nt++)
#pragma unroll
      for (int j = 0; j < 4; j++) acc[mt][nt][j] = 0.f;

  int awz0 = (ln15 * 128 + kg * 16) ^ ((ln15 & 7) << 4);
  int awz1 = (ln15 * 128 + 64 + kg * 16) ^ ((ln15 & 7) << 4);

  stage(0, (int)(codes & 15));
  asm volatile("s_waitcnt vmcnt(0)" ::: "memory");
  __syncthreads();

  int cur = 0;
#pragma unroll 1
  for (int i = 0; i < ns; i++) {
    const char* bufB = ldsB[cur];
    const char* bufW = ldsW[cur];
    if (i + 1 < ns) stage(cur ^ 1, (int)((codes >> (4 * (i + 1))) & 15));
    int code = (int)((codes >> (4 * i)) & 15);
    bf16x8 zv = {0, 0, 0, 0, 0, 0, 0, 0};
#pragma unroll
    for (int kz = 0; kz < 3; kz++) {
      int zi = ln15 + kz - 1;
      bool zok = (zi >= 0) && (zi < 16);
      int zc = zok ? zi : 0;
#pragma unroll
      for (int ch = 0; ch < 2; ch++) {
        int co = ch ? 64 : kg * 16;  // ch=1: broadcast ci 32..39 chunk to all kg
        bf16x8 bv[6];
#pragma unroll
        for (int j = 0; j < 6; j++) {
          int yi = ybase + j - 1;
          int yc = (yi < 0) ? 0 : ((yi > 31) ? 31 : yi);
          bf16x8 v = *(const bf16x8*)(bufB + (size_t)(yc * 16 + zc) * 80 + co);
          bool ok = zok && (yi >= 0) && (yi < 32);
          bv[j] = ok ? v : zv;
        }
        int awz = ch ? awz1 : awz0;
        bf16x8 av[3][2];
#pragma unroll
        for (int ky = 0; ky < 3; ky++) {
          const char* wt = bufW + (size_t)(ky * 3 + kz) * 4096;
          av[ky][0] = *(const bf16x8*)(wt + awz);
          av[ky][1] = *(const bf16x8*)(wt + 2048 + awz);
        }
#pragma unroll
        for (int ky = 0; ky < 3; ky++)
#pragma unroll
          for (int nt = 0; nt < 4; nt++) {
            acc[0][nt] = __builtin_amdgcn_mfma_f32_16x16x32_bf16(av[ky][0], bv[nt + ky], acc[0][nt], 0, 0, 0);
            acc[1][nt] = __builtin_amdgcn_mfma_f32_16x16x32_bf16(av[ky][1], bv[nt + ky], acc[1][nt], 0, 0, 0);
          }
      }
    }
    if (code == 5) {
      // center slab: fused pointwise (x2) tap, ci 0..19 (weights zero for k>=20)
      const char* wt = wb + (size_t)81 * 4096;
      bf16x8 a0 = *(const bf16x8*)(wt + awz0);
      bf16x8 a1 = *(const bf16x8*)(wt + 2048 + awz0);
#pragma unroll
      for (int nt = 0; nt < 4; nt++) {
        bf16x8 bv = *(const bf16x8*)(bufB + (size_t)((ybase + nt) * 16 + ln15) * 80 + kg * 16);
        acc[0][nt] = __builtin_amdgcn_mfma_f32_16x16x32_bf16(a0, bv, acc[0][nt], 0, 0, 0);
        acc[1][nt] = __builtin_amdgcn_mfma_f32_16x16x32_bf16(a1, bv, acc[1][nt], 0, 0, 0);
      }
    }
    asm volatile("s_waitcnt vmcnt(0)" ::: "memory");
    __syncthreads();
    cur ^= 1;
  }

#pragma unroll
  for (int mt = 0; mt < 2; mt++)
#pragma unroll
    for (int r = 0; r < 4; r++) {
      int o = mt * 16 + kg * 4 + r;
      if (o >= 20) continue;
      float bo = bias[o] + bpw[o];
#pragma unroll
      for (int nt = 0; nt < 4; nt++) {
        int y = ybase + nt;
        size_t oidx = ((size_t)(b * 20 + o)) * 262144 +
                      ((((size_t)t0 * 32 + x0) * 32 + y) * 16 + ln15);
        float v = acc[mt][nt][r] + bo + io[oidx];
        io[oidx] = fmaxf(v, 0.f);
      }
    }
}

extern "C" void kernel_launch(void* const* d_in, const int* in_sizes, int n_in,
                              void* d_out, int out_size, void* d_ws, size_t ws_size,
                              hipStream_t stream) {
  const float* x     = (const float*)d_in[0];
  const float* sw1   = (const float*)d_in[1];
  const float* sw2   = (const float*)d_in[2];
  const float* sw3   = (const float*)d_in[3];
  const float* sw4   = (const float*)d_in[4];
  const float* w_pw  = (const float*)d_in[5];
  const float* b_pw  = (const float*)d_in[6];
  const float* c1_w  = (const float*)d_in[7];
  const float* c2_w  = (const float*)d_in[8];
  const float* c21_w = (const float*)d_in[9];
  const float* c3_w  = (const float*)d_in[10];
  const float* c31_w = (const float*)d_in[11];
  const float* bn1_g = (const float*)d_in[12];
  const float* bn1_b = (const float*)d_in[13];
  const float* bn2_g = (const float*)d_in[14];
  const float* bn2_b = (const float*)d_in[15];
  const float* bn21_g = (const float*)d_in[16];
  const float* bn21_b = (const float*)d_in[17];
  const float* bn3_g = (const float*)d_in[18];
  const float* bn3_b = (const float*)d_in[19];
  const float* bn31_g = (const float*)d_in[20];
  const float* bn31_b = (const float*)d_in[21];
  const float* d2_w  = (const float*)d_in[22];
  const float* d2_b  = (const float*)d_in[23];
  const float* d1_w  = (const float*)d_in[24];
  const float* d1_b  = (const float*)d_in[25];
  const float* d0_w  = (const float*)d_in[26];
  const float* d0_b  = (const float*)d_in[27];
  const float* out_w = (const float*)d_in[28];
  const float* out_b = (const float*)d_in[29];
  float* out = (float*)d_out;
  float* ws = (float*)d_ws;

  // spectral arena (phase 1 only)
  float2* A  = (float2*)(ws);
  float2* Bb = (float2*)(ws + 10485760);
  float2* Cb = (float2*)(ws + 13107200);
  float2* Dd = (float2*)(ws + 14417920);
  float2* Ee = (float2*)(ws + 15073280);
  float2* Ff = (float2*)(ws + 15728640);
  float2* Gg = (float2*)(ws + 16384000);
  // twiddle tables: live only during spectral phase; region inside Xcl span,
  // beyond the spectral arena end (17,039,360 fl), overwritten later by k_xcl_x.
  float2* Twid = (float2*)(ws + 23000000);

  // U-Net arena
  float* oc1   = ws;
  short* CLd0  = (short*)(ws + 1310720);
  float* Wc1   = ws + 1310720;  // aliases CLd0 region: used only between pack and cl20
  float* oc2a  = ws + 2621440;
  float* oc2   = ws + 2703360;
  float* oc3a  = ws + 2785280;
  float* oc3   = ws + 2790400;
  float* od2   = ws + 2795520;
  short* Xcl   = (short*)(ws + 2877440);
  float* stats = ws + 23848960;
  short* Wd = (short*)(ws);
  short* Wp = (short*)(ws + 262144);
  short* zp = (short*)(ws + 349184);

  auto nb = [](int n) { return (n + 255) / 256; };
  dim3 blk(256);

  // ---- twiddle tables ----
  k_twid<<<1, 64, 0, stream>>>(Twid);

  // ---- spectral path: x1 -> d_out ----
  k_fwd_z<<<nb(1310720), blk, 0, stream>>>(x, Twid, A, 1310720);
  k_fwd_y<<<nb(1310720), blk, 0, stream>>>(A, Twid, Bb, 1310720);
  k_fwd_x<<<nb(655360), blk, 0, stream>>>(Bb, Twid, Cb, 655360);
  k_fwd_t<<<nb(327680), blk, 0, stream>>>(Cb, Twid, Dd, 327680);
  k_fwd_c<<<nb(327680), blk, 0, stream>>>(Dd, Twid, Ee, 327680);
  k_fwd_b<<<nb(327680), blk, 0, stream>>>(Ee, Twid, Ff, 327680);
  k_smul<<<nb(327680), blk, 0, stream>>>(Ff, sw1, sw2, sw3, sw4, Gg, 327680);
  k_inv_t<<<nb(655360), blk, 0, stream>>>(Gg, Twid, Cb, 655360);
  k_inv_x<<<nb(1310720), blk, 0, stream>>>(Cb, Twid, Bb, 1310720);
  k_inv_yz<<<nb(1310720), blk, 0, stream>>>(Bb, Twid, out, 1310720);

  // ---- Xcl ci 0..19 from x; c1 weight pack (into dead CLd0 region) ----
  k_pack_c1<<<nb(32400), blk, 0, stream>>>(c1_w, Wc1, 32400);
  k_xcl_x<<<nb(1048576), blk, 0, stream>>>(x, Xcl, 1048576);

  // ---- U-Net encoder ----
  k_c1<<<512, dim3(128), 0, stream>>>(x, Wc1, oc1);
  k_bn_stats<<<20, blk, 0, stream>>>(oc1, 16384, stats);
  k_bn_apply<<<nb(1310720), blk, 0, stream>>>(oc1, 16384, stats, bn1_g, bn1_b, 1310720);
  k_cl20<<<nb(65536), blk, 0, stream>>>(oc1, CLd0, 65536);

  k_c2<<<320, blk, 0, stream>>>(oc1, c2_w, oc2a);
  k_bn_stats<<<20, blk, 0, stream>>>(oc2a, 1024, stats);
  k_bn_apply<<<nb(81920), blk, 0, stream>>>(oc2a, 1024, stats, bn2_g, bn2_b, 81920);

  k_c21<<<320, blk, 0, stream>>>(oc2a, c21_w, oc2);
  k_bn_stats<<<20, blk, 0, stream>>>(oc2, 1024, stats);
  k_bn_apply<<<nb(81920), blk, 0, stream>>>(oc2, 1024, stats, bn21_g, bn21_b, 81920);

  k_c3<<<80, dim3(64), 0, stream>>>(oc2, c3_w, oc3a);
  k_bn_stats<<<20, blk, 0, stream>>>(oc3a, 64, stats);
  k_bn_apply<<<nb(5120), blk, 0, stream>>>(oc3a, 64, stats, bn3_g, bn3_b, 5120);

  k_c31<<<80, dim3(64), 0, stream>>>(oc3a, c31_w, oc3);
  k_bn_stats<<<20, blk, 0, stream>>>(oc3, 64, stats);
  k_bn_apply<<<nb(5120), blk, 0, stream>>>(oc3, 64, stats, bn31_g, bn31_b, 5120);

  // ---- decoder ----
  k_deconv4d<<<nb(4096), blk, 0, stream>>>(oc3, 20, nullptr, 0, d2_w, d2_b, od2,
                                           2, 4, 4, 2, 4096);
  k_deconv_d1_cl<<<nb(65536), blk, 0, stream>>>(oc2, od2, d1_w, d1_b, CLd0, 65536);

  // weight packs
  k_pack_w<<<nb(167936), blk, 0, stream>>>(out_w, w_pw, Wp, zp, 167936);
  k_pack_wd<<<nb(524288), blk, 0, stream>>>(d0_w, Wd, 524288);

  // d0 deconv via MFMA (LDS-staged) -> Xcl ci 20..39
  k_d0_mfma<<<512, dim3(512), 0, stream>>>(CLd0, Wd, d0_b, Xcl);

  // final conv via MFMA (fully LDS-staged), fused +bias +x1 +x2(pointwise) +relu into d_out
  k_fconv_mfma<<<2048, dim3(512), 0, stream>>>(Xcl, Wp, out_b, b_pw, out);
}

// Round 8
// 1622.425 us; speedup vs baseline: 2.0948x; 1.0163x over previous
//
#include <hip/hip_runtime.h>

#define PI2 6.28318530717958647692f

typedef __attribute__((ext_vector_type(8))) short bf16x8;
typedef __attribute__((ext_vector_type(4))) float f32x4;

__device__ __forceinline__ void cfma(float2& acc, float2 a, float2 t) {
  acc.x += a.x * t.x - a.y * t.y;
  acc.y += a.x * t.y + a.y * t.x;
}
// multiply by conj(t) (inverse twiddle), t = e^{-i\theta}
__device__ __forceinline__ void cfmac(float2& acc, float2 a, float2 t) {
  acc.x += a.x * t.x + a.y * t.y;
  acc.y += a.y * t.x - a.x * t.y;
}

__device__ __forceinline__ short f2bf(float f) {
  unsigned u = __float_as_uint(f);
  unsigned r = (u + 0x7fff + ((u >> 16) & 1)) >> 16;
  return (short)r;
}

// twiddle tables: T[0..31]=e^{-2pi i m/32}, T[32..47]=N16, T[48..67]=N20, T[68..71]=N4
__global__ void k_twid(float2* __restrict__ T) {
  int i = threadIdx.x;
  float s, c;
  if (i < 32) { __sincosf(-PI2 * (float)i / 32.f, &s, &c); T[i] = make_float2(c, s); }
  if (i < 16) { __sincosf(-PI2 * (float)i / 16.f, &s, &c); T[32 + i] = make_float2(c, s); }
  if (i < 20) { __sincosf(-PI2 * (float)i / 20.f, &s, &c); T[48 + i] = make_float2(c, s); }
  if (i < 4)  { __sincosf(-PI2 * (float)i / 4.f,  &s, &c); T[68 + i] = make_float2(c, s); }
}

// ---------------- spectral forward ----------------
__global__ void k_fwd_z(const float* __restrict__ x, const float2* __restrict__ T,
                        float2* __restrict__ out, int nrows) {
  __shared__ float2 tw[16];
  if (threadIdx.x < 16) tw[threadIdx.x] = T[32 + threadIdx.x];
  __syncthreads();
  int r = blockIdx.x * 256 + threadIdx.x;
  if (r >= nrows) return;
  const float* p = x + (size_t)r * 16;
  float v[16];
#pragma unroll
  for (int z = 0; z < 16; z++) v[z] = p[z];
#pragma unroll
  for (int zk = 0; zk < 4; zk++) {
    float re = 0.f, im = 0.f;
#pragma unroll
    for (int z = 0; z < 16; z++) {
      float2 t = tw[(z * zk) & 15];
      re += v[z] * t.x;
      im += v[z] * t.y;
    }
    out[(size_t)r * 4 + zk] = make_float2(re, im);
  }
}

__global__ void k_fwd_y(const float2* __restrict__ in, const float2* __restrict__ T,
                        float2* __restrict__ out, int n) {
  __shared__ float2 tw[32];
  if (threadIdx.x < 32) tw[threadIdx.x] = T[threadIdx.x];
  __syncthreads();
  int i = blockIdx.x * 256 + threadIdx.x;
  if (i >= n) return;
  int zk = i & 3, yk = (i >> 2) & 7, slab = i >> 5;
  const float2* p = in + (size_t)slab * 128 + zk;
  float2 acc = make_float2(0.f, 0.f);
  for (int y = 0; y < 32; y++) cfma(acc, p[y * 4], tw[(y * yk) & 31]);
  out[i] = acc;
}

__global__ void k_fwd_x(const float2* __restrict__ in, const float2* __restrict__ T,
                        float2* __restrict__ out, int n) {
  __shared__ float2 tw[32];
  if (threadIdx.x < 32) tw[threadIdx.x] = T[threadIdx.x];
  __syncthreads();
  int i = blockIdx.x * 256 + threadIdx.x;
  if (i >= n) return;
  int zk = i & 3, yk = (i >> 2) & 7, xi = (i >> 5) & 15, slab = i >> 9;
  int xk = (xi < 8) ? xi : xi + 16;
  const float2* p = in + (size_t)slab * 1024 + yk * 4 + zk;
  float2 acc = make_float2(0.f, 0.f);
  for (int xx = 0; xx < 32; xx++) cfma(acc, p[xx * 32], tw[(xx * xk) & 31]);
  out[i] = acc;
}

__global__ void k_fwd_t(const float2* __restrict__ in, const float2* __restrict__ T,
                        float2* __restrict__ out, int n) {
  __shared__ float2 tw[16];
  if (threadIdx.x < 16) tw[threadIdx.x] = T[32 + threadIdx.x];
  __syncthreads();
  int i = blockIdx.x * 256 + threadIdx.x;
  if (i >= n) return;
  int zk = i & 3, yk = (i >> 2) & 7, xi = (i >> 5) & 15, ti = (i >> 9) & 7, bc = i >> 12;
  int tk = (ti < 4) ? ti : ti + 8;
  const float2* p = in + (size_t)bc * 8192 + xi * 32 + yk * 4 + zk;
  float2 acc = make_float2(0.f, 0.f);
  for (int t = 0; t < 16; t++) cfma(acc, p[t * 512], tw[(t * tk) & 15]);
  out[i] = acc;
}

__global__ void k_fwd_c(const float2* __restrict__ in, const float2* __restrict__ T,
                        float2* __restrict__ out, int n) {
  __shared__ float2 tw[20];
  if (threadIdx.x < 20) tw[threadIdx.x] = T[48 + threadIdx.x];
  __syncthreads();
  int i = blockIdx.x * 256 + threadIdx.x;
  if (i >= n) return;
  int mode = i & 4095, r = i >> 12, ck = r % 20, b = r / 20;
  const float2* p = in + (size_t)b * 81920 + mode;
  float2 acc = make_float2(0.f, 0.f);
  int idx = 0;
  for (int c = 0; c < 20; c++) {
    cfma(acc, p[(size_t)c * 4096], tw[idx]);
    idx += ck; if (idx >= 20) idx -= 20;
  }
  out[i] = acc;
}

__global__ void k_fwd_b(const float2* __restrict__ in, const float2* __restrict__ T,
                        float2* __restrict__ out, int n) {
  __shared__ float2 tw[4];
  if (threadIdx.x < 4) tw[threadIdx.x] = T[68 + threadIdx.x];
  __syncthreads();
  int i = blockIdx.x * 256 + threadIdx.x;
  if (i >= n) return;
  int mode = i & 4095, r = i >> 12, ck = r % 20, bk = r / 20;
  const float2* p = in + (size_t)ck * 4096 + mode;
  float2 acc = make_float2(0.f, 0.f);
#pragma unroll
  for (int b = 0; b < 4; b++) cfma(acc, p[(size_t)b * 81920], tw[(b * bk) & 3]);
  out[i] = acc;
}

__global__ void k_smul(const float2* __restrict__ in,
                       const float* __restrict__ sw1, const float* __restrict__ sw2,
                       const float* __restrict__ sw3, const float* __restrict__ sw4,
                       float2* __restrict__ out, int n) {
  int i = blockIdx.x * 256 + threadIdx.x;
  if (i >= n) return;
  int mode = i & 4095, r = i >> 12, o = r % 20, bk = r / 20;
  int ti = mode >> 9, xi = (mode >> 5) & 15, yk = (mode >> 2) & 7, zk = mode & 3;
  const float* w = (ti < 4) ? ((xi < 8) ? sw1 : sw3) : ((xi < 8) ? sw2 : sw4);
  int tl = ti & 3, xl = xi & 7;
  const float2* wp = (const float2*)w;
  const float2* ip = in + (size_t)bk * 81920 + mode;
  size_t wsub = (size_t)o * 1024 + (size_t)tl * 256 + (size_t)xl * 32 + yk * 4 + zk;
  float2 acc = make_float2(0.f, 0.f);
  for (int ci = 0; ci < 20; ci++) cfma(acc, ip[(size_t)ci * 4096], wp[(size_t)ci * 20480 + wsub]);
  out[i] = acc;
}

// ---------------- spectral inverse ----------------
__global__ void k_inv_t(const float2* __restrict__ in, const float2* __restrict__ T,
                        float2* __restrict__ out, int n) {
  __shared__ float2 tw[16];
  if (threadIdx.x < 16) tw[threadIdx.x] = T[32 + threadIdx.x];
  __syncthreads();
  int i = blockIdx.x * 256 + threadIdx.x;
  if (i >= n) return;
  int zk = i & 3, yk = (i >> 2) & 7, xi = (i >> 5) & 15, tp = (i >> 9) & 15, bc = i >> 13;
  const float2* p = in + (size_t)bc * 4096 + xi * 32 + yk * 4 + zk;
  float2 acc = make_float2(0.f, 0.f);
#pragma unroll
  for (int ti = 0; ti < 8; ti++) {
    int tk = (ti < 4) ? ti : ti + 8;
    cfmac(acc, p[ti * 512], tw[(tk * tp) & 15]);
  }
  out[i] = acc;
}

__global__ void k_inv_x(const float2* __restrict__ in, const float2* __restrict__ T,
                        float2* __restrict__ out, int n) {
  __shared__ float2 tw[32];
  if (threadIdx.x < 32) tw[threadIdx.x] = T[threadIdx.x];
  __syncthreads();
  int i = blockIdx.x * 256 + threadIdx.x;
  if (i >= n) return;
  int zk = i & 3, yk = (i >> 2) & 7, xp = (i >> 5) & 31, tp = (i >> 10) & 15, bc = i >> 14;
  const float2* p = in + (size_t)bc * 8192 + tp * 512 + yk * 4 + zk;
  float2 acc = make_float2(0.f, 0.f);
#pragma unroll
  for (int xi = 0; xi < 16; xi++) {
    int xk = (xi < 8) ? xi : xi + 16;
    cfmac(acc, p[xi * 32], tw[(xk * xp) & 31]);
  }
  out[i] = acc;
}

// fused inverse-y + c2r-z: thread per (bc,tp,xp,yp), emits full 16-z real row.
__global__ void k_inv_yz(const float2* __restrict__ in, const float2* __restrict__ T,
                         float* __restrict__ out, int n) {
  __shared__ float2 tw[48];  // 0..31: N32, 32..47: N16
  if (threadIdx.x < 48) tw[threadIdx.x] = T[threadIdx.x];
  __syncthreads();
  int i = blockIdx.x * 256 + threadIdx.x;
  if (i >= n) return;
  int yp = i & 31;
  const float2* p = in + (size_t)(i >> 5) * 32;  // [bc][tp][xp] slab: [yk8][zk4]
  float2 Ay[4];
#pragma unroll
  for (int zk = 0; zk < 4; zk++) Ay[zk] = make_float2(0.f, 0.f);
#pragma unroll
  for (int yk = 0; yk < 8; yk++) {
    float2 w = tw[(yk * yp) & 31];
#pragma unroll
    for (int zk = 0; zk < 4; zk++) cfmac(Ay[zk], p[yk * 4 + zk], w);
  }
  float res[16];
#pragma unroll
  for (int zp = 0; zp < 16; zp++) {
    float v = Ay[0].x;
#pragma unroll
    for (int zk = 1; zk < 4; zk++) {
      float2 t = tw[32 + ((zk * zp) & 15)];
      v += 2.f * (Ay[zk].x * t.x + Ay[zk].y * t.y);
    }
    res[zp] = v * (1.f / 262144.f);
  }
  float4* o4 = (float4*)(out + (size_t)i * 16);
#pragma unroll
  for (int q = 0; q < 4; q++)
    o4[q] = make_float4(res[q * 4], res[q * 4 + 1], res[q * 4 + 2], res[q * 4 + 3]);
}

// ---------------- c1 conv (stride 2, 20->20) LDS-tiled, fp32-exact ----------------
// pack c1_w [o][ci][81] -> Wc1p[ci][tap][o] (contiguous per ci)
__global__ void k_pack_c1(const float* __restrict__ c1_w, float* __restrict__ Wc, int n) {
  int i = blockIdx.x * 256 + threadIdx.x;
  if (i >= n) return;
  int o = i % 20; int r = i / 20;
  int tap = r % 81; int ci = r / 81;
  Wc[i] = c1_w[((size_t)o * 20 + ci) * 81 + tap];
}

// Block = (b,to,xo): 4*8*16 = 512 blocks x 128 threads (zo8, yo16), one output each.
__global__ __launch_bounds__(128) void k_c1(
    const float* __restrict__ x, const float* __restrict__ Wc,
    float* __restrict__ out) {
  __shared__ __align__(16) float tileX[2][4608];  // [tt3][xx3][y32][z16]
  __shared__ __align__(16) float tileW[2][1620];
  int bid = blockIdx.x;
  int xo = bid & 15, to = (bid >> 4) & 7, b = bid >> 7;
  int tid = threadIdx.x;
  int zo = tid & 7, yo = tid >> 3;

  auto gld = [](const char* src, char* dst) {
    __builtin_amdgcn_global_load_lds(
        (const __attribute__((address_space(1))) void*)src,
        (__attribute__((address_space(3))) void*)dst, 16, 0, 0);
  };

  // zero-fill invalid (t,x) rows in BOTH buffers once
  for (int g = tid; g < 1152; g += 128) {
    int r = g >> 7, l = g & 127;
    int tt = r / 3, xx = r - tt * 3;
    int t = 2 * to - 1 + tt, xg = 2 * xo - 1 + xx;
    if (t < 0 || t > 15 || xg < 0 || xg > 31) {
      f32x4 z = {0.f, 0.f, 0.f, 0.f};
      *(f32x4*)&tileX[0][r * 512 + l * 4] = z;
      *(f32x4*)&tileX[1][r * 512 + l * 4] = z;
    }
  }

  auto stage = [&](int buf, int ci) {
    const float* base = x + (size_t)(b * 20 + ci) * 262144;
    for (int g = tid; g < 1152; g += 128) {
      int r = g >> 7, l = g & 127;
      int tt = r / 3, xx = r - tt * 3;
      int t = 2 * to - 1 + tt, xg = 2 * xo - 1 + xx;
      if (t >= 0 && t <= 15 && xg >= 0 && xg <= 31) {  // wave-uniform branch
        const char* src = (const char*)(base + (size_t)t * 16384 + (size_t)xg * 512) + l * 16;
        gld(src, (char*)&tileX[buf][r * 512] + l * 16);
      }
    }
    const char* wsrc = (const char*)(Wc + (size_t)ci * 1620);
    for (int g = tid; g < 405; g += 128)
      gld(wsrc + g * 16, (char*)&tileW[buf][0] + g * 16);
  };

  float acc[20];
#pragma unroll
  for (int o = 0; o < 20; o++) acc[o] = 0.f;

  stage(0, 0);
  asm volatile("s_waitcnt vmcnt(0)" ::: "memory");
  __syncthreads();

#pragma unroll 1
  for (int ci = 0; ci < 20; ci++) {
    int cur = ci & 1;
    if (ci + 1 < 20) stage(cur ^ 1, ci + 1);
    const float* tb = tileX[cur];
    const float* wcc = tileW[cur];
#pragma unroll
    for (int kt = 0; kt < 3; kt++)
#pragma unroll
      for (int kx = 0; kx < 3; kx++) {
        int rbase = (kt * 3 + kx) * 512;
#pragma unroll
        for (int ky = 0; ky < 3; ky++) {
          int yc = 2 * yo + ky - 1;
          bool yok = yc >= 0;
          int ycc = yok ? yc : 0;
          int ebase = rbase + ycc * 16;
          float2 vz = *(const float2*)&tb[ebase + 2 * zo];
          int zlo = (zo > 0) ? (2 * zo - 1) : 0;
          float vl = tb[ebase + zlo];
          float v0 = (yok && zo > 0) ? vl : 0.f;
          float v1 = yok ? vz.x : 0.f;
          float v2 = yok ? vz.y : 0.f;
          int tap0 = ((kt * 3 + kx) * 3 + ky) * 3;
          float w[60];
          const f32x4* wv = (const f32x4*)(wcc + tap0 * 20);
#pragma unroll
          for (int q = 0; q < 15; q++) *(f32x4*)&w[q * 4] = wv[q];
#pragma unroll
          for (int o = 0; o < 20; o++) {
            acc[o] += v0 * w[o];
            acc[o] += v1 * w[20 + o];
            acc[o] += v2 * w[40 + o];
          }
        }
      }
    asm volatile("s_waitcnt vmcnt(0)" ::: "memory");
    __syncthreads();
  }

  size_t obase = (size_t)b * 20 * 16384 + (((size_t)to * 16 + xo) * 16 + yo) * 8 + zo;
#pragma unroll
  for (int o = 0; o < 20; o++) out[obase + (size_t)o * 16384] = acc[o];
}

// ---------------- specialized encoder convs (weights-in-LDS, fp32-exact) ----------------
// c2: 3^4 stride-2 conv, in [b][ci20][8][16][16][8] -> out [b][o20][4][8][8][4].
// Block = (to,o,b) (grid 320), 256 thr = (xo8,yo8,zo4); per-o weight slice (1620 f) in LDS.
__global__ __launch_bounds__(256) void k_c2(
    const float* __restrict__ in, const float* __restrict__ W,
    float* __restrict__ out) {
  __shared__ __align__(16) float wsl[1620];
  int bid = blockIdx.x;
  int to = bid & 3, o = (bid >> 2) % 20, b = bid / 80;
  int tid = threadIdx.x;
  int zo = tid & 3, yo = (tid >> 2) & 7, xo = tid >> 5;
  const char* wsrc = (const char*)(W + (size_t)o * 1620);
  for (int g = tid; g < 405; g += 256)
    __builtin_amdgcn_global_load_lds(
        (const __attribute__((address_space(1))) void*)(wsrc + g * 16),
        (__attribute__((address_space(3))) void*)((char*)&wsl[0] + g * 16), 16, 0, 0);
  asm volatile("s_waitcnt vmcnt(0)" ::: "memory");
  __syncthreads();
  float acc = 0.f;
#pragma unroll 2
  for (int ci = 0; ci < 20; ci++) {
    const float* base = in + (size_t)(b * 20 + ci) * 16384;
    const float* wc = wsl + ci * 81;
#pragma unroll
    for (int kt = 0; kt < 3; kt++) {
      int t = 2 * to + kt - 1;
      if (t < 0) continue;  // wave-uniform (to uniform per block)
#pragma unroll
      for (int kx = 0; kx < 3; kx++) {
        int xx = 2 * xo + kx - 1;
        bool xok = xx >= 0; int xc = xok ? xx : 0;
#pragma unroll
        for (int ky = 0; ky < 3; ky++) {
          int yy = 2 * yo + ky - 1;
          bool yok = yy >= 0; int yc = yok ? yy : 0;
          const float* p = base + t * 2048 + xc * 128 + yc * 8;
          float2 vz = *(const float2*)(p + 2 * zo);
          float vl = p[(zo > 0) ? (2 * zo - 1) : 0];
          bool m = xok && yok;
          float v0 = (m && zo > 0) ? vl : 0.f;
          float v1 = m ? vz.x : 0.f;
          float v2 = m ? vz.y : 0.f;
          const float* wp = wc + ((kt * 3 + kx) * 3 + ky) * 3;
          acc += v0 * wp[0];
          acc += v1 * wp[1];
          acc += v2 * wp[2];
        }
      }
    }
  }
  size_t oidx = ((((size_t)(b * 20 + o) * 4 + to) * 8 + xo) * 8 + yo) * 4 + zo;
  out[oidx] = acc;
}

// c21: 3^4 stride-1 conv, in/out [b][20][4][8][8][4]. Block = (to,o,b) grid 320.
__global__ __launch_bounds__(256) void k_c21(
    const float* __restrict__ in, const float* __restrict__ W,
    float* __restrict__ out) {
  __shared__ __align__(16) float wsl[1620];
  int bid = blockIdx.x;
  int to = bid & 3, o = (bid >> 2) % 20, b = bid / 80;
  int tid = threadIdx.x;
  int zo = tid & 3, yo = (tid >> 2) & 7, xo = tid >> 5;
  const char* wsrc = (const char*)(W + (size_t)o * 1620);
  for (int g = tid; g < 405; g += 256)
    __builtin_amdgcn_global_load_lds(
        (const __attribute__((address_space(1))) void*)(wsrc + g * 16),
        (__attribute__((address_space(3))) void*)((char*)&wsl[0] + g * 16), 16, 0, 0);
  asm volatile("s_waitcnt vmcnt(0)" ::: "memory");
  __syncthreads();
  float acc = 0.f;
#pragma unroll 2
  for (int ci = 0; ci < 20; ci++) {
    const float* base = in + (size_t)(b * 20 + ci) * 1024;
    const float* wc = wsl + ci * 81;
#pragma unroll
    for (int kt = 0; kt < 3; kt++) {
      int t = to + kt - 1;
      if (t < 0 || t > 3) continue;  // wave-uniform
#pragma unroll
      for (int kx = 0; kx < 3; kx++) {
        int xx = xo + kx - 1;
        bool xok = (xx >= 0) && (xx < 8); int xc = xok ? xx : 0;
#pragma unroll
        for (int ky = 0; ky < 3; ky++) {
          int yy = yo + ky - 1;
          bool yok = (yy >= 0) && (yy < 8); int yc = yok ? yy : 0;
          const float* p = base + t * 256 + xc * 32 + yc * 4;
          float vl = p[(zo > 0) ? (zo - 1) : 0];
          float vm = p[zo];
          float vh = p[zo + 1];  // overread by <=1 elem at zo==3: masked, in-arena
          bool m = xok && yok;
          float v0 = (m && zo > 0) ? vl : 0.f;
          float v1 = m ? vm : 0.f;
          float v2 = (m && zo < 3) ? vh : 0.f;
          const float* wp = wc + ((kt * 3 + kx) * 3 + ky) * 3;
          acc += v0 * wp[0];
          acc += v1 * wp[1];
          acc += v2 * wp[2];
        }
      }
    }
  }
  size_t oidx = ((((size_t)(b * 20 + o) * 4 + to) * 8 + xo) * 8 + yo) * 4 + zo;
  out[oidx] = acc;
}

// c3: 3^4 stride-2 conv, in [b][ci20][4][8][8][4] -> out [b][o20][2][4][4][2].
// Block = (o,b) grid 80, 64 thr = (to2,xo4,yo4,zo2).
__global__ __launch_bounds__(64) void k_c3(
    const float* __restrict__ in, const float* __restrict__ W,
    float* __restrict__ out) {
  __shared__ __align__(16) float wsl[1620];
  int bid = blockIdx.x;
  int o = bid % 20, b = bid / 20;
  int tid = threadIdx.x;
  int zo = tid & 1, yo = (tid >> 1) & 3, xo = (tid >> 3) & 3, to = tid >> 5;
  const char* wsrc = (const char*)(W + (size_t)o * 1620);
  for (int g = tid; g < 405; g += 64)
    __builtin_amdgcn_global_load_lds(
        (const __attribute__((address_space(1))) void*)(wsrc + g * 16),
        (__attribute__((address_space(3))) void*)((char*)&wsl[0] + g * 16), 16, 0, 0);
  asm volatile("s_waitcnt vmcnt(0)" ::: "memory");
  __syncthreads();
  float acc = 0.f;
#pragma unroll 2
  for (int ci = 0; ci < 20; ci++) {
    const float* base = in + (size_t)(b * 20 + ci) * 1024;
    const float* wc = wsl + ci * 81;
#pragma unroll
    for (int kt = 0; kt < 3; kt++) {
      int t = 2 * to + kt - 1;
      bool tok = t >= 0; int tc = tok ? t : 0;
#pragma unroll
      for (int kx = 0; kx < 3; kx++) {
        int xx = 2 * xo + kx - 1;
        bool xok = xx >= 0; int xc = xok ? xx : 0;
#pragma unroll
        for (int ky = 0; ky < 3; ky++) {
          int yy = 2 * yo + ky - 1;
          bool yok = yy >= 0; int yc = yok ? yy : 0;
          const float* p = base + tc * 256 + xc * 32 + yc * 4;
          float2 vz = *(const float2*)(p + 2 * zo);
          float vl = p[(zo > 0) ? (2 * zo - 1) : 0];
          bool m = tok && xok && yok;
          float v0 = (m && zo > 0) ? vl : 0.f;
          float v1 = m ? vz.x : 0.f;
          float v2 = m ? vz.y : 0.f;
          const float* wp = wc + ((kt * 3 + kx) * 3 + ky) * 3;
          acc += v0 * wp[0];
          acc += v1 * wp[1];
          acc += v2 * wp[2];
        }
      }
    }
  }
  size_t oidx = ((((size_t)(b * 20 + o) * 2 + to) * 4 + xo) * 4 + yo) * 2 + zo;
  out[oidx] = acc;
}

// c31: 3^4 stride-1 conv, in/out [b][20][2][4][4][2]. Block = (o,b) grid 80, 64 thr.
__global__ __launch_bounds__(64) void k_c31(
    const float* __restrict__ in, const float* __restrict__ W,
    float* __restrict__ out) {
  __shared__ __align__(16) float wsl[1620];
  int bid = blockIdx.x;
  int o = bid % 20, b = bid / 20;
  int tid = threadIdx.x;
  int zo = tid & 1, yo = (tid >> 1) & 3, xo = (tid >> 3) & 3, to = tid >> 5;
  const char* wsrc = (const char*)(W + (size_t)o * 1620);
  for (int g = tid; g < 405; g += 64)
    __builtin_amdgcn_global_load_lds(
        (const __attribute__((address_space(1))) void*)(wsrc + g * 16),
        (__attribute__((address_space(3))) void*)((char*)&wsl[0] + g * 16), 16, 0, 0);
  asm volatile("s_waitcnt vmcnt(0)" ::: "memory");
  __syncthreads();
  float acc = 0.f;
#pragma unroll 2
  for (int ci = 0; ci < 20; ci++) {
    const float* base = in + (size_t)(b * 20 + ci) * 64;
    const float* wc = wsl + ci * 81;
#pragma unroll
    for (int kt = 0; kt < 3; kt++) {
      int t = to + kt - 1;
      bool tok = (t >= 0) && (t < 2); int tc = tok ? t : 0;
#pragma unroll
      for (int kx = 0; kx < 3; kx++) {
        int xx = xo + kx - 1;
        bool xok = (xx >= 0) && (xx < 4); int xc = xok ? xx : 0;
#pragma unroll
        for (int ky = 0; ky < 3; ky++) {
          int yy = yo + ky - 1;
          bool yok = (yy >= 0) && (yy < 4); int yc = yok ? yy : 0;
          const float* p = base + tc * 32 + xc * 8 + yc * 2;
          float vl = p[(zo > 0) ? (zo - 1) : 0];
          float vm = p[zo];
          float vh = p[zo + 1];  // overread <=1 elem at zo==1: masked, in-arena
          bool m = tok && xok && yok;
          float v0 = (m && zo > 0) ? vl : 0.f;
          float v1 = m ? vm : 0.f;
          float v2 = (m && zo < 1) ? vh : 0.f;
          const float* wp = wc + ((kt * 3 + kx) * 3 + ky) * 3;
          acc += v0 * wp[0];
          acc += v1 * wp[1];
          acc += v2 * wp[2];
        }
      }
    }
  }
  size_t oidx = ((((size_t)(b * 20 + o) * 2 + to) * 4 + xo) * 4 + yo) * 2 + zo;
  out[oidx] = acc;
}

// ---------------- BN ----------------
__global__ void k_bn_stats(const float* __restrict__ d, int S, float* __restrict__ stats) {
  int c = blockIdx.x;
  int tid = threadIdx.x;
  float s = 0.f, s2 = 0.f;
  for (int b = 0; b < 4; b++) {
    const float* p = d + ((size_t)b * 20 + c) * S;
    for (int i = tid; i < S; i += 256) { float v = p[i]; s += v; s2 += v * v; }
  }
  __shared__ float ls[256], lq[256];
  ls[tid] = s; lq[tid] = s2;
  __syncthreads();
  for (int off = 128; off > 0; off >>= 1) {
    if (tid < off) { ls[tid] += ls[tid + off]; lq[tid] += lq[tid + off]; }
    __syncthreads();
  }
  if (tid == 0) {
    float cnt = 4.f * (float)S;
    float mean = ls[0] / cnt;
    float var = lq[0] / cnt - mean * mean;
    stats[2 * c] = mean;
    stats[2 * c + 1] = rsqrtf(var + 1e-5f);
  }
}

__global__ void k_bn_apply(float* __restrict__ d, int S, const float* __restrict__ stats,
                           const float* __restrict__ g, const float* __restrict__ bb, int n) {
  int idx = blockIdx.x * 256 + threadIdx.x;
  if (idx >= n) return;
  int c = (idx / S) % 20;
  float v = d[idx];
  v = (v - stats[2 * c]) * stats[2 * c + 1] * g[c] + bb[c];
  d[idx] = (v >= 0.f) ? v : 0.1f * v;
}

// channels-last bf16 fill of CLd0 ci 0..19 from post-BN oc1: thread per (b,s),
// 20 strided coalesced reads -> one packed 40B vector store (5 x uint2).
__global__ void k_cl20(const float* __restrict__ oc1, short* __restrict__ CL, int n) {
  int i = blockIdx.x * 256 + threadIdx.x;
  if (i >= n) return;
  int s = i & 16383, b = i >> 14;
  const float* src = oc1 + (size_t)b * 20 * 16384 + s;
  unsigned h[20];
#pragma unroll
  for (int c = 0; c < 20; c++) h[c] = (unsigned)(unsigned short)f2bf(src[(size_t)c * 16384]);
  uint2* dst = (uint2*)(CL + (size_t)i * 40);
#pragma unroll
  for (int q = 0; q < 5; q++) dst[q] = make_uint2(h[4 * q] | (h[4 * q + 1] << 16),
                                                  h[4 * q + 2] | (h[4 * q + 3] << 16));
}

// ---------------- deconv (ConvTranspose4d k=4 s=2 p=1), bias+lrelu fused ----------------
__device__ __forceinline__ int dcands(int p, int n_in, int* q, int* k) {
  int cnt = 0;
  int q0 = (p + 1) >> 1, k0 = p + 1 - 2 * q0;
  if (q0 >= 0 && q0 < n_in) { q[cnt] = q0; k[cnt] = k0; cnt++; }
  int q1 = q0 - 1, k1 = k0 + 2;
  if (q1 >= 0 && q1 < n_in) { q[cnt] = q1; k[cnt] = k1; cnt++; }
  return cnt;
}

// d2 deconv specialized: in oc3 [b][ci20][2][4][4][2] -> out od2 [b][o20][4][8][8][4],
// bias+lrelu. Block = (to,o,b) grid 320, 256 thr = (xo8,yo8,zo4).
// Per-o weight slice (20 ci x 256 taps = 20KB) staged once into LDS.
__global__ __launch_bounds__(256) void k_d2(
    const float* __restrict__ in, const float* __restrict__ W,
    const float* __restrict__ bias, float* __restrict__ out) {
  __shared__ __align__(16) float wsl[5120];  // [ci20][tap256]
  int bid = blockIdx.x;
  int to = bid & 3, o = (bid >> 2) % 20, b = bid / 80;
  int tid = threadIdx.x;
  int zo = tid & 3, yo = (tid >> 2) & 7, xo = tid >> 5;
  for (int g = tid; g < 1280; g += 256) {
    int ci = g >> 6, off = g & 63;
    const char* src = (const char*)(W + (size_t)ci * 5120 + (size_t)o * 256 + off * 4);
    __builtin_amdgcn_global_load_lds(
        (const __attribute__((address_space(1))) void*)src,
        (__attribute__((address_space(3))) void*)((char*)&wsl[ci * 256] + off * 16), 16, 0, 0);
  }
  asm volatile("s_waitcnt vmcnt(0)" ::: "memory");
  __syncthreads();
  int qt[2], kt[2], qx[2], kx[2], qy[2], ky[2], qz[2], kz[2];
  int nt = dcands(to, 2, qt, kt), nx = dcands(xo, 4, qx, kx);
  int ny = dcands(yo, 4, qy, ky), nz = dcands(zo, 2, qz, kz);
  float acc = 0.f;
#pragma unroll 2
  for (int ci = 0; ci < 20; ci++) {
    const float* base = in + (size_t)(b * 20 + ci) * 64;
    const float* wc = wsl + ci * 256;
    for (int it = 0; it < nt; it++)
      for (int ix = 0; ix < nx; ix++)
        for (int iy = 0; iy < ny; iy++)
          for (int iz = 0; iz < nz; iz++) {
            float v = base[(((size_t)qt[it] * 4 + qx[ix]) * 4 + qy[iy]) * 2 + qz[iz]];
            int tap = ((kt[it] * 4 + kx[ix]) * 4 + ky[iy]) * 4 + kz[iz];
            acc += v * wc[tap];
          }
  }
  float v2 = acc + bias[o];
  size_t oidx = ((((size_t)(b * 20 + o) * 4 + to) * 8 + xo) * 8 + yo) * 4 + zo;
  out[oidx] = (v2 >= 0.f) ? v2 : 0.1f * v2;
}

// d1 deconv: in 4x8x8x4 (oc2|od2, Ci=40) -> out 8x16x16x8 written bf16 CL ci 20..39.
// Per-ci weight slice (20KB contiguous) double-buffered in LDS: stage ci+1 || compute ci.
__global__ __launch_bounds__(256) void k_deconv_d1_cl(
    const float* __restrict__ in1, const float* __restrict__ in2,
    const float* __restrict__ W, const float* __restrict__ bias,
    short* __restrict__ CL, int n) {
  __shared__ __align__(16) float tileW[2][5120];  // [o20][tap256] per ci
  int idx = blockIdx.x * 256 + threadIdx.x;
  int tid = threadIdx.x;
  int zo = idx & 7; int r = idx >> 3;
  int yo = r & 15; r >>= 4;
  int xo = r & 15; r >>= 4;
  int to = r & 7; int b = r >> 3;
  int qt[2], kt[2], qx[2], kx[2], qy[2], ky[2], qz[2], kz[2];
  int nt = dcands(to, 4, qt, kt), nx = dcands(xo, 8, qx, kx);
  int ny = dcands(yo, 8, qy, ky), nz = dcands(zo, 4, qz, kz);
  float acc[20];
#pragma unroll
  for (int o = 0; o < 20; o++) acc[o] = 0.f;
  const size_t in_sp = 4 * 8 * 8 * 4;

  auto stage = [&](int buf, int ci) {
    const char* wsrc = (const char*)(W + (size_t)ci * 5120);
    for (int g = tid; g < 1280; g += 256)
      __builtin_amdgcn_global_load_lds(
          (const __attribute__((address_space(1))) void*)(wsrc + g * 16),
          (__attribute__((address_space(3))) void*)((char*)&tileW[buf][0] + g * 16), 16, 0, 0);
  };

  stage(0, 0);
  asm volatile("s_waitcnt vmcnt(0)" ::: "memory");
  __syncthreads();

#pragma unroll 1
  for (int ci = 0; ci < 40; ci++) {
    int cur = ci & 1;
    if (ci + 1 < 40) stage(cur ^ 1, ci + 1);
    const float* base = (ci < 20) ? in1 + ((size_t)b * 20 + ci) * in_sp
                                  : in2 + ((size_t)b * 20 + (ci - 20)) * in_sp;
    const float* wc = tileW[cur];
    for (int it = 0; it < nt; it++)
      for (int ix = 0; ix < nx; ix++)
        for (int iy = 0; iy < ny; iy++)
          for (int iz = 0; iz < nz; iz++) {
            float v = base[(((size_t)qt[it] * 8 + qx[ix]) * 8 + qy[iy]) * 4 + qz[iz]];
            int tap = ((kt[it] * 4 + kx[ix]) * 4 + ky[iy]) * 4 + kz[iz];
#pragma unroll
            for (int o = 0; o < 20; o++) acc[o] += v * wc[o * 256 + tap];
          }
    asm volatile("s_waitcnt vmcnt(0)" ::: "memory");
    __syncthreads();
  }
  size_t pos = (((size_t)b * 8 + to) * 16 + xo) * 16 * 8 + (size_t)yo * 8 + zo;
  unsigned h[20];
#pragma unroll
  for (int o = 0; o < 20; o++) {
    float v2 = acc[o] + bias[o];
    v2 = (v2 >= 0.f) ? v2 : 0.1f * v2;
    h[o] = (unsigned)(unsigned short)f2bf(v2);
  }
  uint2* dst = (uint2*)(CL + pos * 40 + 20);
#pragma unroll
  for (int q = 0; q < 5; q++) dst[q] = make_uint2(h[4 * q] | (h[4 * q + 1] << 16),
                                                  h[4 * q + 2] | (h[4 * q + 3] << 16));
}

// fill Xcl ci 0..19 from x (packed 40B vector stores)
__global__ void k_xcl_x(const float* __restrict__ x, short* __restrict__ Xcl, int n) {
  int i = blockIdx.x * 256 + threadIdx.x;
  if (i >= n) return;
  int s = i & 262143, b = i >> 18;
  const float* src = x + (size_t)b * 20 * 262144 + s;
  unsigned h[20];
#pragma unroll
  for (int c = 0; c < 20; c++) h[c] = (unsigned)(unsigned short)f2bf(src[(size_t)c * 262144]);
  uint2* dst = (uint2*)(Xcl + (size_t)i * 40);
#pragma unroll
  for (int q = 0; q < 5; q++) dst[q] = make_uint2(h[4 * q] | (h[4 * q + 1] << 16),
                                                  h[4 * q + 2] | (h[4 * q + 3] << 16));
}

// pack out_w [20][40][81] + w_pw [20][20] -> Wp[tap(82)][mt(2)][m(16)][k(64)] bf16,
// bank-swizzled for LDS staging: short index i -> i ^ ((m&7)<<3)  (byte ^ ((m&7)<<4)).
// tap 81 = pointwise (x2) weights.
__global__ void k_pack_w(const float* __restrict__ out_w, const float* __restrict__ w_pw,
                         short* __restrict__ Wp, short* __restrict__ zp, int n) {
  int i = blockIdx.x * 256 + threadIdx.x;
  if (i >= n) return;
  int k = i & 63, m = (i >> 6) & 15, mt = (i >> 10) & 1, tap = i >> 11;
  int o = mt * 16 + m;
  float v = 0.f;
  if (o < 20 && k < 40) {
    if (tap < 81) v = out_w[((size_t)o * 40 + k) * 81 + tap];
    else if (k < 20) v = w_pw[o * 20 + k];
  }
  Wp[i ^ ((m & 7) << 3)] = f2bf(v);
  if (i < 64) zp[i] = 0;
}

// pack d0_w [40][20][256] -> Wd parity-class-major:
// [h(32)=cls*2+it][sub(8)=ix*4+iz*2+iy][mt(2)][m(16)][k(64)] bf16,
// bank-swizzled: element index i -> i ^ ((m&7)<<3)  (byte ^ ((row&7)<<4)).
__global__ void k_pack_wd(const float* __restrict__ d0_w, short* __restrict__ Wd, int n) {
  int i = blockIdx.x * 256 + threadIdx.x;
  if (i >= n) return;
  int k = i & 63, m = (i >> 6) & 15, mt = (i >> 10) & 1, sub = (i >> 11) & 7, h = i >> 14;
  int it = h & 1, cls = h >> 1;
  int ez = cls & 1, ey = (cls >> 1) & 1, ex = (cls >> 2) & 1, et = (cls >> 3) & 1;
  int iy = sub & 1, iz = (sub >> 1) & 1, ix = (sub >> 2) & 1;
  int kt = et ? (2 * it) : (1 + 2 * it);
  int kx = ex ? (2 * ix) : (1 + 2 * ix);
  int ky = ey ? (2 * iy) : (1 + 2 * iy);
  int kz = ez ? (2 * iz) : (1 + 2 * iz);
  int tap = ((kt * 4 + kx) * 4 + ky) * 4 + kz;
  int o = mt * 16 + m;
  float v = (o < 20 && k < 40) ? d0_w[((size_t)k * 20 + o) * 256 + tap] : 0.f;
  Wd[i ^ ((m & 7) << 3)] = f2bf(v);
}

// ---------------- d0 deconv via MFMA (parity-class, LDS-staged) ----------------
__global__ __launch_bounds__(512) void k_d0_mfma(
    const short* __restrict__ CLd0, const short* __restrict__ Wd,
    const float* __restrict__ bias, short* __restrict__ Xcl) {
  __shared__ __align__(16) char lds[157696];  // 9*10240 B-planes + 2*32768 A dbuf
  char* lds_a = lds + 92160;
  int bid = blockIdx.x;
  int ux = bid & 15, ut = (bid >> 4) & 7, b = bid >> 7;
  int tid = threadIdx.x;
  int uz = tid >> 6;
  int lane = tid & 63, ln15 = lane & 15, kg = lane >> 4;  // ln15 = uy

  const char* xb = (const char*)CLd0;
  const char* wb = (const char*)Wd;

  auto gld = [](const char* src, char* dst) {
    __builtin_amdgcn_global_load_lds(
        (const __attribute__((address_space(1))) void*)src,
        (__attribute__((address_space(3))) void*)dst, 16, 0, 0);
  };

  // ---- prologue: stage B planes (swizzle baked into per-lane global src) ----
#pragma unroll
  for (int pt = 0; pt < 3; pt++) {
    int qt = ut - 1 + pt;
    if (qt < 0 || qt > 7) continue;
#pragma unroll
    for (int px = 0; px < 3; px++) {
      int qx = ux - 1 + px;
      if (qx < 0 || qx > 15) continue;
      const char* src = xb + (size_t)((b * 8 + qt) * 16 + qx) * 10240;
      char* dst = lds + (pt * 3 + px) * 10240;
      for (int g = tid; g < 640; g += 512) {
        int key = ((g / 40) & 7) << 4;
        gld(src + ((g * 16) ^ key), dst + g * 16);
      }
    }
  }
  // stage A half-block h=0 (pack is pre-swizzled -> linear copy)
  for (int g = tid; g < 2048; g += 512) gld(wb + g * 16, lds_a + g * 16);
  asm volatile("s_waitcnt vmcnt(0)" ::: "memory");
  __syncthreads();

  bf16x8 zv = {0, 0, 0, 0, 0, 0, 0, 0};
  int aswz = ((ln15 * 128 + kg * 16) ^ ((ln15 & 7) << 4));

#pragma unroll 1
  for (int cls = 0; cls < 16; cls++) {
    int ez = cls & 1, ey = (cls >> 1) & 1, ex = (cls >> 2) & 1, et = (cls >> 3) & 1;
    f32x4 acc0, acc1;
#pragma unroll
    for (int j = 0; j < 4; j++) { acc0[j] = 0.f; acc1[j] = 0.f; }
#pragma unroll
    for (int it = 0; it < 2; it++) {
      int h = cls * 2 + it;
      // stage next A half-block into the other buffer
      if (h + 1 < 32) {
        const char* asrc = wb + (size_t)(h + 1) * 32768;
        char* adst = lds_a + (it ^ 1) * 32768;
        for (int g = tid; g < 2048; g += 512) gld(asrc + g * 16, adst + g * 16);
      }
      const char* ab = lds_a + it * 32768;
      int kt_q = ut + (et ? (1 - it) : (-it));
      if (kt_q >= 0 && kt_q <= 7) {
        int pt = kt_q - ut + 1;
#pragma unroll
        for (int ix = 0; ix < 2; ix++) {
          int qx = ux + (ex ? (1 - ix) : (-ix));
          if (qx < 0 || qx > 15) continue;
          int px = qx - ux + 1;
          const char* pbase = lds + (pt * 3 + px) * 10240;
#pragma unroll
          for (int iz = 0; iz < 2; iz++) {
            int qz = uz + (ez ? (1 - iz) : (-iz));
            if (qz < 0 || qz > 7) continue;
#pragma unroll
            for (int iy = 0; iy < 2; iy++) {
              int qy = ln15 + (ey ? (1 - iy) : (-iy));
              bool yok = (qy >= 0) && (qy < 16);
              int qyc = yok ? qy : 0;
              int bkey = (qyc & 7) << 4;
              const char* abase = ab + (ix * 4 + iz * 2 + iy) * 4096;
#pragma unroll
              for (int ch = 0; ch < 2; ch++) {
                int co = ch ? 64 : kg * 16;  // ch=1: broadcast ci 32..39 (k>=40 wts are 0)
                int boff = (qyc * 640 + qz * 80 + co) ^ bkey;
                bf16x8 bvv = *(const bf16x8*)(pbase + boff);
                bf16x8 bv = yok ? bvv : zv;
                int aoff = (ch ? (aswz ^ 64) : aswz);
                bf16x8 a0 = *(const bf16x8*)(abase + aoff);
                bf16x8 a1 = *(const bf16x8*)(abase + 2048 + aoff);
                acc0 = __builtin_amdgcn_mfma_f32_16x16x32_bf16(a0, bv, acc0, 0, 0, 0);
                acc1 = __builtin_amdgcn_mfma_f32_16x16x32_bf16(a1, bv, acc1, 0, 0, 0);
              }
            }
          }
        }
      }
      asm volatile("s_waitcnt vmcnt(0)" ::: "memory");
      __syncthreads();
    }
    int to = 2 * ut + et, xo = 2 * ux + ex, zo = 2 * uz + ez, yo = 2 * ln15 + ey;
    long opos = ((((long)b * 16 + to) * 32 + xo) * 32 + yo) * 16 + zo;
    short* dst = Xcl + opos * 40 + 20;
    {
      unsigned hh[4];
#pragma unroll
      for (int r = 0; r < 4; r++) {
        float v = acc0[r] + bias[kg * 4 + r];
        v = (v >= 0.f) ? v : 0.1f * v;
        hh[r] = (unsigned)(unsigned short)f2bf(v);
      }
      uint2 u;
      u.x = hh[0] | (hh[1] << 16);
      u.y = hh[2] | (hh[3] << 16);
      *(uint2*)(dst + kg * 4) = u;
    }
    if (kg == 0) {
      unsigned hh[4];
#pragma unroll
      for (int r = 0; r < 4; r++) {
        float v = acc1[r] + bias[16 + r];
        v = (v >= 0.f) ? v : 0.1f * v;
        hh[r] = (unsigned)(unsigned short)f2bf(v);
      }
      uint2 u;
      u.x = hh[0] | (hh[1] << 16);
      u.y = hh[2] | (hh[3] << 16);
      *(uint2*)(dst + 16) = u;
    }
  }
}

// ---------------- final conv: fully LDS-staged bf16 MFMA implicit GEMM ----------------
__global__ __launch_bounds__(512) void k_fconv_mfma(
    const short* __restrict__ Xcl, const short* __restrict__ Wp,
    const float* __restrict__ bias, const float* __restrict__ bpw,
    float* __restrict__ io) {
  __shared__ __align__(16) char ldsB[2][40960];
  __shared__ __align__(16) char ldsW[2][36864];
  int bid = blockIdx.x;
  int xcd = bid & 7, idx = bid >> 3;
  int b = xcd >> 1, xh = xcd & 1;
  // t0-major within each XCD: working set 3 xi-slabs x 16 ti x 40KB ~ 1.9MB < 4MB L2
  int t0 = idx & 15, x0 = xh * 16 + ((idx >> 4) & 15);
  int tid = threadIdx.x;
  int lane = tid & 63;
  int ln15 = lane & 15, kg = lane >> 4;
  int ybase = (tid >> 6) * 4;

  // valid (kt,kx) slab list, 4 bits per entry (code = kt*4+kx; center = 5)
  unsigned long long codes = 0ull;
  int ns = 0;
  for (int kt = 0; kt < 3; kt++) {
    int ti = t0 + kt - 1;
    if (ti < 0 || ti > 15) continue;
    for (int kx = 0; kx < 3; kx++) {
      int xi = x0 + kx - 1;
      if (xi < 0 || xi > 31) continue;
      codes |= (unsigned long long)(kt * 4 + kx) << (4 * ns);
      ns++;
    }
  }

  const char* xb = (const char*)Xcl;
  const char* wb = (const char*)Wp;

  auto gld = [](const char* src, char* dst) {
    __builtin_amdgcn_global_load_lds(
        (const __attribute__((address_space(1))) void*)src,
        (__attribute__((address_space(3))) void*)dst, 16, 0, 0);
  };

  auto stage = [&](int buf, int code) {
    int kt = code >> 2, kx = code & 3;
    int ti = t0 + kt - 1, xi = x0 + kx - 1;
    const char* src = xb + (size_t)((b * 16 + ti) * 32 + xi) * 512 * 80;
    char* dstB = ldsB[buf];
#pragma unroll
    for (int s = 0; s < 5; s++) {
      int off = s * 8192 + tid * 16;
      gld(src + off, dstB + off);
    }
    // 9-tap contiguous weight run for this slab: taps (kt*3+kx)*9 .. +8
    const char* wsrc = wb + (size_t)(kt * 3 + kx) * 9 * 4096;
    char* dstW = ldsW[buf];
    for (int g = tid; g < 2304; g += 512) gld(wsrc + g * 16, dstW + g * 16);
  };

  f32x4 acc[2][4];
#pragma unroll
  for (int mt = 0; mt < 2; mt++)
#pragma unroll
    for (int nt = 0; nt < 4; nt++)
#pragma unroll
      for (int j = 0; j < 4; j++) acc[mt][nt][j] = 0.f;

  int awz0 = (ln15 * 128 + kg * 16) ^ ((ln15 & 7) << 4);
  int awz1 = (ln15 * 128 + 64 + kg * 16) ^ ((ln15 & 7) << 4);

  stage(0, (int)(codes & 15));
  asm volatile("s_waitcnt vmcnt(0)" ::: "memory");
  __syncthreads();

  int cur = 0;
#pragma unroll 1
  for (int i = 0; i < ns; i++) {
    const char* bufB = ldsB[cur];
    const char* bufW = ldsW[cur];
    if (i + 1 < ns) stage(cur ^ 1, (int)((codes >> (4 * (i + 1))) & 15));
    int code = (int)((codes >> (4 * i)) & 15);
    bf16x8 zv = {0, 0, 0, 0, 0, 0, 0, 0};
#pragma unroll
    for (int kz = 0; kz < 3; kz++) {
      int zi = ln15 + kz - 1;
      bool zok = (zi >= 0) && (zi < 16);
      int zc = zok ? zi : 0;
#pragma unroll
      for (int ch = 0; ch < 2; ch++) {
        int co = ch ? 64 : kg * 16;  // ch=1: broadcast ci 32..39 chunk to all kg
        bf16x8 bv[6];
#pragma unroll
        for (int j = 0; j < 6; j++) {
          int yi = ybase + j - 1;
          int yc = (yi < 0) ? 0 : ((yi > 31) ? 31 : yi);
          bf16x8 v = *(const bf16x8*)(bufB + (size_t)(yc * 16 + zc) * 80 + co);
          bool ok = zok && (yi >= 0) && (yi < 32);
          bv[j] = ok ? v : zv;
        }
        int awz = ch ? awz1 : awz0;
        bf16x8 av[3][2];
#pragma unroll
        for (int ky = 0; ky < 3; ky++) {
          const char* wt = bufW + (size_t)(ky * 3 + kz) * 4096;
          av[ky][0] = *(const bf16x8*)(wt + awz);
          av[ky][1] = *(const bf16x8*)(wt + 2048 + awz);
        }
#pragma unroll
        for (int ky = 0; ky < 3; ky++)
#pragma unroll
          for (int nt = 0; nt < 4; nt++) {
            acc[0][nt] = __builtin_amdgcn_mfma_f32_16x16x32_bf16(av[ky][0], bv[nt + ky], acc[0][nt], 0, 0, 0);
            acc[1][nt] = __builtin_amdgcn_mfma_f32_16x16x32_bf16(av[ky][1], bv[nt + ky], acc[1][nt], 0, 0, 0);
          }
      }
    }
    if (code == 5) {
      // center slab: fused pointwise (x2) tap, ci 0..19 (weights zero for k>=20)
      const char* wt = wb + (size_t)81 * 4096;
      bf16x8 a0 = *(const bf16x8*)(wt + awz0);
      bf16x8 a1 = *(const bf16x8*)(wt + 2048 + awz0);
#pragma unroll
      for (int nt = 0; nt < 4; nt++) {
        bf16x8 bv = *(const bf16x8*)(bufB + (size_t)((ybase + nt) * 16 + ln15) * 80 + kg * 16);
        acc[0][nt] = __builtin_amdgcn_mfma_f32_16x16x32_bf16(a0, bv, acc[0][nt], 0, 0, 0);
        acc[1][nt] = __builtin_amdgcn_mfma_f32_16x16x32_bf16(a1, bv, acc[1][nt], 0, 0, 0);
      }
    }
    asm volatile("s_waitcnt vmcnt(0)" ::: "memory");
    __syncthreads();
    cur ^= 1;
  }

#pragma unroll
  for (int mt = 0; mt < 2; mt++)
#pragma unroll
    for (int r = 0; r < 4; r++) {
      int o = mt * 16 + kg * 4 + r;
      if (o >= 20) continue;
      float bo = bias[o] + bpw[o];
#pragma unroll
      for (int nt = 0; nt < 4; nt++) {
        int y = ybase + nt;
        size_t oidx = ((size_t)(b * 20 + o)) * 262144 +
                      ((((size_t)t0 * 32 + x0) * 32 + y) * 16 + ln15);
        float v = acc[mt][nt][r] + bo + io[oidx];
        io[oidx] = fmaxf(v, 0.f);
      }
    }
}

extern "C" void kernel_launch(void* const* d_in, const int* in_sizes, int n_in,
                              void* d_out, int out_size, void* d_ws, size_t ws_size,
                              hipStream_t stream) {
  const float* x     = (const float*)d_in[0];
  const float* sw1   = (const float*)d_in[1];
  const float* sw2   = (const float*)d_in[2];
  const float* sw3   = (const float*)d_in[3];
  const float* sw4   = (const float*)d_in[4];
  const float* w_pw  = (const float*)d_in[5];
  const float* b_pw  = (const float*)d_in[6];
  const float* c1_w  = (const float*)d_in[7];
  const float* c2_w  = (const float*)d_in[8];
  const float* c21_w = (const float*)d_in[9];
  const float* c3_w  = (const float*)d_in[10];
  const float* c31_w = (const float*)d_in[11];
  const float* bn1_g = (const float*)d_in[12];
  const float* bn1_b = (const float*)d_in[13];
  const float* bn2_g = (const float*)d_in[14];
  const float* bn2_b = (const float*)d_in[15];
  const float* bn21_g = (const float*)d_in[16];
  const float* bn21_b = (const float*)d_in[17];
  const float* bn3_g = (const float*)d_in[18];
  const float* bn3_b = (const float*)d_in[19];
  const float* bn31_g = (const float*)d_in[20];
  const float* bn31_b = (const float*)d_in[21];
  const float* d2_w  = (const float*)d_in[22];
  const float* d2_b  = (const float*)d_in[23];
  const float* d1_w  = (const float*)d_in[24];
  const float* d1_b  = (const float*)d_in[25];
  const float* d0_w  = (const float*)d_in[26];
  const float* d0_b  = (const float*)d_in[27];
  const float* out_w = (const float*)d_in[28];
  const float* out_b = (const float*)d_in[29];
  float* out = (float*)d_out;
  float* ws = (float*)d_ws;

  // spectral arena (phase 1 only)
  float2* A  = (float2*)(ws);
  float2* Bb = (float2*)(ws + 10485760);
  float2* Cb = (float2*)(ws + 13107200);
  float2* Dd = (float2*)(ws + 14417920);
  float2* Ee = (float2*)(ws + 15073280);
  float2* Ff = (float2*)(ws + 15728640);
  float2* Gg = (float2*)(ws + 16384000);
  // twiddle tables: live only during spectral phase; region inside Xcl span,
  // beyond the spectral arena end (17,039,360 fl), overwritten later by k_xcl_x.
  float2* Twid = (float2*)(ws + 23000000);

  // U-Net arena
  float* oc1   = ws;
  short* CLd0  = (short*)(ws + 1310720);
  float* Wc1   = ws + 1310720;  // aliases CLd0 region: used only between pack and cl20
  float* oc2a  = ws + 2621440;
  float* oc2   = ws + 2703360;
  float* oc3a  = ws + 2785280;
  float* oc3   = ws + 2790400;
  float* od2   = ws + 2795520;
  short* Xcl   = (short*)(ws + 2877440);
  float* stats = ws + 23848960;
  short* Wd = (short*)(ws);
  short* Wp = (short*)(ws + 262144);
  short* zp = (short*)(ws + 349184);

  auto nb = [](int n) { return (n + 255) / 256; };
  dim3 blk(256);

  // ---- twiddle tables ----
  k_twid<<<1, 64, 0, stream>>>(Twid);

  // ---- spectral path: x1 -> d_out ----
  k_fwd_z<<<nb(1310720), blk, 0, stream>>>(x, Twid, A, 1310720);
  k_fwd_y<<<nb(1310720), blk, 0, stream>>>(A, Twid, Bb, 1310720);
  k_fwd_x<<<nb(655360), blk, 0, stream>>>(Bb, Twid, Cb, 655360);
  k_fwd_t<<<nb(327680), blk, 0, stream>>>(Cb, Twid, Dd, 327680);
  k_fwd_c<<<nb(327680), blk, 0, stream>>>(Dd, Twid, Ee, 327680);
  k_fwd_b<<<nb(327680), blk, 0, stream>>>(Ee, Twid, Ff, 327680);
  k_smul<<<nb(327680), blk, 0, stream>>>(Ff, sw1, sw2, sw3, sw4, Gg, 327680);
  k_inv_t<<<nb(655360), blk, 0, stream>>>(Gg, Twid, Cb, 655360);
  k_inv_x<<<nb(1310720), blk, 0, stream>>>(Cb, Twid, Bb, 1310720);
  k_inv_yz<<<nb(1310720), blk, 0, stream>>>(Bb, Twid, out, 1310720);

  // ---- Xcl ci 0..19 from x; c1 weight pack (into dead CLd0 region) ----
  k_pack_c1<<<nb(32400), blk, 0, stream>>>(c1_w, Wc1, 32400);
  k_xcl_x<<<nb(1048576), blk, 0, stream>>>(x, Xcl, 1048576);

  // ---- U-Net encoder ----
  k_c1<<<512, dim3(128), 0, stream>>>(x, Wc1, oc1);
  k_bn_stats<<<20, blk, 0, stream>>>(oc1, 16384, stats);
  k_bn_apply<<<nb(1310720), blk, 0, stream>>>(oc1, 16384, stats, bn1_g, bn1_b, 1310720);
  k_cl20<<<nb(65536), blk, 0, stream>>>(oc1, CLd0, 65536);

  k_c2<<<320, blk, 0, stream>>>(oc1, c2_w, oc2a);
  k_bn_stats<<<20, blk, 0, stream>>>(oc2a, 1024, stats);
  k_bn_apply<<<nb(81920), blk, 0, stream>>>(oc2a, 1024, stats, bn2_g, bn2_b, 81920);

  k_c21<<<320, blk, 0, stream>>>(oc2a, c21_w, oc2);
  k_bn_stats<<<20, blk, 0, stream>>>(oc2, 1024, stats);
  k_bn_apply<<<nb(81920), blk, 0, stream>>>(oc2, 1024, stats, bn21_g, bn21_b, 81920);

  k_c3<<<80, dim3(64), 0, stream>>>(oc2, c3_w, oc3a);
  k_bn_stats<<<20, blk, 0, stream>>>(oc3a, 64, stats);
  k_bn_apply<<<nb(5120), blk, 0, stream>>>(oc3a, 64, stats, bn3_g, bn3_b, 5120);

  k_c31<<<80, dim3(64), 0, stream>>>(oc3a, c31_w, oc3);
  k_bn_stats<<<20, blk, 0, stream>>>(oc3, 64, stats);
  k_bn_apply<<<nb(5120), blk, 0, stream>>>(oc3, 64, stats, bn31_g, bn31_b, 5120);

  // ---- decoder ----
  k_d2<<<320, blk, 0, stream>>>(oc3, d2_w, d2_b, od2);
  k_deconv_d1_cl<<<256, blk, 0, stream>>>(oc2, od2, d1_w, d1_b, CLd0, 65536);

  // weight packs
  k_pack_w<<<nb(167936), blk, 0, stream>>>(out_w, w_pw, Wp, zp, 167936);
  k_pack_wd<<<nb(524288), blk, 0, stream>>>(d0_w, Wd, 524288);

  // d0 deconv via MFMA (LDS-staged) -> Xcl ci 20..39
  k_d0_mfma<<<512, dim3(512), 0, stream>>>(CLd0, Wd, d0_b, Xcl);

  // final conv via MFMA (fully LDS-staged), fused +bias +x1 +x2(pointwise) +relu into d_out
  k_fconv_mfma<<<2048, dim3(512), 0, stream>>>(Xcl, Wp, out_b, b_pw, out);
}